// Round 3
// baseline (5126.226 us; speedup 1.0000x reference)
//
#include <hip/hip_runtime.h>

#define SEQN 3840
#define BATCH 2
#define DIMC 768
#define NH 8
#define DHD 96
#define ML 384
#define LW 10
#define BHN 16
#define ROWS (BATCH*SEQN)

static const int BND = BATCH*SEQN*DIMC;   // 5,898,240
static const int MD  = BHN*ML*DHD;        // 589,824
static const int MM_ = BHN*ML*ML;         // 2,359,296

// ---------------- reductions ----------------
__device__ __forceinline__ float wave_sum(float v) {
#pragma unroll
    for (int m = 32; m; m >>= 1) v += __shfl_xor(v, m, 64);
    return v;
}
__device__ __forceinline__ float wave_max(float v) {
#pragma unroll
    for (int m = 32; m; m >>= 1) v = fmaxf(v, __shfl_xor(v, m, 64));
    return v;
}

// ---------------- generic tiled GEMM ----------------
// BT=true : C[i,j] = sum_k A[i*lda+k] * B[j*ldb+k]
// BT=false: C[i,j] = sum_k A[i*lda+k] * B[k*ldb+j]
// conv_k>0: A element (i, kg) = x[b, n + kg/DIMC - conv_k/2, kg%DIMC] (zero pad), i=(b,n)
// bdiag   : (NN only) B'[k][j] = (k==j ? bdiag_alpha : 0) - B[k][j]
// epi==1  : scatter C[r, 0..2303] into Q/K/V [B,H,N,Dh] (q scaled by Dh^-0.5)
template<bool BT>
__global__ __launch_bounds__(256) void gemm_k(
    const float* __restrict__ A, int lda, long long sA,
    const float* __restrict__ Bm, int ldb, long long sB,
    float* __restrict__ C, int ldc, long long sC,
    int Mr, int Nc, int Kd, float alpha,
    const float* __restrict__ bias, int accumulate,
    int conv_k, int bdiag, float bdiag_alpha,
    int epi, float* __restrict__ Qo, float* __restrict__ Ko, float* __restrict__ Vo)
{
    __shared__ float As[16][64];
    __shared__ float Bs[16][64];
    const int bz = blockIdx.z;
    A  += (long long)bz * sA;
    Bm += (long long)bz * sB;
    if (C) C += (long long)bz * sC;
    const int i0 = blockIdx.y * 64, j0 = blockIdx.x * 64;
    const int tid = threadIdx.x;
    const int tx = tid & 15, ty = tid >> 4;

    const int srow = tid >> 2;        // 0..63
    const int skk  = (tid & 3) << 2;  // 0,4,8,12

    const int gi = i0 + srow;
    const bool a_valid = (gi < Mr);
    int a_b = 0, a_n = 0;
    const float* aptr = nullptr;
    if (a_valid) {
        if (conv_k) { a_b = gi / SEQN; a_n = gi - a_b * SEQN; }
        else aptr = A + (long long)gi * lda;
    }
    const float* bptr = nullptr;
    if (BT) {
        int gj = j0 + srow;
        if (gj < Nc) bptr = Bm + (long long)gj * ldb;
    }
    const int khalf = conv_k >> 1;

    float acc[4][4] = {};

    for (int k0 = 0; k0 < Kd; k0 += 16) {
        // ---- stage A ----
        float4 av = make_float4(0.f, 0.f, 0.f, 0.f);
        if (conv_k) {
            if (a_valid) {
                int tap = k0 / DIMC;
                int s = a_n + tap - khalf;
                if (s >= 0 && s < SEQN)
                    av = *(const float4*)(A + ((long long)(a_b * SEQN + s)) * lda
                                          + (k0 - tap * DIMC) + skk);
            }
        } else if (aptr) {
            av = *(const float4*)(aptr + k0 + skk);
        }
        As[skk+0][srow] = av.x; As[skk+1][srow] = av.y;
        As[skk+2][srow] = av.z; As[skk+3][srow] = av.w;
        // ---- stage B ----
        if (BT) {
            float4 bv = make_float4(0.f, 0.f, 0.f, 0.f);
            if (bptr) bv = *(const float4*)(bptr + k0 + skk);
            Bs[skk+0][srow] = bv.x; Bs[skk+1][srow] = bv.y;
            Bs[skk+2][srow] = bv.z; Bs[skk+3][srow] = bv.w;
        } else {
            const int kk = tid >> 4, j4 = (tid & 15) << 2;
            const int gk = k0 + kk;
            float4 bv = make_float4(0.f, 0.f, 0.f, 0.f);
            const float* bp = Bm + (long long)gk * ldb + j0 + j4;
            if (j0 + 64 <= Nc) {
                bv = *(const float4*)bp;
            } else {
                int rem = Nc - (j0 + j4);
                if (rem > 0) bv.x = bp[0];
                if (rem > 1) bv.y = bp[1];
                if (rem > 2) bv.z = bp[2];
                if (rem > 3) bv.w = bp[3];
            }
            if (bdiag) {
                bv.x = ((gk == j0+j4+0) ? bdiag_alpha : 0.f) - bv.x;
                bv.y = ((gk == j0+j4+1) ? bdiag_alpha : 0.f) - bv.y;
                bv.z = ((gk == j0+j4+2) ? bdiag_alpha : 0.f) - bv.z;
                bv.w = ((gk == j0+j4+3) ? bdiag_alpha : 0.f) - bv.w;
            }
            *(float4*)&Bs[kk][j4] = bv;
        }
        __syncthreads();
#pragma unroll
        for (int kk = 0; kk < 16; ++kk) {
            const float4 a4 = *(const float4*)&As[kk][ty << 2];
            const float4 b4 = *(const float4*)&Bs[kk][tx << 2];
            acc[0][0] += a4.x*b4.x; acc[0][1] += a4.x*b4.y; acc[0][2] += a4.x*b4.z; acc[0][3] += a4.x*b4.w;
            acc[1][0] += a4.y*b4.x; acc[1][1] += a4.y*b4.y; acc[1][2] += a4.y*b4.z; acc[1][3] += a4.y*b4.w;
            acc[2][0] += a4.z*b4.x; acc[2][1] += a4.z*b4.y; acc[2][2] += a4.z*b4.z; acc[2][3] += a4.z*b4.w;
            acc[3][0] += a4.w*b4.x; acc[3][1] += a4.w*b4.y; acc[3][2] += a4.w*b4.z; acc[3][3] += a4.w*b4.w;
        }
        __syncthreads();
    }
    // ---- epilogue ----
#pragma unroll
    for (int ii = 0; ii < 4; ++ii) {
        int go = i0 + (ty << 2) + ii;
        if (go >= Mr) continue;
#pragma unroll
        for (int jj = 0; jj < 4; ++jj) {
            int gj = j0 + (tx << 2) + jj;
            if (gj >= Nc) continue;
            float v = acc[ii][jj] * alpha;
            if (epi == 0) {
                if (bias) v += bias[gj];
                long long idx = (long long)go * ldc + gj;
                if (accumulate) v += C[idx];
                C[idx] = v;
            } else {
                int which = gj / DIMC;
                int c = gj - which * DIMC;
                int h = c / DHD, d = c - h * DHD;
                int b = go / SEQN, n = go - b * SEQN;
                long long o = (((long long)(b * NH + h)) * SEQN + n) * DHD + d;
                if (which == 0)      Qo[o] = v * 0.10206207261596575f; // 96^-0.5
                else if (which == 1) Ko[o] = v;
                else                 Vo[o] = v;
            }
        }
    }
}

// ---------------- fused softmax(Q K^T) @ V  (flash-style, fp32) ----------------
// Qm: [Rq, 96] rows (contiguous, stride 96); Km/Vm: [Nk, 96]; O: [Rq, 96].
// Rq and Nk divisible by 32 / 64 respectively for all call sites.
#define FA_ROWS 32
#define FA_KT 64
__global__ __launch_bounds__(256) void attn_fused_k(
    const float* __restrict__ Qm, long long sQ,
    const float* __restrict__ Km, long long sK,
    const float* __restrict__ Vm, long long sV, int Nk,
    float* __restrict__ O, long long sO)
{
    const int bh = blockIdx.z;
    Qm += (long long)bh * sQ; Km += (long long)bh * sK;
    Vm += (long long)bh * sV; O  += (long long)bh * sO;
    const int r0 = blockIdx.x * FA_ROWS;

    __shared__ float Qs[FA_ROWS][DHD+4];
    __shared__ float Ks[FA_KT][DHD+4];
    __shared__ float Vs[FA_KT][DHD+4];
    __shared__ float Ps[FA_ROWS][FA_KT+1];

    const int tid = threadIdx.x;
    const int row = tid >> 3;      // 0..31
    const int j8  = tid & 7;       // 0..7

    for (int idx = tid; idx < FA_ROWS*DHD; idx += 256) {
        int r = idx / DHD, d = idx - r*DHD;
        Qs[r][d] = Qm[(long long)(r0 + r)*DHD + d];
    }

    float acc[12];
#pragma unroll
    for (int i = 0; i < 12; ++i) acc[i] = 0.f;
    float mrow = -3.4e38f, lrow = 0.f;

    for (int k0 = 0; k0 < Nk; k0 += FA_KT) {
        __syncthreads();   // prev-iter Ps/Vs reads done before overwrite
        for (int idx = tid; idx < FA_KT*DHD; idx += 256) {
            int r = idx / DHD, d = idx - r*DHD;
            Ks[r][d] = Km[(long long)(k0 + r)*DHD + d];
            Vs[r][d] = Vm[(long long)(k0 + r)*DHD + d];
        }
        __syncthreads();   // also covers initial Qs load
        // scores: this thread handles keys j8+8*j of its row
        float sc[8];
#pragma unroll
        for (int j = 0; j < 8; ++j) sc[j] = 0.f;
        for (int d = 0; d < DHD; d += 4) {
            const float4 q4 = *(const float4*)&Qs[row][d];
#pragma unroll
            for (int j = 0; j < 8; ++j) {
                const float4 k4 = *(const float4*)&Ks[j8 + (j<<3)][d];
                sc[j] += q4.x*k4.x + q4.y*k4.y + q4.z*k4.z + q4.w*k4.w;
            }
        }
        // online softmax update (8 threads of a row are consecutive lanes)
        float mt = sc[0];
#pragma unroll
        for (int j = 1; j < 8; ++j) mt = fmaxf(mt, sc[j]);
#pragma unroll
        for (int m = 1; m < 8; m <<= 1) mt = fmaxf(mt, __shfl_xor(mt, m, 64));
        const float mnew = fmaxf(mrow, mt);
        const float corr = __expf(mrow - mnew);
        float psum = 0.f;
#pragma unroll
        for (int j = 0; j < 8; ++j) {
            float p = __expf(sc[j] - mnew);
            psum += p;
            Ps[row][j8 + (j<<3)] = p;
        }
#pragma unroll
        for (int m = 1; m < 8; m <<= 1) psum += __shfl_xor(psum, m, 64);
        lrow = lrow * corr + psum;
        mrow = mnew;
#pragma unroll
        for (int i = 0; i < 12; ++i) acc[i] *= corr;
        __syncthreads();   // Ps visible to all 8 threads of each row
#pragma unroll 4
        for (int k = 0; k < FA_KT; ++k) {
            const float p = Ps[row][k];
#pragma unroll
            for (int i = 0; i < 12; ++i)
                acc[i] += p * Vs[k][j8 + (i<<3)];
        }
    }
    const float inv = 1.f / lrow;
#pragma unroll
    for (int i = 0; i < 12; ++i)
        O[(long long)(r0 + row)*DHD + j8 + (i<<3)] = acc[i] * inv;
}

// ---------------- LayerNorm (row = 768) ----------------
__global__ __launch_bounds__(256) void ln_kernel(
    const float* __restrict__ in, const float* __restrict__ w,
    const float* __restrict__ b, float* __restrict__ out)
{
    __shared__ float red[4];
    const long long r = blockIdx.x;
    const float* row = in + r * DIMC;
    const int t = threadIdx.x, lane = t & 63, wid = t >> 6;
    float x0 = row[t], x1 = row[t+256], x2 = row[t+512];
    float s = wave_sum(x0 + x1 + x2);
    if (lane == 0) red[wid] = s;
    __syncthreads();
    float mu = (red[0]+red[1]+red[2]+red[3]) * (1.f/DIMC);
    __syncthreads();
    float d0 = x0-mu, d1 = x1-mu, d2 = x2-mu;
    float q = wave_sum(d0*d0 + d1*d1 + d2*d2);
    if (lane == 0) red[wid] = q;
    __syncthreads();
    float rs = rsqrtf((red[0]+red[1]+red[2]+red[3]) * (1.f/DIMC) + 1e-5f);
    float* orow = out + r * DIMC;
    orow[t]     = d0*rs*w[t]     + b[t];
    orow[t+256] = d1*rs*w[t+256] + b[t+256];
    orow[t+512] = d2*rs*w[t+512] + b[t+512];
}

// conv-branch epilogue: acc = (init ? x + relu(ln(y+cb)) : acc + relu(ln(y+cb)))
__global__ __launch_bounds__(256) void ln_relu_add_kernel(
    const float* __restrict__ Y, const float* __restrict__ cb,
    const float* __restrict__ w, const float* __restrict__ b,
    const float* __restrict__ xin, float* __restrict__ acc, int init)
{
    __shared__ float red[4];
    const long long r = blockIdx.x;
    const float* row = Y + r * DIMC;
    const int t = threadIdx.x, lane = t & 63, wid = t >> 6;
    float x0 = row[t]     + cb[t];
    float x1 = row[t+256] + cb[t+256];
    float x2 = row[t+512] + cb[t+512];
    float s = wave_sum(x0 + x1 + x2);
    if (lane == 0) red[wid] = s;
    __syncthreads();
    float mu = (red[0]+red[1]+red[2]+red[3]) * (1.f/DIMC);
    __syncthreads();
    float d0 = x0-mu, d1 = x1-mu, d2 = x2-mu;
    float q = wave_sum(d0*d0 + d1*d1 + d2*d2);
    if (lane == 0) red[wid] = q;
    __syncthreads();
    float rs = rsqrtf((red[0]+red[1]+red[2]+red[3]) * (1.f/DIMC) + 1e-5f);
    float v0 = fmaxf(d0*rs*w[t]     + b[t],     0.f);
    float v1 = fmaxf(d1*rs*w[t+256] + b[t+256], 0.f);
    float v2 = fmaxf(d2*rs*w[t+512] + b[t+512], 0.f);
    float* arow = acc + r * DIMC;
    if (init) {
        const float* xr = xin + r * DIMC;
        arow[t]     = xr[t]     + v0;
        arow[t+256] = xr[t+256] + v1;
        arow[t+512] = xr[t+512] + v2;
    } else {
        arow[t]     += v0;
        arow[t+256] += v1;
        arow[t+512] += v2;
    }
}

// ---------------- row softmax (in-place, W=384 for attn2) ----------------
__global__ __launch_bounds__(256) void softmax_rows(float* __restrict__ data, int W)
{
    __shared__ float red[4];
    const long long r = blockIdx.x;
    float* row = data + r * (long long)W;
    const int t = threadIdx.x, lane = t & 63, wid = t >> 6;
    float mx = -3.4e38f;
    for (int j = t; j < W; j += 256) mx = fmaxf(mx, row[j]);
    mx = wave_max(mx);
    if (lane == 0) red[wid] = mx;
    __syncthreads();
    mx = fmaxf(fmaxf(red[0], red[1]), fmaxf(red[2], red[3]));
    __syncthreads();
    float s = 0.f;
    for (int j = t; j < W; j += 256) s += __expf(row[j] - mx);
    s = wave_sum(s);
    if (lane == 0) red[wid] = s;
    __syncthreads();
    s = red[0]+red[1]+red[2]+red[3];
    const float inv = 1.f / s;
    for (int j = t; j < W; j += 256) row[j] = __expf(row[j] - mx) * inv;
}

// ---------------- small helpers ----------------
__global__ void transpose_w_kernel(const float* __restrict__ W, float* __restrict__ WT,
                                   int K, int total)
{
    int idx = blockIdx.x * 256 + threadIdx.x;
    if (idx >= total) return;
    int i = idx % DIMC; int t = idx / DIMC; int k = t % K; int o = t / K;
    WT[idx] = W[((long long)o * DIMC + i) * K + k];
}

__global__ void landmark_kernel(const float* __restrict__ src, float* __restrict__ dst)
{
    int idx = blockIdx.x * 256 + threadIdx.x;
    if (idx >= MD) return;
    int d = idx % DHD; int rem = idx / DHD; int m = rem % ML; int bh = rem / ML;
    const float* p = src + ((long long)bh * SEQN + m * LW) * DHD + d;
    float s = 0.f;
#pragma unroll
    for (int j = 0; j < LW; ++j) s += p[(long long)j * DHD];
    dst[idx] = s * (1.f / LW);
}

__global__ void init_scalars_kernel(float* sc)
{
    if (blockIdx.x == 0 && threadIdx.x < 2) sc[threadIdx.x] = 0.f;
}
__global__ void rowsum_max_kernel(const float* __restrict__ A2, float* sc)
{
    int r = blockIdx.x * 256 + threadIdx.x;
    if (r >= BHN * ML) return;
    const float* row = A2 + (long long)r * ML;
    float s = 0.f;
    for (int j = 0; j < ML; ++j) s += fabsf(row[j]);
    atomicMax((unsigned int*)(sc + 0), __float_as_uint(s));
}
__global__ void colsum_max_kernel(const float* __restrict__ A2, float* sc)
{
    int idx = blockIdx.x * 256 + threadIdx.x;
    if (idx >= BHN * ML) return;
    int j = idx % ML, bh = idx / ML;
    const float* base = A2 + (long long)bh * ML * ML + j;
    float s = 0.f;
    for (int i = 0; i < ML; ++i) s += fabsf(base[(long long)i * ML]);
    atomicMax((unsigned int*)(sc + 1), __float_as_uint(s));
}
__global__ void z0_kernel(const float* __restrict__ A2, const float* __restrict__ sc,
                          float* __restrict__ Z)
{
    long long idx = (long long)blockIdx.x * 256 + threadIdx.x;
    if (idx >= (long long)MM_) return;
    int j = idx % ML; long long rem = idx / ML; int i = (int)(rem % ML); long long bh = rem / ML;
    float inv = 1.f / (sc[0] * sc[1]);
    Z[idx] = A2[(bh * ML + j) * ML + i] * inv;
}

__global__ void resconv_kernel(const float* __restrict__ V, const float* __restrict__ RW,
                               float* __restrict__ AO)
{
    int idx = blockIdx.x * 256 + threadIdx.x;
    if (idx >= BND) return;
    int d = idx % DHD; int rem = idx / DHD; int n = rem % SEQN; int bh = rem / SEQN;
    int h = bh % NH;
    const float* vb = V + (long long)bh * SEQN * DHD + d;
    float s = 0.f;
#pragma unroll
    for (int j = 0; j < 33; ++j) {
        int sn = n + j - 16;
        if (sn >= 0 && sn < SEQN) s += vb[(long long)sn * DHD] * RW[h * 33 + j];
    }
    AO[idx] += s;
}

__global__ void concat_heads_kernel(const float* __restrict__ AO, float* __restrict__ CT)
{
    int idx = blockIdx.x * 256 + threadIdx.x;
    if (idx >= BND) return;
    int d = idx % DHD; int rem = idx / DHD; int n = rem % SEQN; int bh = rem / SEQN;
    int h = bh % NH, b = bh / NH;
    CT[((long long)(b * SEQN + n)) * DIMC + h * DHD + d] = AO[idx];
}

__global__ void sentinel_kernel(float* __restrict__ out, int n)
{
    int i = blockIdx.x * 256 + threadIdx.x;
    if (i < n) out[i] = 1.0e6f;
}

// ---------------- host ----------------
extern "C" void kernel_launch(void* const* d_in, const int* in_sizes, int n_in,
                              void* d_out, int out_size, void* d_ws, size_t ws_size,
                              hipStream_t stream)
{
    (void)in_sizes; (void)n_in;
    const float* x    = (const float*)d_in[0];
    const float* c1w  = (const float*)d_in[1];
    const float* c1b  = (const float*)d_in[2];
    const float* c2w  = (const float*)d_in[3];
    const float* c2b  = (const float*)d_in[4];
    const float* c3w  = (const float*)d_in[5];
    const float* c3b  = (const float*)d_in[6];
    const float* nw   = (const float*)d_in[7];
    const float* nb   = (const float*)d_in[8];
    const float* tw   = (const float*)d_in[9];
    const float* tb   = (const float*)d_in[10];
    const float* qkvw = (const float*)d_in[11];
    const float* outw = (const float*)d_in[12];
    const float* outb = (const float*)d_in[13];
    const float* rcw  = (const float*)d_in[14];
    float* out = (float*)d_out;
    float* ws  = (float*)d_ws;

    // workspace layout (floats) — total 37,748,752 floats ≈ 151 MB
    float* OUT_ACC = ws;                  // BND
    float* Q    = OUT_ACC + BND;          // BND  (later reused as AO, in place)
    float* Kb   = Q + BND;                // BND
    float* V    = Kb + BND;               // BND
    float* QL   = V + BND;                // MD
    float* KL   = QL + MD;                // MD
    float* A2   = KL + MD;                // MM_
    float* Za   = A2 + MM_;               // MM_
    float* Zb   = Za + MM_;               // MM_
    float* XZ   = Zb + MM_;               // MM_
    float* T1   = XZ + MM_;               // MM_
    float* R3   = T1 + MM_;               // MD
    float* W2   = R3 + MD;                // MD
    float* SC   = W2 + MD;                // 16
    // aliases (phase-disjoint):
    float* WT    = Q;                     // 15*DD = 8.85M <= Q+Kb (11.8M), conv phase only
    float* CONVY = V;                     // conv phase only
    float* T     = out;                   // tnorm output lives in d_out until final LN
    float* AO    = Q;                     // attn output overwrites Q (per-row in-place, safe)
    float* CT    = out;                   // concat target, read by out-proj, then overwritten

    size_t need_bytes = (size_t)(SC + 16 - ws) * sizeof(float);
    if (ws_size < need_bytes) {
        // loud failure signature: absmax ~1e6 instead of "all zeros"
        sentinel_kernel<<<(out_size + 255)/256, 256, 0, stream>>>(out, out_size);
        return;
    }

    auto gemm = [&](bool bt, const float* A, int lda, long long sA,
                    const float* Bm, int ldb, long long sB,
                    float* C, int ldc, long long sC,
                    int Mr, int Nc, int Kd, float alpha,
                    const float* bias, int accflag, int conv_kk,
                    int bdiag, float bd_alpha,
                    int epi, float* Qo, float* Ko, float* Vo, int batch) {
        dim3 g((Nc + 63) / 64, (Mr + 63) / 64, batch), blk(256);
        if (bt) gemm_k<true ><<<g, blk, 0, stream>>>(A, lda, sA, Bm, ldb, sB, C, ldc, sC,
                    Mr, Nc, Kd, alpha, bias, accflag, conv_kk, bdiag, bd_alpha, epi, Qo, Ko, Vo);
        else    gemm_k<false><<<g, blk, 0, stream>>>(A, lda, sA, Bm, ldb, sB, C, ldc, sC,
                    Mr, Nc, Kd, alpha, bias, accflag, conv_kk, bdiag, bd_alpha, epi, Qo, Ko, Vo);
    };

    const int DD = DIMC * DIMC;
    // 1. conv weight transposes to [O][K][I]  (WT lives in Q/Kb region)
    transpose_w_kernel<<<(DD*3 + 255)/256, 256, 0, stream>>>(c1w, WT,                   3, DD*3);
    transpose_w_kernel<<<(DD*5 + 255)/256, 256, 0, stream>>>(c2w, WT + (long long)3*DD, 5, DD*5);
    transpose_w_kernel<<<(DD*7 + 255)/256, 256, 0, stream>>>(c3w, WT + (long long)8*DD, 7, DD*7);

    // 2-4. three conv branches -> OUT_ACC = x + sum relu(ln(conv_i + b_i))
    const float* cbs[3] = {c1b, c2b, c3b};
    const int    cks[3] = {3, 5, 7};
    const long long coff[3] = {0, (long long)3*DD, (long long)8*DD};
    for (int ci = 0; ci < 3; ++ci) {
        int K = cks[ci];
        gemm(true, x, DIMC, 0, WT + coff[ci], K*DIMC, 0, CONVY, DIMC, 0,
             ROWS, DIMC, K*DIMC, 1.f, nullptr, 0, K, 0, 0.f, 0, nullptr, nullptr, nullptr, 1);
        ln_relu_add_kernel<<<ROWS, 256, 0, stream>>>(CONVY, cbs[ci], nw, nb, x, OUT_ACC, ci == 0);
    }

    // 5. T = ln(OUT_ACC, tnorm)   (T == d_out used as scratch)
    ln_kernel<<<ROWS, 256, 0, stream>>>(OUT_ACC, tw, tb, T);

    // 6. QKV projection with head-scatter epilogue (q scaled); overwrites WT/CONVY aliases
    gemm(true, T, DIMC, 0, qkvw, DIMC, 0, nullptr, 0, 0,
         ROWS, 3*DIMC, DIMC, 1.f, nullptr, 0, 0, 0, 0.f, 1, Q, Kb, V, 1);

    // 7. landmarks (means of 10-groups)
    landmark_kernel<<<(MD + 255)/256, 256, 0, stream>>>(Q,  QL);
    landmark_kernel<<<(MD + 255)/256, 256, 0, stream>>>(Kb, KL);

    const long long sMD = (long long)ML*DHD, sMM = (long long)ML*ML,
                    sND = (long long)SEQN*DHD;

    // 8-9. sim2 + softmax -> A2 (materialized; pinv needs it)
    gemm(true, QL, DHD, sMD, KL, DHD, sMD, A2, ML, sMM,
         ML, ML, DHD, 1.f, nullptr, 0, 0, 0, 0.f, 0, nullptr, nullptr, nullptr, BHN);
    softmax_rows<<<BHN*ML, 256, 0, stream>>>(A2, ML);

    // 10. pinv init: z0 = attn2^T / (max_rowsum * max_colsum)
    init_scalars_kernel<<<1, 64, 0, stream>>>(SC);
    rowsum_max_kernel<<<(BHN*ML + 255)/256, 256, 0, stream>>>(A2, SC);
    colsum_max_kernel<<<(BHN*ML + 255)/256, 256, 0, stream>>>(A2, SC);
    z0_kernel<<<(MM_ + 255)/256, 256, 0, stream>>>(A2, SC, Za);

    // 11. Newton-Schulz x6: z = 0.25 z (13I - xz(15I - xz(7I - xz)))
    float* Zc = Za; float* Zn = Zb;
    for (int it = 0; it < 6; ++it) {
        gemm(false, A2, ML, sMM, Zc, ML, sMM, XZ, ML, sMM,
             ML, ML, ML, 1.f, nullptr, 0, 0, 0, 0.f, 0, nullptr, nullptr, nullptr, BHN);
        gemm(false, XZ, ML, sMM, XZ, ML, sMM, Zn, ML, sMM,
             ML, ML, ML, 1.f, nullptr, 0, 0, 1, 7.f, 0, nullptr, nullptr, nullptr, BHN);
        gemm(false, XZ, ML, sMM, Zn, ML, sMM, T1, ML, sMM,
             ML, ML, ML, 1.f, nullptr, 0, 0, 1, 15.f, 0, nullptr, nullptr, nullptr, BHN);
        gemm(false, Zc, ML, sMM, T1, ML, sMM, Zn, ML, sMM,
             ML, ML, ML, 0.25f, nullptr, 0, 0, 1, 13.f, 0, nullptr, nullptr, nullptr, BHN);
        float* tswap = Zc; Zc = Zn; Zn = tswap;
    }

    // 12. R3 = softmax(QL K^T) @ V    (fused; no score materialization)
    {
        dim3 g(ML/FA_ROWS, 1, BHN), blk(256);
        attn_fused_k<<<g, blk, 0, stream>>>(QL, sMD, Kb, sND, V, sND, SEQN, R3, sMD);
    }

    // 13. W2 = pinv(attn2) @ R3
    gemm(false, Zc, ML, sMM, R3, DHD, sMD, W2, DHD, sMD,
         ML, DHD, ML, 1.f, nullptr, 0, 0, 0, 0.f, 0, nullptr, nullptr, nullptr, BHN);

    // 14. AO = softmax(Q KL^T) @ W2   (fused; AO overwrites Q in place, row-identity)
    {
        dim3 g(SEQN/FA_ROWS, 1, BHN), blk(256);
        attn_fused_k<<<g, blk, 0, stream>>>(Q, sND, KL, sMD, W2, sMD, ML, AO, sND);
    }

    // 15. residual depthwise conv on V, added to AO
    resconv_kernel<<<(BND + 255)/256, 256, 0, stream>>>(V, rcw, AO);

    // 16. [B,H,N,Dh] -> [B,N,D]  (CT == d_out)
    concat_heads_kernel<<<(BND + 255)/256, 256, 0, stream>>>(AO, CT);

    // 17. out projection + bias, accumulated into OUT_ACC (outer residual)
    gemm(true, CT, DIMC, 0, outw, DIMC, 0, OUT_ACC, DIMC, 0,
         ROWS, DIMC, DIMC, 1.f, outb, 1, 0, 0, 0.f, 0, nullptr, nullptr, nullptr, 1);

    // 18. final layernorm -> d_out
    ln_kernel<<<ROWS, 256, 0, stream>>>(OUT_ACC, nw, nb, out);
}

// Round 4
// 2666.823 us; speedup vs baseline: 1.9222x; 1.9222x over previous
//
#include <hip/hip_runtime.h>

#define SEQN 3840
#define BATCH 2
#define DIMC 768
#define NH 8
#define DHD 96
#define ML 384
#define LW 10
#define BHN 16
#define ROWS (BATCH*SEQN)
#define PADX 4
#define XPADN (SEQN + 2*PADX)   // 3848

static const int BND = BATCH*SEQN*DIMC;   // 5,898,240
static const int MD  = BHN*ML*DHD;        // 589,824
static const int MM_ = BHN*ML*ML;         // 2,359,296

// ---------------- bf16 helpers ----------------
__device__ __forceinline__ unsigned short f2bf(float f) {
    unsigned int u = __float_as_uint(f);
    u = (u + 0x7FFF + ((u >> 16) & 1)) >> 16;   // RNE
    return (unsigned short)u;
}
__device__ __forceinline__ float bf2f(unsigned short s) {
    return __uint_as_float(((unsigned int)s) << 16);
}

// ---------------- reductions ----------------
__device__ __forceinline__ float wave_sum(float v) {
#pragma unroll
    for (int m = 32; m; m >>= 1) v += __shfl_xor(v, m, 64);
    return v;
}
__device__ __forceinline__ float wave_max(float v) {
#pragma unroll
    for (int m = 32; m; m >>= 1) v = fmaxf(v, __shfl_xor(v, m, 64));
    return v;
}

// ================= bf16 MFMA GEMM =================
// C = alpha * A @ B' ; A bf16 [Mr][Kd] (or implicit conv im2col of padded X)
// BMODE 0 (BT): B' from B[N][K] row-major (rows along K)
// BMODE 1 (NN): B' from B[K][N] row-major; optional bdiag: B'[k][j] = (k==j?bda:0)-B[k][j]
// epi: 0 = f32 store; 1 = f32 C += v + bias; 2 = bf16 store; 3 = QKV head-scatter (bf16)
typedef short bf16x8 __attribute__((ext_vector_type(8)));
typedef float f32x4 __attribute__((ext_vector_type(4)));
#define ROWP 40   // LDS row pitch in shorts (80 B: 16B-aligned, 2-way-max bank pattern)

template<int BMODE>
__global__ __launch_bounds__(256) void mgemm_k(
    const unsigned short* __restrict__ A, int lda, long long sA,
    const unsigned short* __restrict__ Bm, int ldb, long long sB,
    int Mr, int Nc, int Kd, float alpha, int bdiag, float bda, int conv_k,
    int epi, float* __restrict__ Cf, long long sC, int ldc,
    unsigned short* __restrict__ Cb, const float* __restrict__ bias,
    unsigned short* __restrict__ Qo, unsigned short* __restrict__ Ko,
    unsigned short* __restrict__ Vo)
{
    __shared__ unsigned short As[128*ROWP] __attribute__((aligned(16)));
    __shared__ unsigned short Bs[128*ROWP] __attribute__((aligned(16)));
    const int bz = blockIdx.z;
    const long long aoff = (long long)bz * sA, boff = (long long)bz * sB;
    const long long coff = (long long)bz * sC;
    const int i0 = blockIdx.y * 128, j0 = blockIdx.x * 128;
    const int tid = threadIdx.x;
    const int w = tid >> 6, l = tid & 63;
    const int wr = (w >> 1) << 6, wc = (w & 1) << 6;
    const int lr = l & 15, lk = l >> 4;
    const int khalf = conv_k >> 1;

    f32x4 acc[4][4] = {};

    for (int k0 = 0; k0 < Kd; k0 += 32) {
        // ---- stage A: 128 rows x 32 shorts ----
#pragma unroll
        for (int pass = 0; pass < 2; ++pass) {
            const int flat = tid + pass * 256;
            const int row = flat >> 2, seg = (flat & 3) << 3;
            long long ga;
            if (conv_k) {
                const int gi = i0 + row;
                const int b = gi / SEQN, n = gi - b * SEQN;
                const int tap = k0 / DIMC, c = k0 - tap * DIMC;
                ga = ((long long)(b * XPADN + n + tap + PADX - khalf)) * DIMC + c + seg;
            } else {
                ga = aoff + (long long)(i0 + row) * lda + k0 + seg;
            }
            *(uint4*)&As[row * ROWP + seg] = *(const uint4*)&A[ga];
        }
        // ---- stage B into Bs[col][k] ----
        if (BMODE == 0) {
#pragma unroll
            for (int pass = 0; pass < 2; ++pass) {
                const int flat = tid + pass * 256;
                const int row = flat >> 2, seg = (flat & 3) << 3;
                const int gj = j0 + row;
                uint4 v;
                if (gj < Nc) v = *(const uint4*)&Bm[boff + (long long)gj * ldb + k0 + seg];
                else { v.x = v.y = v.z = v.w = 0u; }
                *(uint4*)&Bs[row * ROWP + seg] = v;
            }
        } else {
            const int col = tid & 127, kb = tid >> 7;
            const int gj = j0 + col;
#pragma unroll
            for (int pass = 0; pass < 4; ++pass) {
                const int k4 = ((kb + pass * 2) << 2);
                unsigned short pk[4];
                if (gj < Nc) {
#pragma unroll
                    for (int u = 0; u < 4; ++u) {
                        const int gk = k0 + k4 + u;
                        float v = bf2f(Bm[boff + (long long)gk * ldb + gj]);
                        if (bdiag) v = ((gk == gj) ? bda : 0.f) - v;
                        pk[u] = f2bf(v);
                    }
                } else pk[0] = pk[1] = pk[2] = pk[3] = 0;
                unsigned short* d = &Bs[col * ROWP + k4];
                d[0] = pk[0]; d[1] = pk[1]; d[2] = pk[2]; d[3] = pk[3];
            }
        }
        __syncthreads();
        // ---- compute: each wave 64x64 via 16 MFMA 16x16x32 ----
        bf16x8 af[4], bfv[4];
#pragma unroll
        for (int fi = 0; fi < 4; ++fi)
            af[fi] = *(const bf16x8*)&As[(wr + fi * 16 + lr) * ROWP + lk * 8];
#pragma unroll
        for (int fj = 0; fj < 4; ++fj)
            bfv[fj] = *(const bf16x8*)&Bs[(wc + fj * 16 + lr) * ROWP + lk * 8];
#pragma unroll
        for (int fi = 0; fi < 4; ++fi)
#pragma unroll
            for (int fj = 0; fj < 4; ++fj)
                acc[fi][fj] = __builtin_amdgcn_mfma_f32_16x16x32_bf16(
                    af[fi], bfv[fj], acc[fi][fj], 0, 0, 0);
        __syncthreads();
    }
    // ---- epilogue ----
#pragma unroll
    for (int fi = 0; fi < 4; ++fi) {
#pragma unroll
        for (int fj = 0; fj < 4; ++fj) {
            const int col = j0 + wc + fj * 16 + lr;
            if (col >= Nc) continue;
#pragma unroll
            for (int r = 0; r < 4; ++r) {
                const int row = i0 + wr + fi * 16 + lk * 4 + r;
                float v = acc[fi][fj][r] * alpha;
                if (epi == 0) {
                    Cf[coff + (long long)row * ldc + col] = v;
                } else if (epi == 1) {
                    const long long ix = coff + (long long)row * ldc + col;
                    Cf[ix] = Cf[ix] + v + bias[col];
                } else if (epi == 2) {
                    Cb[coff + (long long)row * ldc + col] = f2bf(v);
                } else {
                    const int which = col / DIMC;
                    const int c = col - which * DIMC;
                    const int h = c / DHD, d = c - h * DHD;
                    const int b = row / SEQN, n = row - b * SEQN;
                    const long long o = (((long long)(b * NH + h)) * SEQN + n) * DHD + d;
                    if (which == 0)      Qo[o] = f2bf(v * 0.10206207261596575f);
                    else if (which == 1) Ko[o] = f2bf(v);
                    else                 Vo[o] = f2bf(v);
                }
            }
        }
    }
}

// ---------------- fp32 tiled GEMM (kept for small sim2) ----------------
template<bool BT>
__global__ __launch_bounds__(256) void gemm_k(
    const float* __restrict__ A, int lda, long long sA,
    const float* __restrict__ Bm, int ldb, long long sB,
    float* __restrict__ C, int ldc, long long sC,
    int Mr, int Nc, int Kd)
{
    __shared__ float As[16][64];
    __shared__ float Bs[16][64];
    const int bz = blockIdx.z;
    A += (long long)bz * sA; Bm += (long long)bz * sB; C += (long long)bz * sC;
    const int i0 = blockIdx.y * 64, j0 = blockIdx.x * 64;
    const int tid = threadIdx.x;
    const int tx = tid & 15, ty = tid >> 4;
    const int srow = tid >> 2, skk = (tid & 3) << 2;
    const int gi = i0 + srow;
    const float* aptr = (gi < Mr) ? A + (long long)gi * lda : nullptr;
    const float* bptr = nullptr;
    {
        int gj = j0 + srow;
        if (gj < Nc) bptr = Bm + (long long)gj * ldb;
    }
    float acc[4][4] = {};
    for (int k0 = 0; k0 < Kd; k0 += 16) {
        float4 av = make_float4(0.f,0.f,0.f,0.f);
        if (aptr) av = *(const float4*)(aptr + k0 + skk);
        As[skk+0][srow]=av.x; As[skk+1][srow]=av.y; As[skk+2][srow]=av.z; As[skk+3][srow]=av.w;
        float4 bv = make_float4(0.f,0.f,0.f,0.f);
        if (bptr) bv = *(const float4*)(bptr + k0 + skk);
        Bs[skk+0][srow]=bv.x; Bs[skk+1][srow]=bv.y; Bs[skk+2][srow]=bv.z; Bs[skk+3][srow]=bv.w;
        __syncthreads();
#pragma unroll
        for (int kk = 0; kk < 16; ++kk) {
            const float4 a4 = *(const float4*)&As[kk][ty << 2];
            const float4 b4 = *(const float4*)&Bs[kk][tx << 2];
            acc[0][0]+=a4.x*b4.x; acc[0][1]+=a4.x*b4.y; acc[0][2]+=a4.x*b4.z; acc[0][3]+=a4.x*b4.w;
            acc[1][0]+=a4.y*b4.x; acc[1][1]+=a4.y*b4.y; acc[1][2]+=a4.y*b4.z; acc[1][3]+=a4.y*b4.w;
            acc[2][0]+=a4.z*b4.x; acc[2][1]+=a4.z*b4.y; acc[2][2]+=a4.z*b4.z; acc[2][3]+=a4.z*b4.w;
            acc[3][0]+=a4.w*b4.x; acc[3][1]+=a4.w*b4.y; acc[3][2]+=a4.w*b4.z; acc[3][3]+=a4.w*b4.w;
        }
        __syncthreads();
    }
#pragma unroll
    for (int ii = 0; ii < 4; ++ii) {
        int go = i0 + (ty << 2) + ii;
        if (go >= Mr) continue;
#pragma unroll
        for (int jj = 0; jj < 4; ++jj) {
            int gj = j0 + (tx << 2) + jj;
            if (gj >= Nc) continue;
            C[(long long)go * ldc + gj] = acc[ii][jj];
        }
    }
}

// ---------------- fused softmax(Q K^T) @ V (flash-style; bf16 in, f32 math) ----------------
#define FA_ROWS 32
#define FA_KT 64
template<int OBF>   // 1: bf16 output, 0: f32 output
__global__ __launch_bounds__(256) void attn_fused_k(
    const unsigned short* __restrict__ Qm, long long sQ,
    const unsigned short* __restrict__ Km, long long sK,
    const unsigned short* __restrict__ Vm, long long sV, int Nk,
    float* __restrict__ Of, unsigned short* __restrict__ Ob, long long sO)
{
    const int bh = blockIdx.z;
    Qm += (long long)bh * sQ; Km += (long long)bh * sK; Vm += (long long)bh * sV;
    const int r0 = blockIdx.x * FA_ROWS;

    __shared__ float Qs[FA_ROWS][DHD+4];
    __shared__ float Ks[FA_KT][DHD+4];
    __shared__ float Vs[FA_KT][DHD+4];
    __shared__ float Ps[FA_ROWS][FA_KT+1];

    const int tid = threadIdx.x;
    const int row = tid >> 3, j8 = tid & 7;

    for (int idx = tid; idx < FA_ROWS*DHD/4; idx += 256) {
        int e = idx * 4; int r = e / DHD, d = e - r * DHD;
        ushort4 q = *(const ushort4*)&Qm[(long long)(r0 + r) * DHD + d];
        Qs[r][d] = bf2f(q.x); Qs[r][d+1] = bf2f(q.y); Qs[r][d+2] = bf2f(q.z); Qs[r][d+3] = bf2f(q.w);
    }

    float acc[12];
#pragma unroll
    for (int i = 0; i < 12; ++i) acc[i] = 0.f;
    float mrow = -3.4e38f, lrow = 0.f;

    for (int k0 = 0; k0 < Nk; k0 += FA_KT) {
        __syncthreads();
        for (int idx = tid; idx < FA_KT*DHD/4; idx += 256) {
            int e = idx * 4; int r = e / DHD, d = e - r * DHD;
            ushort4 kv = *(const ushort4*)&Km[(long long)(k0 + r) * DHD + d];
            Ks[r][d] = bf2f(kv.x); Ks[r][d+1] = bf2f(kv.y); Ks[r][d+2] = bf2f(kv.z); Ks[r][d+3] = bf2f(kv.w);
            ushort4 vv = *(const ushort4*)&Vm[(long long)(k0 + r) * DHD + d];
            Vs[r][d] = bf2f(vv.x); Vs[r][d+1] = bf2f(vv.y); Vs[r][d+2] = bf2f(vv.z); Vs[r][d+3] = bf2f(vv.w);
        }
        __syncthreads();
        float sc[8];
#pragma unroll
        for (int j = 0; j < 8; ++j) sc[j] = 0.f;
        for (int d = 0; d < DHD; d += 4) {
            const float4 q4 = *(const float4*)&Qs[row][d];
#pragma unroll
            for (int j = 0; j < 8; ++j) {
                const float4 k4 = *(const float4*)&Ks[j8 + (j<<3)][d];
                sc[j] += q4.x*k4.x + q4.y*k4.y + q4.z*k4.z + q4.w*k4.w;
            }
        }
        float mt = sc[0];
#pragma unroll
        for (int j = 1; j < 8; ++j) mt = fmaxf(mt, sc[j]);
#pragma unroll
        for (int m = 1; m < 8; m <<= 1) mt = fmaxf(mt, __shfl_xor(mt, m, 64));
        const float mnew = fmaxf(mrow, mt);
        const float corr = __expf(mrow - mnew);
        float psum = 0.f;
#pragma unroll
        for (int j = 0; j < 8; ++j) {
            float p = __expf(sc[j] - mnew);
            psum += p;
            Ps[row][j8 + (j<<3)] = p;
        }
#pragma unroll
        for (int m = 1; m < 8; m <<= 1) psum += __shfl_xor(psum, m, 64);
        lrow = lrow * corr + psum;
        mrow = mnew;
#pragma unroll
        for (int i = 0; i < 12; ++i) acc[i] *= corr;
        __syncthreads();
#pragma unroll 4
        for (int k = 0; k < FA_KT; ++k) {
            const float p = Ps[row][k];
#pragma unroll
            for (int i = 0; i < 12; ++i)
                acc[i] += p * Vs[k][j8 + (i<<3)];
        }
    }
    const float inv = 1.f / lrow;
    const long long ob = (long long)bh * sO + (long long)(r0 + row) * DHD + j8;
#pragma unroll
    for (int i = 0; i < 12; ++i) {
        if (OBF) Ob[ob + (i<<3)] = f2bf(acc[i] * inv);
        else     Of[ob + (i<<3)] = acc[i] * inv;
    }
}

// ---------------- LayerNorm (row = 768), dual-dtype output ----------------
__global__ __launch_bounds__(256) void ln_kernel(
    const float* __restrict__ in, const float* __restrict__ w,
    const float* __restrict__ b, float* __restrict__ outf,
    unsigned short* __restrict__ outb)
{
    __shared__ float red[4];
    const long long r = blockIdx.x;
    const float* row = in + r * DIMC;
    const int t = threadIdx.x, lane = t & 63, wid = t >> 6;
    float x0 = row[t], x1 = row[t+256], x2 = row[t+512];
    float s = wave_sum(x0 + x1 + x2);
    if (lane == 0) red[wid] = s;
    __syncthreads();
    float mu = (red[0]+red[1]+red[2]+red[3]) * (1.f/DIMC);
    __syncthreads();
    float d0 = x0-mu, d1 = x1-mu, d2 = x2-mu;
    float q = wave_sum(d0*d0 + d1*d1 + d2*d2);
    if (lane == 0) red[wid] = q;
    __syncthreads();
    float rs = rsqrtf((red[0]+red[1]+red[2]+red[3]) * (1.f/DIMC) + 1e-5f);
    float v0 = d0*rs*w[t]     + b[t];
    float v1 = d1*rs*w[t+256] + b[t+256];
    float v2 = d2*rs*w[t+512] + b[t+512];
    if (outf) {
        float* o = outf + r * DIMC;
        o[t] = v0; o[t+256] = v1; o[t+512] = v2;
    }
    if (outb) {
        unsigned short* o = outb + r * DIMC;
        o[t] = f2bf(v0); o[t+256] = f2bf(v1); o[t+512] = f2bf(v2);
    }
}

// conv-branch epilogue: acc = (init ? x : acc) + relu(ln(y+cb))
__global__ __launch_bounds__(256) void ln_relu_add_kernel(
    const float* __restrict__ Y, const float* __restrict__ cb,
    const float* __restrict__ w, const float* __restrict__ b,
    const float* __restrict__ xin, float* __restrict__ acc, int init)
{
    __shared__ float red[4];
    const long long r = blockIdx.x;
    const float* row = Y + r * DIMC;
    const int t = threadIdx.x, lane = t & 63, wid = t >> 6;
    float x0 = row[t]     + cb[t];
    float x1 = row[t+256] + cb[t+256];
    float x2 = row[t+512] + cb[t+512];
    float s = wave_sum(x0 + x1 + x2);
    if (lane == 0) red[wid] = s;
    __syncthreads();
    float mu = (red[0]+red[1]+red[2]+red[3]) * (1.f/DIMC);
    __syncthreads();
    float d0 = x0-mu, d1 = x1-mu, d2 = x2-mu;
    float q = wave_sum(d0*d0 + d1*d1 + d2*d2);
    if (lane == 0) red[wid] = q;
    __syncthreads();
    float rs = rsqrtf((red[0]+red[1]+red[2]+red[3]) * (1.f/DIMC) + 1e-5f);
    float v0 = fmaxf(d0*rs*w[t]     + b[t],     0.f);
    float v1 = fmaxf(d1*rs*w[t+256] + b[t+256], 0.f);
    float v2 = fmaxf(d2*rs*w[t+512] + b[t+512], 0.f);
    float* arow = acc + r * DIMC;
    if (init) {
        const float* xr = xin + r * DIMC;
        arow[t]     = xr[t]     + v0;
        arow[t+256] = xr[t+256] + v1;
        arow[t+512] = xr[t+512] + v2;
    } else {
        arow[t]     += v0;
        arow[t+256] += v1;
        arow[t+512] += v2;
    }
}

// ---------------- row softmax (in-place, W=384) ----------------
__global__ __launch_bounds__(256) void softmax_rows(float* __restrict__ data, int W)
{
    __shared__ float red[4];
    const long long r = blockIdx.x;
    float* row = data + r * (long long)W;
    const int t = threadIdx.x, lane = t & 63, wid = t >> 6;
    float mx = -3.4e38f;
    for (int j = t; j < W; j += 256) mx = fmaxf(mx, row[j]);
    mx = wave_max(mx);
    if (lane == 0) red[wid] = mx;
    __syncthreads();
    mx = fmaxf(fmaxf(red[0], red[1]), fmaxf(red[2], red[3]));
    __syncthreads();
    float s = 0.f;
    for (int j = t; j < W; j += 256) s += __expf(row[j] - mx);
    s = wave_sum(s);
    if (lane == 0) red[wid] = s;
    __syncthreads();
    s = red[0]+red[1]+red[2]+red[3];
    const float inv = 1.f / s;
    for (int j = t; j < W; j += 256) row[j] = __expf(row[j] - mx) * inv;
}

// ---------------- small helpers ----------------
__global__ void pad_x_kernel(const float* __restrict__ x, unsigned short* __restrict__ xp)
{
    int i = blockIdx.x * 256 + threadIdx.x;
    if (i >= BATCH * XPADN * (DIMC/4)) return;
    int e = i * 4;
    int c = e % DIMC; int rr = e / DIMC; int pr = rr % XPADN; int b = rr / XPADN;
    int n = pr - PADX;
    ushort4 o;
    if (n < 0 || n >= SEQN) { o.x = o.y = o.z = o.w = 0; }
    else {
        float4 v = *(const float4*)&x[((long long)(b * SEQN + n)) * DIMC + c];
        o.x = f2bf(v.x); o.y = f2bf(v.y); o.z = f2bf(v.z); o.w = f2bf(v.w);
    }
    *(ushort4*)&xp[e] = o;
}

// conv weight [O][I][K] -> bf16 [O][K][I]
__global__ void transpose_w_bf16_kernel(const float* __restrict__ W,
                                        unsigned short* __restrict__ WT, int K, int total)
{
    int idx = blockIdx.x * 256 + threadIdx.x;
    if (idx >= total) return;
    int i = idx % DIMC; int t = idx / DIMC; int k = t % K; int o = t / K;
    WT[idx] = f2bf(W[((long long)o * DIMC + i) * K + k]);
}

__global__ void cvt_bf16_kernel(const float* __restrict__ src,
                                unsigned short* __restrict__ dst, int n4)
{
    int i = blockIdx.x * 256 + threadIdx.x;
    if (i >= n4) return;
    float4 v = ((const float4*)src)[i];
    ushort4 o; o.x = f2bf(v.x); o.y = f2bf(v.y); o.z = f2bf(v.z); o.w = f2bf(v.w);
    ((ushort4*)dst)[i] = o;
}

__global__ void landmark_kernel(const unsigned short* __restrict__ src,
                                float* __restrict__ dstf, unsigned short* __restrict__ dstb)
{
    int idx = blockIdx.x * 256 + threadIdx.x;
    if (idx >= MD) return;
    int d = idx % DHD; int rem = idx / DHD; int m = rem % ML; int bh = rem / ML;
    const unsigned short* p = src + ((long long)bh * SEQN + m * LW) * DHD + d;
    float s = 0.f;
#pragma unroll
    for (int j = 0; j < LW; ++j) s += bf2f(p[(long long)j * DHD]);
    s *= (1.f / LW);
    dstf[idx] = s;
    dstb[idx] = f2bf(s);
}

__global__ void init_scalars_kernel(float* sc)
{
    if (blockIdx.x == 0 && threadIdx.x < 2) sc[threadIdx.x] = 0.f;
}
__global__ void rowsum_max_kernel(const float* __restrict__ A2, float* sc)
{
    int r = blockIdx.x * 256 + threadIdx.x;
    if (r >= BHN * ML) return;
    const float* row = A2 + (long long)r * ML;
    float s = 0.f;
    for (int j = 0; j < ML; ++j) s += fabsf(row[j]);
    atomicMax((unsigned int*)(sc + 0), __float_as_uint(s));
}
__global__ void colsum_max_kernel(const float* __restrict__ A2, float* sc)
{
    int idx = blockIdx.x * 256 + threadIdx.x;
    if (idx >= BHN * ML) return;
    int j = idx % ML, bh = idx / ML;
    const float* base = A2 + (long long)bh * ML * ML + j;
    float s = 0.f;
    for (int i = 0; i < ML; ++i) s += fabsf(base[(long long)i * ML]);
    atomicMax((unsigned int*)(sc + 1), __float_as_uint(s));
}
__global__ void z0_kernel(const float* __restrict__ A2, const float* __restrict__ sc,
                          unsigned short* __restrict__ Z)
{
    long long idx = (long long)blockIdx.x * 256 + threadIdx.x;
    if (idx >= (long long)MM_) return;
    int j = idx % ML; long long rem = idx / ML; int i = (int)(rem % ML); long long bh = rem / ML;
    float inv = 1.f / (sc[0] * sc[1]);
    Z[idx] = f2bf(A2[(bh * ML + j) * ML + i] * inv);
}

__global__ void resconv_kernel(const unsigned short* __restrict__ V,
                               const float* __restrict__ RW, float* __restrict__ AO)
{
    int idx = blockIdx.x * 256 + threadIdx.x;
    if (idx >= BND) return;
    int d = idx % DHD; int rem = idx / DHD; int n = rem % SEQN; int bh = rem / SEQN;
    int h = bh % NH;
    const unsigned short* vb = V + (long long)bh * SEQN * DHD + d;
    float s = 0.f;
#pragma unroll
    for (int j = 0; j < 33; ++j) {
        int sn = n + j - 16;
        if (sn >= 0 && sn < SEQN) s += bf2f(vb[(long long)sn * DHD]) * RW[h * 33 + j];
    }
    AO[idx] += s;
}

__global__ void concat_heads_kernel(const float* __restrict__ AO,
                                    unsigned short* __restrict__ CT)
{
    int idx = blockIdx.x * 256 + threadIdx.x;
    if (idx >= BND) return;
    int d = idx % DHD; int rem = idx / DHD; int n = rem % SEQN; int bh = rem / SEQN;
    int h = bh % NH, b = bh / NH;
    CT[((long long)(b * SEQN + n)) * DIMC + h * DHD + d] = f2bf(AO[idx]);
}

__global__ void sentinel_kernel(float* __restrict__ out, int n)
{
    int i = blockIdx.x * 256 + threadIdx.x;
    if (i < n) out[i] = 1.0e6f;
}

// ---------------- host ----------------
extern "C" void kernel_launch(void* const* d_in, const int* in_sizes, int n_in,
                              void* d_out, int out_size, void* d_ws, size_t ws_size,
                              hipStream_t stream)
{
    (void)in_sizes; (void)n_in;
    const float* x    = (const float*)d_in[0];
    const float* c1w  = (const float*)d_in[1];
    const float* c1b  = (const float*)d_in[2];
    const float* c2w  = (const float*)d_in[3];
    const float* c2b  = (const float*)d_in[4];
    const float* c3w  = (const float*)d_in[5];
    const float* c3b  = (const float*)d_in[6];
    const float* nw   = (const float*)d_in[7];
    const float* nb   = (const float*)d_in[8];
    const float* tw   = (const float*)d_in[9];
    const float* tb   = (const float*)d_in[10];
    const float* qkvw = (const float*)d_in[11];
    const float* outw = (const float*)d_in[12];
    const float* outb = (const float*)d_in[13];
    const float* rcw  = (const float*)d_in[14];
    float* out = (float*)d_out;
    float* ws  = (float*)d_ws;

    // ---------- workspace layout (float units; bf16 buffers carved as ushort*) ----------
    const int POOLA_F = 7378944;   // Xpad(5,910,528sh)+WTbf(8,847,360sh); Tbf aliases Xpad
    const int POOLB_F = 8847360;   // Qbf/Kbf/Vbf (BND sh each); CONVY f32 alias; CTbf aliases Kbf
    const int POOLC_F = 3538944;   // qkvw/outw/A2bf/R3bf/QLbf/KLbf/W2bf
    float* OUT_ACC = ws;                          // BND f32
    float* A2f  = OUT_ACC + BND;                  // MM_ f32; reused as XZbf+T1bf after z0
    float* QLf  = A2f + MM_;                      // MD f32
    float* KLf  = QLf + MD;                       // MD f32
    float* Zab  = KLf + MD;                       // MM_ f32 (= Za_bf + Zb_bf shorts)
    float* AOf  = Zab + MM_;                      // BND f32
    float* poolA = AOf + BND;
    float* poolB = poolA + POOLA_F;
    float* poolC = poolB + POOLB_F;
    float* SC   = poolC + POOLC_F;                // 16 f32

    unsigned short* Xpad  = (unsigned short*)poolA;          // [2][3848][768]
    unsigned short* WTbf  = Xpad + BATCH*XPADN*DIMC;         // 8,847,360 sh
    unsigned short* Tbf   = Xpad;                            // alias (post-conv)
    float*          CONVY = poolB;                           // f32 alias (conv phase)
    unsigned short* Qbf   = (unsigned short*)poolB;          // BND sh
    unsigned short* Kbf   = Qbf + BND;
    unsigned short* Vbf   = Kbf + BND;
    unsigned short* CTbf  = Kbf;                             // alias (post-attn)
    unsigned short* qkvwb = (unsigned short*)poolC;          // 1,769,472 sh
    unsigned short* outwb = qkvwb + 3*DIMC*DIMC;             // 589,824 sh
    unsigned short* A2bf  = outwb + DIMC*DIMC;               // MM_ sh
    unsigned short* R3bf  = A2bf + MM_;                      // MD sh
    unsigned short* QLbf  = R3bf + MD;                       // MD sh
    unsigned short* KLbf  = QLbf + MD;                       // MD sh
    unsigned short* W2bf  = KLbf + MD;                       // MD sh
    unsigned short* XZbf  = (unsigned short*)A2f;            // MM_ sh (A2f dead post-z0/cvt)
    unsigned short* T1bf  = XZbf + MM_;
    unsigned short* Zabf  = (unsigned short*)Zab;
    unsigned short* Zbbf  = Zabf + MM_;

    size_t need_bytes = (size_t)(SC + 16 - ws) * sizeof(float);
    if (ws_size < need_bytes) {
        sentinel_kernel<<<(out_size + 255)/256, 256, 0, stream>>>(out, out_size);
        return;
    }

    auto mg = [&](int bmode, const unsigned short* A, int lda, long long sA,
                  const unsigned short* Bm, int ldb, long long sB,
                  int Mr, int Nc, int Kd, float alpha, int bdiag, float bda, int convk,
                  int epi, float* Cf, long long sC, int ldc, unsigned short* Cb,
                  const float* bias, unsigned short* Qo, unsigned short* Ko,
                  unsigned short* Vo, int batch) {
        dim3 g((Nc + 127) / 128, Mr / 128, batch), blk(256);
        if (bmode == 0)
            mgemm_k<0><<<g, blk, 0, stream>>>(A, lda, sA, Bm, ldb, sB, Mr, Nc, Kd,
                alpha, bdiag, bda, convk, epi, Cf, sC, ldc, Cb, bias, Qo, Ko, Vo);
        else
            mgemm_k<1><<<g, blk, 0, stream>>>(A, lda, sA, Bm, ldb, sB, Mr, Nc, Kd,
                alpha, bdiag, bda, convk, epi, Cf, sC, ldc, Cb, bias, Qo, Ko, Vo);
    };

    const int DD = DIMC * DIMC;
    // 0. bf16 conversions: padded X, conv weights (transposed), qkv/out weights
    pad_x_kernel<<<(BATCH*XPADN*(DIMC/4) + 255)/256, 256, 0, stream>>>(x, Xpad);
    transpose_w_bf16_kernel<<<(DD*3 + 255)/256, 256, 0, stream>>>(c1w, WTbf,                  3, DD*3);
    transpose_w_bf16_kernel<<<(DD*5 + 255)/256, 256, 0, stream>>>(c2w, WTbf + (long long)3*DD, 5, DD*5);
    transpose_w_bf16_kernel<<<(DD*7 + 255)/256, 256, 0, stream>>>(c3w, WTbf + (long long)8*DD, 7, DD*7);
    cvt_bf16_kernel<<<(3*DD/4 + 255)/256, 256, 0, stream>>>(qkvw, qkvwb, 3*DD/4);
    cvt_bf16_kernel<<<(DD/4 + 255)/256, 256, 0, stream>>>(outw, outwb, DD/4);

    // 1-3. conv branches (implicit im2col MFMA GEMM) -> OUT_ACC
    const float* cbs[3] = {c1b, c2b, c3b};
    const int    cks[3] = {3, 5, 7};
    const long long coff[3] = {0, (long long)3*DD, (long long)8*DD};
    for (int ci = 0; ci < 3; ++ci) {
        int K = cks[ci];
        mg(0, Xpad, DIMC, 0, WTbf + coff[ci], K*DIMC, 0, ROWS, DIMC, K*DIMC,
           1.f, 0, 0.f, K, 0, CONVY, 0, DIMC, nullptr, nullptr, nullptr, nullptr, nullptr, 1);
        ln_relu_add_kernel<<<ROWS, 256, 0, stream>>>(CONVY, cbs[ci], nw, nb, x, OUT_ACC, ci == 0);
    }

    // 4. T = ln(OUT_ACC, tnorm) -> bf16 (aliases Xpad; conv phase done)
    ln_kernel<<<ROWS, 256, 0, stream>>>(OUT_ACC, tw, tb, nullptr, Tbf);

    // 5. QKV projection, head-scatter epilogue -> Qbf/Kbf/Vbf (q scaled)
    mg(0, Tbf, DIMC, 0, qkvwb, DIMC, 0, ROWS, 3*DIMC, DIMC,
       1.f, 0, 0.f, 0, 3, nullptr, 0, 0, nullptr, nullptr, Qbf, Kbf, Vbf, 1);

    // 6. landmarks (f32 for sim2, bf16 for fused attn)
    landmark_kernel<<<(MD + 255)/256, 256, 0, stream>>>(Qbf, QLf, QLbf);
    landmark_kernel<<<(MD + 255)/256, 256, 0, stream>>>(Kbf, KLf, KLbf);

    const long long sMD = (long long)ML*DHD, sMM = (long long)ML*ML,
                    sND = (long long)SEQN*DHD;

    // 7. sim2 (small fp32 GEMM) + softmax -> A2f
    {
        dim3 g(6, 6, BHN), blk(256);
        gemm_k<true><<<g, blk, 0, stream>>>(QLf, DHD, sMD, KLf, DHD, sMD, A2f, ML, sMM,
                                            ML, ML, DHD);
    }
    softmax_rows<<<BHN*ML, 256, 0, stream>>>(A2f, ML);

    // 8. pinv init: z0 = attn2^T / (max_rowsum * max_colsum); A2 -> bf16
    init_scalars_kernel<<<1, 64, 0, stream>>>(SC);
    rowsum_max_kernel<<<(BHN*ML + 255)/256, 256, 0, stream>>>(A2f, SC);
    colsum_max_kernel<<<(BHN*ML + 255)/256, 256, 0, stream>>>(A2f, SC);
    z0_kernel<<<(MM_ + 255)/256, 256, 0, stream>>>(A2f, SC, Zabf);
    cvt_bf16_kernel<<<(MM_/4 + 255)/256, 256, 0, stream>>>(A2f, A2bf, MM_/4);

    // 9. Newton-Schulz x6 (bf16 MFMA): z = 0.25 z (13I - xz(15I - xz(7I - xz)))
    unsigned short* Zc = Zabf; unsigned short* Zn = Zbbf;
    for (int it = 0; it < 6; ++it) {
        mg(1, A2bf, ML, sMM, Zc,  ML, sMM, ML, ML, ML, 1.f,  0, 0.f,  0, 2,
           nullptr, sMM, ML, XZbf, nullptr, nullptr, nullptr, nullptr, BHN);
        mg(1, XZbf, ML, sMM, XZbf, ML, sMM, ML, ML, ML, 1.f,  1, 7.f,  0, 2,
           nullptr, sMM, ML, Zn,   nullptr, nullptr, nullptr, nullptr, BHN);
        mg(1, XZbf, ML, sMM, Zn,  ML, sMM, ML, ML, ML, 1.f,  1, 15.f, 0, 2,
           nullptr, sMM, ML, T1bf, nullptr, nullptr, nullptr, nullptr, BHN);
        mg(1, Zc,   ML, sMM, T1bf, ML, sMM, ML, ML, ML, 0.25f, 1, 13.f, 0, 2,
           nullptr, sMM, ML, Zn,   nullptr, nullptr, nullptr, nullptr, BHN);
        unsigned short* t = Zc; Zc = Zn; Zn = t;
    }

    // 10. R3 = softmax(QL K^T) @ V  (fused flash, bf16 out)
    {
        dim3 g(ML/FA_ROWS, 1, BHN), blk(256);
        attn_fused_k<1><<<g, blk, 0, stream>>>(QLbf, sMD, Kbf, sND, Vbf, sND, SEQN,
                                               nullptr, R3bf, sMD);
    }

    // 11. W2 = pinv(attn2) @ R3  (bf16 MFMA, N=96)
    mg(1, Zc, ML, sMM, R3bf, DHD, sMD, ML, DHD, ML, 1.f, 0, 0.f, 0, 2,
       nullptr, sMD, DHD, W2bf, nullptr, nullptr, nullptr, nullptr, BHN);

    // 12. AO = softmax(Q KL^T) @ W2  (fused flash, f32 out)
    {
        dim3 g(SEQN/FA_ROWS, 1, BHN), blk(256);
        attn_fused_k<0><<<g, blk, 0, stream>>>(Qbf, sND, KLbf, sMD, W2bf, sMD, ML,
                                               AOf, nullptr, sND);
    }

    // 13. residual depthwise conv on V -> AOf
    resconv_kernel<<<(BND + 255)/256, 256, 0, stream>>>(Vbf, rcw, AOf);

    // 14. [B,H,N,Dh] -> [B,N,D] bf16 (CTbf aliases Kbf)
    concat_heads_kernel<<<(BND + 255)/256, 256, 0, stream>>>(AOf, CTbf);

    // 15. out projection + bias, accumulate into OUT_ACC (outer residual)
    mg(0, CTbf, DIMC, 0, outwb, DIMC, 0, ROWS, DIMC, DIMC,
       1.f, 0, 0.f, 0, 1, OUT_ACC, 0, DIMC, nullptr, outb, nullptr, nullptr, nullptr, 1);

    // 16. final layernorm -> d_out
    ln_kernel<<<ROWS, 256, 0, stream>>>(OUT_ACC, nw, nb, out, nullptr);
}

// Round 5
// 2402.933 us; speedup vs baseline: 2.1333x; 1.1098x over previous
//
#include <hip/hip_runtime.h>

#define SEQN 3840
#define BATCH 2
#define DIMC 768
#define NH 8
#define DHD 96
#define ML 384
#define LW 10
#define BHN 16
#define ROWS (BATCH*SEQN)
#define PADX 4
#define XPADN (SEQN + 2*PADX)   // 3848

static const int BND = BATCH*SEQN*DIMC;   // 5,898,240
static const int MD  = BHN*ML*DHD;        // 589,824
static const int MM_ = BHN*ML*ML;         // 2,359,296

// ---------------- bf16 helpers ----------------
__device__ __forceinline__ unsigned short f2bf(float f) {
    unsigned int u = __float_as_uint(f);
    u = (u + 0x7FFF + ((u >> 16) & 1)) >> 16;   // RNE
    return (unsigned short)u;
}
__device__ __forceinline__ float bf2f(unsigned short s) {
    return __uint_as_float(((unsigned int)s) << 16);
}

// ---------------- reductions ----------------
__device__ __forceinline__ float wave_sum(float v) {
#pragma unroll
    for (int m = 32; m; m >>= 1) v += __shfl_xor(v, m, 64);
    return v;
}
__device__ __forceinline__ float wave_max(float v) {
#pragma unroll
    for (int m = 32; m; m >>= 1) v = fmaxf(v, __shfl_xor(v, m, 64));
    return v;
}

// ================= bf16 MFMA GEMM =================
// C = alpha * A @ B' ; A bf16 [Mr][Kd] (or implicit conv im2col of padded X)
// BMODE 0 (BT): B' from B[N][K] row-major (rows along K)
// BMODE 1 (NN): B' from B[K][N] row-major; optional bdiag: B'[k][j] = (k==j?bda:0)-B[k][j]
// epi: 0 = f32 store; 1 = f32 C += v + bias; 2 = bf16 store; 3 = QKV head-scatter (bf16)
typedef short bf16x8 __attribute__((ext_vector_type(8)));
typedef float f32x4 __attribute__((ext_vector_type(4)));
#define ROWP 40   // LDS row pitch in shorts (80 B: 16B-aligned, 2-way-max bank pattern)

template<int BMODE>
__global__ __launch_bounds__(256) void mgemm_k(
    const unsigned short* __restrict__ A, int lda, long long sA,
    const unsigned short* __restrict__ Bm, int ldb, long long sB,
    int Mr, int Nc, int Kd, float alpha, int bdiag, float bda, int conv_k,
    int epi, float* __restrict__ Cf, long long sC, int ldc,
    unsigned short* __restrict__ Cb, const float* __restrict__ bias,
    unsigned short* __restrict__ Qo, unsigned short* __restrict__ Ko,
    unsigned short* __restrict__ Vo)
{
    __shared__ unsigned short As[128*ROWP] __attribute__((aligned(16)));
    __shared__ unsigned short Bs[128*ROWP] __attribute__((aligned(16)));
    const int bz = blockIdx.z;
    const long long aoff = (long long)bz * sA, boff = (long long)bz * sB;
    const long long coff = (long long)bz * sC;
    const int i0 = blockIdx.y * 128, j0 = blockIdx.x * 128;
    const int tid = threadIdx.x;
    const int w = tid >> 6, l = tid & 63;
    const int wr = (w >> 1) << 6, wc = (w & 1) << 6;
    const int lr = l & 15, lk = l >> 4;
    const int khalf = conv_k >> 1;

    f32x4 acc[4][4] = {};

    for (int k0 = 0; k0 < Kd; k0 += 32) {
        // ---- stage A: 128 rows x 32 shorts ----
#pragma unroll
        for (int pass = 0; pass < 2; ++pass) {
            const int flat = tid + pass * 256;
            const int row = flat >> 2, seg = (flat & 3) << 3;
            long long ga;
            if (conv_k) {
                const int gi = i0 + row;
                const int b = gi / SEQN, n = gi - b * SEQN;
                const int tap = k0 / DIMC, c = k0 - tap * DIMC;
                ga = ((long long)(b * XPADN + n + tap + PADX - khalf)) * DIMC + c + seg;
            } else {
                ga = aoff + (long long)(i0 + row) * lda + k0 + seg;
            }
            *(uint4*)&As[row * ROWP + seg] = *(const uint4*)&A[ga];
        }
        // ---- stage B into Bs[col][k] ----
        if (BMODE == 0) {
#pragma unroll
            for (int pass = 0; pass < 2; ++pass) {
                const int flat = tid + pass * 256;
                const int row = flat >> 2, seg = (flat & 3) << 3;
                const int gj = j0 + row;
                uint4 v;
                if (gj < Nc) v = *(const uint4*)&Bm[boff + (long long)gj * ldb + k0 + seg];
                else { v.x = v.y = v.z = v.w = 0u; }
                *(uint4*)&Bs[row * ROWP + seg] = v;
            }
        } else {
            // vectorized: thread (kk, j16) loads 16 contiguous j's of row gk
            const int kk  = tid >> 3;           // 0..31
            const int j16 = (tid & 7) << 4;     // 0,16,...,112
            const int gk  = k0 + kk;
            const int gj0 = j0 + j16;
            unsigned short buf[16];
            if (gj0 + 16 <= Nc) {
                const unsigned short* bp = &Bm[boff + (long long)gk * ldb + gj0];
                *(uint4*)&buf[0] = *(const uint4*)bp;
                *(uint4*)&buf[8] = *(const uint4*)(bp + 8);
                if (bdiag) {
#pragma unroll
                    for (int u = 0; u < 16; ++u) {
                        float v = ((gk == gj0 + u) ? bda : 0.f) - bf2f(buf[u]);
                        buf[u] = f2bf(v);
                    }
                }
            } else {
#pragma unroll
                for (int u = 0; u < 16; ++u) buf[u] = 0;
            }
#pragma unroll
            for (int u = 0; u < 16; ++u)
                Bs[(j16 + u) * ROWP + kk] = buf[u];
        }
        __syncthreads();
        // ---- compute: each wave 64x64 via 16 MFMA 16x16x32 ----
        bf16x8 af[4], bfv[4];
#pragma unroll
        for (int fi = 0; fi < 4; ++fi)
            af[fi] = *(const bf16x8*)&As[(wr + fi * 16 + lr) * ROWP + lk * 8];
#pragma unroll
        for (int fj = 0; fj < 4; ++fj)
            bfv[fj] = *(const bf16x8*)&Bs[(wc + fj * 16 + lr) * ROWP + lk * 8];
#pragma unroll
        for (int fi = 0; fi < 4; ++fi)
#pragma unroll
            for (int fj = 0; fj < 4; ++fj)
                acc[fi][fj] = __builtin_amdgcn_mfma_f32_16x16x32_bf16(
                    af[fi], bfv[fj], acc[fi][fj], 0, 0, 0);
        __syncthreads();
    }
    // ---- epilogue ----
#pragma unroll
    for (int fi = 0; fi < 4; ++fi) {
#pragma unroll
        for (int fj = 0; fj < 4; ++fj) {
            const int col = j0 + wc + fj * 16 + lr;
            if (col >= Nc) continue;
#pragma unroll
            for (int r = 0; r < 4; ++r) {
                const int row = i0 + wr + fi * 16 + lk * 4 + r;
                float v = acc[fi][fj][r] * alpha;
                if (epi == 0) {
                    Cf[coff + (long long)row * ldc + col] = v;
                } else if (epi == 1) {
                    const long long ix = coff + (long long)row * ldc + col;
                    Cf[ix] = Cf[ix] + v + bias[col];
                } else if (epi == 2) {
                    Cb[coff + (long long)row * ldc + col] = f2bf(v);
                } else {
                    const int which = col / DIMC;
                    const int c = col - which * DIMC;
                    const int h = c / DHD, d = c - h * DHD;
                    const int b = row / SEQN, n = row - b * SEQN;
                    const long long o = (((long long)(b * NH + h)) * SEQN + n) * DHD + d;
                    if (which == 0)      Qo[o] = f2bf(v * 0.10206207261596575f);
                    else if (which == 1) Ko[o] = f2bf(v);
                    else                 Vo[o] = f2bf(v);
                }
            }
        }
    }
}

// ---------------- fp32 tiled GEMM (kept for small sim2) ----------------
template<bool BT>
__global__ __launch_bounds__(256) void gemm_k(
    const float* __restrict__ A, int lda, long long sA,
    const float* __restrict__ Bm, int ldb, long long sB,
    float* __restrict__ C, int ldc, long long sC,
    int Mr, int Nc, int Kd)
{
    __shared__ float As[16][64];
    __shared__ float Bs[16][64];
    const int bz = blockIdx.z;
    A += (long long)bz * sA; Bm += (long long)bz * sB; C += (long long)bz * sC;
    const int i0 = blockIdx.y * 64, j0 = blockIdx.x * 64;
    const int tid = threadIdx.x;
    const int tx = tid & 15, ty = tid >> 4;
    const int srow = tid >> 2, skk = (tid & 3) << 2;
    const int gi = i0 + srow;
    const float* aptr = (gi < Mr) ? A + (long long)gi * lda : nullptr;
    const float* bptr = nullptr;
    {
        int gj = j0 + srow;
        if (gj < Nc) bptr = Bm + (long long)gj * ldb;
    }
    float acc[4][4] = {};
    for (int k0 = 0; k0 < Kd; k0 += 16) {
        float4 av = make_float4(0.f,0.f,0.f,0.f);
        if (aptr) av = *(const float4*)(aptr + k0 + skk);
        As[skk+0][srow]=av.x; As[skk+1][srow]=av.y; As[skk+2][srow]=av.z; As[skk+3][srow]=av.w;
        float4 bv = make_float4(0.f,0.f,0.f,0.f);
        if (bptr) bv = *(const float4*)(bptr + k0 + skk);
        Bs[skk+0][srow]=bv.x; Bs[skk+1][srow]=bv.y; Bs[skk+2][srow]=bv.z; Bs[skk+3][srow]=bv.w;
        __syncthreads();
#pragma unroll
        for (int kk = 0; kk < 16; ++kk) {
            const float4 a4 = *(const float4*)&As[kk][ty << 2];
            const float4 b4 = *(const float4*)&Bs[kk][tx << 2];
            acc[0][0]+=a4.x*b4.x; acc[0][1]+=a4.x*b4.y; acc[0][2]+=a4.x*b4.z; acc[0][3]+=a4.x*b4.w;
            acc[1][0]+=a4.y*b4.x; acc[1][1]+=a4.y*b4.y; acc[1][2]+=a4.y*b4.z; acc[1][3]+=a4.y*b4.w;
            acc[2][0]+=a4.z*b4.x; acc[2][1]+=a4.z*b4.y; acc[2][2]+=a4.z*b4.z; acc[2][3]+=a4.z*b4.w;
            acc[3][0]+=a4.w*b4.x; acc[3][1]+=a4.w*b4.y; acc[3][2]+=a4.w*b4.z; acc[3][3]+=a4.w*b4.w;
        }
        __syncthreads();
    }
#pragma unroll
    for (int ii = 0; ii < 4; ++ii) {
        int go = i0 + (ty << 2) + ii;
        if (go >= Mr) continue;
#pragma unroll
        for (int jj = 0; jj < 4; ++jj) {
            int gj = j0 + (tx << 2) + jj;
            if (gj >= Nc) continue;
            C[(long long)go * ldc + gj] = acc[ii][jj];
        }
    }
}

// ---------------- fused softmax(Q K^T) @ V (flash-style; bf16 in, f32 math) ----------------
#define FA_ROWS 32
#define FA_KT 64
template<int OBF>   // 1: bf16 output, 0: f32 output
__global__ __launch_bounds__(256) void attn_fused_k(
    const unsigned short* __restrict__ Qm, long long sQ,
    const unsigned short* __restrict__ Km, long long sK,
    const unsigned short* __restrict__ Vm, long long sV, int Nk,
    float* __restrict__ Of, unsigned short* __restrict__ Ob, long long sO)
{
    const int bh = blockIdx.z;
    Qm += (long long)bh * sQ; Km += (long long)bh * sK; Vm += (long long)bh * sV;
    const int r0 = blockIdx.x * FA_ROWS;

    __shared__ float Qs[FA_ROWS][DHD+4];
    __shared__ float Ks[FA_KT][DHD+4];
    __shared__ float Vs[FA_KT][DHD+4];
    __shared__ float Ps[FA_ROWS][FA_KT+1];

    const int tid = threadIdx.x;
    const int row = tid >> 3, j8 = tid & 7;

    for (int idx = tid; idx < FA_ROWS*DHD/4; idx += 256) {
        int e = idx * 4; int r = e / DHD, d = e - r * DHD;
        ushort4 q = *(const ushort4*)&Qm[(long long)(r0 + r) * DHD + d];
        Qs[r][d] = bf2f(q.x); Qs[r][d+1] = bf2f(q.y); Qs[r][d+2] = bf2f(q.z); Qs[r][d+3] = bf2f(q.w);
    }

    float acc[12];
#pragma unroll
    for (int i = 0; i < 12; ++i) acc[i] = 0.f;
    float mrow = -3.4e38f, lrow = 0.f;

    for (int k0 = 0; k0 < Nk; k0 += FA_KT) {
        __syncthreads();
        for (int idx = tid; idx < FA_KT*DHD/4; idx += 256) {
            int e = idx * 4; int r = e / DHD, d = e - r * DHD;
            ushort4 kv = *(const ushort4*)&Km[(long long)(k0 + r) * DHD + d];
            Ks[r][d] = bf2f(kv.x); Ks[r][d+1] = bf2f(kv.y); Ks[r][d+2] = bf2f(kv.z); Ks[r][d+3] = bf2f(kv.w);
            ushort4 vv = *(const ushort4*)&Vm[(long long)(k0 + r) * DHD + d];
            Vs[r][d] = bf2f(vv.x); Vs[r][d+1] = bf2f(vv.y); Vs[r][d+2] = bf2f(vv.z); Vs[r][d+3] = bf2f(vv.w);
        }
        __syncthreads();
        float sc[8];
#pragma unroll
        for (int j = 0; j < 8; ++j) sc[j] = 0.f;
        for (int d = 0; d < DHD; d += 4) {
            const float4 q4 = *(const float4*)&Qs[row][d];
#pragma unroll
            for (int j = 0; j < 8; ++j) {
                const float4 k4 = *(const float4*)&Ks[j8 + (j<<3)][d];
                sc[j] += q4.x*k4.x + q4.y*k4.y + q4.z*k4.z + q4.w*k4.w;
            }
        }
        float mt = sc[0];
#pragma unroll
        for (int j = 1; j < 8; ++j) mt = fmaxf(mt, sc[j]);
#pragma unroll
        for (int m = 1; m < 8; m <<= 1) mt = fmaxf(mt, __shfl_xor(mt, m, 64));
        const float mnew = fmaxf(mrow, mt);
        const float corr = __expf(mrow - mnew);
        float psum = 0.f;
#pragma unroll
        for (int j = 0; j < 8; ++j) {
            float p = __expf(sc[j] - mnew);
            psum += p;
            Ps[row][j8 + (j<<3)] = p;
        }
#pragma unroll
        for (int m = 1; m < 8; m <<= 1) psum += __shfl_xor(psum, m, 64);
        lrow = lrow * corr + psum;
        mrow = mnew;
#pragma unroll
        for (int i = 0; i < 12; ++i) acc[i] *= corr;
        __syncthreads();
#pragma unroll 4
        for (int k = 0; k < FA_KT; ++k) {
            const float p = Ps[row][k];
#pragma unroll
            for (int i = 0; i < 12; ++i)
                acc[i] += p * Vs[k][j8 + (i<<3)];
        }
    }
    const float inv = 1.f / lrow;
    const long long ob = (long long)bh * sO + (long long)(r0 + row) * DHD + j8;
#pragma unroll
    for (int i = 0; i < 12; ++i) {
        if (OBF) Ob[ob + (i<<3)] = f2bf(acc[i] * inv);
        else     Of[ob + (i<<3)] = acc[i] * inv;
    }
}

// ---------------- split-K partial flash attention (for R3) ----------------
#define NCH 6
#define CHKT 640   // keys per chunk (10 tiles of 64); NCH*CHKT = SEQN
__global__ __launch_bounds__(256) void attn_part_k(
    const unsigned short* __restrict__ Qm, long long sQ,
    const unsigned short* __restrict__ Km, long long sK,
    const unsigned short* __restrict__ Vm, long long sV,
    float* __restrict__ Pacc, float* __restrict__ Pm, float* __restrict__ Pl)
{
    const int bh = blockIdx.z, chunk = blockIdx.y;
    Qm += (long long)bh * sQ; Km += (long long)bh * sK; Vm += (long long)bh * sV;
    const int r0 = blockIdx.x * FA_ROWS;

    __shared__ float Qs[FA_ROWS][DHD+4];
    __shared__ float Ks[FA_KT][DHD+4];
    __shared__ float Vs[FA_KT][DHD+4];
    __shared__ float Ps[FA_ROWS][FA_KT+1];

    const int tid = threadIdx.x;
    const int row = tid >> 3, j8 = tid & 7;

    for (int idx = tid; idx < FA_ROWS*DHD/4; idx += 256) {
        int e = idx * 4; int r = e / DHD, d = e - r * DHD;
        ushort4 q = *(const ushort4*)&Qm[(long long)(r0 + r) * DHD + d];
        Qs[r][d] = bf2f(q.x); Qs[r][d+1] = bf2f(q.y); Qs[r][d+2] = bf2f(q.z); Qs[r][d+3] = bf2f(q.w);
    }

    float acc[12];
#pragma unroll
    for (int i = 0; i < 12; ++i) acc[i] = 0.f;
    float mrow = -3.4e38f, lrow = 0.f;

    const int kbeg = chunk * CHKT, kend = kbeg + CHKT;
    for (int k0 = kbeg; k0 < kend; k0 += FA_KT) {
        __syncthreads();
        for (int idx = tid; idx < FA_KT*DHD/4; idx += 256) {
            int e = idx * 4; int r = e / DHD, d = e - r * DHD;
            ushort4 kv = *(const ushort4*)&Km[(long long)(k0 + r) * DHD + d];
            Ks[r][d] = bf2f(kv.x); Ks[r][d+1] = bf2f(kv.y); Ks[r][d+2] = bf2f(kv.z); Ks[r][d+3] = bf2f(kv.w);
            ushort4 vv = *(const ushort4*)&Vm[(long long)(k0 + r) * DHD + d];
            Vs[r][d] = bf2f(vv.x); Vs[r][d+1] = bf2f(vv.y); Vs[r][d+2] = bf2f(vv.z); Vs[r][d+3] = bf2f(vv.w);
        }
        __syncthreads();
        float sc[8];
#pragma unroll
        for (int j = 0; j < 8; ++j) sc[j] = 0.f;
        for (int d = 0; d < DHD; d += 4) {
            const float4 q4 = *(const float4*)&Qs[row][d];
#pragma unroll
            for (int j = 0; j < 8; ++j) {
                const float4 k4 = *(const float4*)&Ks[j8 + (j<<3)][d];
                sc[j] += q4.x*k4.x + q4.y*k4.y + q4.z*k4.z + q4.w*k4.w;
            }
        }
        float mt = sc[0];
#pragma unroll
        for (int j = 1; j < 8; ++j) mt = fmaxf(mt, sc[j]);
#pragma unroll
        for (int m = 1; m < 8; m <<= 1) mt = fmaxf(mt, __shfl_xor(mt, m, 64));
        const float mnew = fmaxf(mrow, mt);
        const float corr = __expf(mrow - mnew);
        float psum = 0.f;
#pragma unroll
        for (int j = 0; j < 8; ++j) {
            float p = __expf(sc[j] - mnew);
            psum += p;
            Ps[row][j8 + (j<<3)] = p;
        }
#pragma unroll
        for (int m = 1; m < 8; m <<= 1) psum += __shfl_xor(psum, m, 64);
        lrow = lrow * corr + psum;
        mrow = mnew;
#pragma unroll
        for (int i = 0; i < 12; ++i) acc[i] *= corr;
        __syncthreads();
#pragma unroll 4
        for (int k = 0; k < FA_KT; ++k) {
            const float p = Ps[row][k];
#pragma unroll
            for (int i = 0; i < 12; ++i)
                acc[i] += p * Vs[k][j8 + (i<<3)];
        }
    }
    const long long pr = ((long long)(bh * NCH + chunk)) * ML + r0 + row;
#pragma unroll
    for (int i = 0; i < 12; ++i)
        Pacc[pr * DHD + j8 + (i<<3)] = acc[i];
    if (j8 == 0) { Pm[pr] = mrow; Pl[pr] = lrow; }
}

// combine partials -> R3 bf16
__global__ __launch_bounds__(256) void combine_r3_k(
    const float* __restrict__ Pacc, const float* __restrict__ Pm,
    const float* __restrict__ Pl, unsigned short* __restrict__ R3, long long sO)
{
    const int bh = blockIdx.z;
    const int r = blockIdx.x * FA_ROWS + (threadIdx.x >> 3);
    const int j8 = threadIdx.x & 7;
    float wgt[NCH];
    float M = -3.4e38f;
#pragma unroll
    for (int c = 0; c < NCH; ++c)
        M = fmaxf(M, Pm[((long long)(bh * NCH + c)) * ML + r]);
    float L = 0.f;
#pragma unroll
    for (int c = 0; c < NCH; ++c) {
        const long long pr = ((long long)(bh * NCH + c)) * ML + r;
        wgt[c] = __expf(Pm[pr] - M);
        L += Pl[pr] * wgt[c];
    }
    const float inv = 1.f / L;
#pragma unroll
    for (int i = 0; i < 12; ++i) {
        const int d = j8 + (i << 3);
        float s = 0.f;
#pragma unroll
        for (int c = 0; c < NCH; ++c)
            s += Pacc[(((long long)(bh * NCH + c)) * ML + r) * DHD + d] * wgt[c];
        R3[(long long)bh * sO + (long long)r * DHD + d] = f2bf(s * inv);
    }
}

// ---------------- LayerNorm (row = 768), dual-dtype output ----------------
__global__ __launch_bounds__(256) void ln_kernel(
    const float* __restrict__ in, const float* __restrict__ w,
    const float* __restrict__ b, float* __restrict__ outf,
    unsigned short* __restrict__ outb)
{
    __shared__ float red[4];
    const long long r = blockIdx.x;
    const float* row = in + r * DIMC;
    const int t = threadIdx.x, lane = t & 63, wid = t >> 6;
    float x0 = row[t], x1 = row[t+256], x2 = row[t+512];
    float s = wave_sum(x0 + x1 + x2);
    if (lane == 0) red[wid] = s;
    __syncthreads();
    float mu = (red[0]+red[1]+red[2]+red[3]) * (1.f/DIMC);
    __syncthreads();
    float d0 = x0-mu, d1 = x1-mu, d2 = x2-mu;
    float q = wave_sum(d0*d0 + d1*d1 + d2*d2);
    if (lane == 0) red[wid] = q;
    __syncthreads();
    float rs = rsqrtf((red[0]+red[1]+red[2]+red[3]) * (1.f/DIMC) + 1e-5f);
    float v0 = d0*rs*w[t]     + b[t];
    float v1 = d1*rs*w[t+256] + b[t+256];
    float v2 = d2*rs*w[t+512] + b[t+512];
    if (outf) {
        float* o = outf + r * DIMC;
        o[t] = v0; o[t+256] = v1; o[t+512] = v2;
    }
    if (outb) {
        unsigned short* o = outb + r * DIMC;
        o[t] = f2bf(v0); o[t+256] = f2bf(v1); o[t+512] = f2bf(v2);
    }
}

// conv-branch epilogue: acc = (init ? x : acc) + relu(ln(y+cb))
__global__ __launch_bounds__(256) void ln_relu_add_kernel(
    const float* __restrict__ Y, const float* __restrict__ cb,
    const float* __restrict__ w, const float* __restrict__ b,
    const float* __restrict__ xin, float* __restrict__ acc, int init)
{
    __shared__ float red[4];
    const long long r = blockIdx.x;
    const float* row = Y + r * DIMC;
    const int t = threadIdx.x, lane = t & 63, wid = t >> 6;
    float x0 = row[t]     + cb[t];
    float x1 = row[t+256] + cb[t+256];
    float x2 = row[t+512] + cb[t+512];
    float s = wave_sum(x0 + x1 + x2);
    if (lane == 0) red[wid] = s;
    __syncthreads();
    float mu = (red[0]+red[1]+red[2]+red[3]) * (1.f/DIMC);
    __syncthreads();
    float d0 = x0-mu, d1 = x1-mu, d2 = x2-mu;
    float q = wave_sum(d0*d0 + d1*d1 + d2*d2);
    if (lane == 0) red[wid] = q;
    __syncthreads();
    float rs = rsqrtf((red[0]+red[1]+red[2]+red[3]) * (1.f/DIMC) + 1e-5f);
    float v0 = fmaxf(d0*rs*w[t]     + b[t],     0.f);
    float v1 = fmaxf(d1*rs*w[t+256] + b[t+256], 0.f);
    float v2 = fmaxf(d2*rs*w[t+512] + b[t+512], 0.f);
    float* arow = acc + r * DIMC;
    if (init) {
        const float* xr = xin + r * DIMC;
        arow[t]     = xr[t]     + v0;
        arow[t+256] = xr[t+256] + v1;
        arow[t+512] = xr[t+512] + v2;
    } else {
        arow[t]     += v0;
        arow[t+256] += v1;
        arow[t+512] += v2;
    }
}

// ---------------- row softmax (in-place, W=384) ----------------
__global__ __launch_bounds__(256) void softmax_rows(float* __restrict__ data, int W)
{
    __shared__ float red[4];
    const long long r = blockIdx.x;
    float* row = data + r * (long long)W;
    const int t = threadIdx.x, lane = t & 63, wid = t >> 6;
    float mx = -3.4e38f;
    for (int j = t; j < W; j += 256) mx = fmaxf(mx, row[j]);
    mx = wave_max(mx);
    if (lane == 0) red[wid] = mx;
    __syncthreads();
    mx = fmaxf(fmaxf(red[0], red[1]), fmaxf(red[2], red[3]));
    __syncthreads();
    float s = 0.f;
    for (int j = t; j < W; j += 256) s += __expf(row[j] - mx);
    s = wave_sum(s);
    if (lane == 0) red[wid] = s;
    __syncthreads();
    s = red[0]+red[1]+red[2]+red[3];
    const float inv = 1.f / s;
    for (int j = t; j < W; j += 256) row[j] = __expf(row[j] - mx) * inv;
}

// ---------------- small helpers ----------------
__global__ void pad_x_kernel(const float* __restrict__ x, unsigned short* __restrict__ xp)
{
    int i = blockIdx.x * 256 + threadIdx.x;
    if (i >= BATCH * XPADN * (DIMC/4)) return;
    int e = i * 4;
    int c = e % DIMC; int rr = e / DIMC; int pr = rr % XPADN; int b = rr / XPADN;
    int n = pr - PADX;
    ushort4 o;
    if (n < 0 || n >= SEQN) { o.x = o.y = o.z = o.w = 0; }
    else {
        float4 v = *(const float4*)&x[((long long)(b * SEQN + n)) * DIMC + c];
        o.x = f2bf(v.x); o.y = f2bf(v.y); o.z = f2bf(v.z); o.w = f2bf(v.w);
    }
    *(ushort4*)&xp[e] = o;
}

// conv weight [O][I][K] -> bf16 [O][K][I]
__global__ void transpose_w_bf16_kernel(const float* __restrict__ W,
                                        unsigned short* __restrict__ WT, int K, int total)
{
    int idx = blockIdx.x * 256 + threadIdx.x;
    if (idx >= total) return;
    int i = idx % DIMC; int t = idx / DIMC; int k = t % K; int o = t / K;
    WT[idx] = f2bf(W[((long long)o * DIMC + i) * K + k]);
}

__global__ void cvt_bf16_kernel(const float* __restrict__ src,
                                unsigned short* __restrict__ dst, int n4)
{
    int i = blockIdx.x * 256 + threadIdx.x;
    if (i >= n4) return;
    float4 v = ((const float4*)src)[i];
    ushort4 o; o.x = f2bf(v.x); o.y = f2bf(v.y); o.z = f2bf(v.z); o.w = f2bf(v.w);
    ((ushort4*)dst)[i] = o;
}

__global__ void landmark_kernel(const unsigned short* __restrict__ src,
                                float* __restrict__ dstf, unsigned short* __restrict__ dstb)
{
    int idx = blockIdx.x * 256 + threadIdx.x;
    if (idx >= MD) return;
    int d = idx % DHD; int rem = idx / DHD; int m = rem % ML; int bh = rem / ML;
    const unsigned short* p = src + ((long long)bh * SEQN + m * LW) * DHD + d;
    float s = 0.f;
#pragma unroll
    for (int j = 0; j < LW; ++j) s += bf2f(p[(long long)j * DHD]);
    s *= (1.f / LW);
    dstf[idx] = s;
    dstb[idx] = f2bf(s);
}

__global__ void init_scalars_kernel(float* sc)
{
    if (blockIdx.x == 0 && threadIdx.x < 2) sc[threadIdx.x] = 0.f;
}
__global__ void rowsum_max_kernel(const float* __restrict__ A2, float* sc)
{
    int r = blockIdx.x * 256 + threadIdx.x;
    if (r >= BHN * ML) return;
    const float* row = A2 + (long long)r * ML;
    float s = 0.f;
    for (int j = 0; j < ML; ++j) s += fabsf(row[j]);
    atomicMax((unsigned int*)(sc + 0), __float_as_uint(s));
}
__global__ void colsum_max_kernel(const float* __restrict__ A2, float* sc)
{
    int idx = blockIdx.x * 256 + threadIdx.x;
    if (idx >= BHN * ML) return;
    int j = idx % ML, bh = idx / ML;
    const float* base = A2 + (long long)bh * ML * ML + j;
    float s = 0.f;
    for (int i = 0; i < ML; ++i) s += fabsf(base[(long long)i * ML]);
    atomicMax((unsigned int*)(sc + 1), __float_as_uint(s));
}
__global__ void z0_kernel(const float* __restrict__ A2, const float* __restrict__ sc,
                          unsigned short* __restrict__ Z)
{
    long long idx = (long long)blockIdx.x * 256 + threadIdx.x;
    if (idx >= (long long)MM_) return;
    int j = idx % ML; long long rem = idx / ML; int i = (int)(rem % ML); long long bh = rem / ML;
    float inv = 1.f / (sc[0] * sc[1]);
    Z[idx] = f2bf(A2[(bh * ML + j) * ML + i] * inv);
}

__global__ void resconv_kernel(const unsigned short* __restrict__ V,
                               const float* __restrict__ RW, float* __restrict__ AO)
{
    int idx = blockIdx.x * 256 + threadIdx.x;
    if (idx >= BND) return;
    int d = idx % DHD; int rem = idx / DHD; int n = rem % SEQN; int bh = rem / SEQN;
    int h = bh % NH;
    const unsigned short* vb = V + (long long)bh * SEQN * DHD + d;
    float s = 0.f;
#pragma unroll
    for (int j = 0; j < 33; ++j) {
        int sn = n + j - 16;
        if (sn >= 0 && sn < SEQN) s += bf2f(vb[(long long)sn * DHD]) * RW[h * 33 + j];
    }
    AO[idx] += s;
}

__global__ void concat_heads_kernel(const float* __restrict__ AO,
                                    unsigned short* __restrict__ CT)
{
    int idx = blockIdx.x * 256 + threadIdx.x;
    if (idx >= BND) return;
    int d = idx % DHD; int rem = idx / DHD; int n = rem % SEQN; int bh = rem / SEQN;
    int h = bh % NH, b = bh / NH;
    CT[((long long)(b * SEQN + n)) * DIMC + h * DHD + d] = f2bf(AO[idx]);
}

__global__ void sentinel_kernel(float* __restrict__ out, int n)
{
    int i = blockIdx.x * 256 + threadIdx.x;
    if (i < n) out[i] = 1.0e6f;
}

// ---------------- host ----------------
extern "C" void kernel_launch(void* const* d_in, const int* in_sizes, int n_in,
                              void* d_out, int out_size, void* d_ws, size_t ws_size,
                              hipStream_t stream)
{
    (void)in_sizes; (void)n_in;
    const float* x    = (const float*)d_in[0];
    const float* c1w  = (const float*)d_in[1];
    const float* c1b  = (const float*)d_in[2];
    const float* c2w  = (const float*)d_in[3];
    const float* c2b  = (const float*)d_in[4];
    const float* c3w  = (const float*)d_in[5];
    const float* c3b  = (const float*)d_in[6];
    const float* nw   = (const float*)d_in[7];
    const float* nb   = (const float*)d_in[8];
    const float* tw   = (const float*)d_in[9];
    const float* tb   = (const float*)d_in[10];
    const float* qkvw = (const float*)d_in[11];
    const float* outw = (const float*)d_in[12];
    const float* outb = (const float*)d_in[13];
    const float* rcw  = (const float*)d_in[14];
    float* out = (float*)d_out;
    float* ws  = (float*)d_ws;

    // ---------- workspace layout (float units; bf16 buffers carved as ushort*) ----------
    const int POOLA_F = 7378944;   // Xpad(5,910,528sh)+WTbf(8,847,360sh); Tbf aliases Xpad
    const int POOLB_F = 8847360;   // Qbf/Kbf/Vbf (BND sh each); CONVY f32 alias; CTbf aliases Kbf
    const int POOLC_F = 3538944;   // qkvw/outw/A2bf/R3bf/QLbf/KLbf/W2bf
    float* OUT_ACC = ws;                          // BND f32
    float* A2f  = OUT_ACC + BND;                  // MM_ f32; reused as XZbf+T1bf after z0
    float* QLf  = A2f + MM_;                      // MD f32
    float* KLf  = QLf + MD;                       // MD f32
    float* Zab  = KLf + MD;                       // MM_ f32 (= Za_bf + Zb_bf shorts)
    float* AOf  = Zab + MM_;                      // BND f32 (also split-K partials, pre-step-12)
    float* poolA = AOf + BND;
    float* poolB = poolA + POOLA_F;
    float* poolC = poolB + POOLB_F;
    float* SC   = poolC + POOLC_F;                // 16 f32

    unsigned short* Xpad  = (unsigned short*)poolA;          // [2][3848][768]
    unsigned short* WTbf  = Xpad + BATCH*XPADN*DIMC;         // 8,847,360 sh
    unsigned short* Tbf   = Xpad;                            // alias (post-conv)
    float*          CONVY = poolB;                           // f32 alias (conv phase)
    unsigned short* Qbf   = (unsigned short*)poolB;          // BND sh
    unsigned short* Kbf   = Qbf + BND;
    unsigned short* Vbf   = Kbf + BND;
    unsigned short* CTbf  = Kbf;                             // alias (post-attn)
    unsigned short* qkvwb = (unsigned short*)poolC;          // 1,769,472 sh
    unsigned short* outwb = qkvwb + 3*DIMC*DIMC;             // 589,824 sh
    unsigned short* A2bf  = outwb + DIMC*DIMC;               // MM_ sh
    unsigned short* R3bf  = A2bf + MM_;                      // MD sh
    unsigned short* QLbf  = R3bf + MD;                       // MD sh
    unsigned short* KLbf  = QLbf + MD;                       // MD sh
    unsigned short* W2bf  = KLbf + MD;                       // MD sh
    unsigned short* XZbf  = (unsigned short*)A2f;            // MM_ sh (A2f dead post-z0/cvt)
    unsigned short* T1bf  = XZbf + MM_;
    unsigned short* Zabf  = (unsigned short*)Zab;
    unsigned short* Zbbf  = Zabf + MM_;
    // split-K partials (in AOf region, consumed before step 12 writes AOf)
    float* Pacc = AOf;                                       // 16*6*384*96 = 3,538,944 f32
    float* Pm   = Pacc + BHN*NCH*ML*DHD;                     // 36,864 f32
    float* Pl   = Pm + BHN*NCH*ML;                           // 36,864 f32

    size_t need_bytes = (size_t)(SC + 16 - ws) * sizeof(float);
    if (ws_size < need_bytes) {
        sentinel_kernel<<<(out_size + 255)/256, 256, 0, stream>>>(out, out_size);
        return;
    }

    auto mg = [&](int bmode, const unsigned short* A, int lda, long long sA,
                  const unsigned short* Bm, int ldb, long long sB,
                  int Mr, int Nc, int Kd, float alpha, int bdiag, float bda, int convk,
                  int epi, float* Cf, long long sC, int ldc, unsigned short* Cb,
                  const float* bias, unsigned short* Qo, unsigned short* Ko,
                  unsigned short* Vo, int batch) {
        dim3 g((Nc + 127) / 128, Mr / 128, batch), blk(256);
        if (bmode == 0)
            mgemm_k<0><<<g, blk, 0, stream>>>(A, lda, sA, Bm, ldb, sB, Mr, Nc, Kd,
                alpha, bdiag, bda, convk, epi, Cf, sC, ldc, Cb, bias, Qo, Ko, Vo);
        else
            mgemm_k<1><<<g, blk, 0, stream>>>(A, lda, sA, Bm, ldb, sB, Mr, Nc, Kd,
                alpha, bdiag, bda, convk, epi, Cf, sC, ldc, Cb, bias, Qo, Ko, Vo);
    };

    const int DD = DIMC * DIMC;
    // 0. bf16 conversions: padded X, conv weights (transposed), qkv/out weights
    pad_x_kernel<<<(BATCH*XPADN*(DIMC/4) + 255)/256, 256, 0, stream>>>(x, Xpad);
    transpose_w_bf16_kernel<<<(DD*3 + 255)/256, 256, 0, stream>>>(c1w, WTbf,                  3, DD*3);
    transpose_w_bf16_kernel<<<(DD*5 + 255)/256, 256, 0, stream>>>(c2w, WTbf + (long long)3*DD, 5, DD*5);
    transpose_w_bf16_kernel<<<(DD*7 + 255)/256, 256, 0, stream>>>(c3w, WTbf + (long long)8*DD, 7, DD*7);
    cvt_bf16_kernel<<<(3*DD/4 + 255)/256, 256, 0, stream>>>(qkvw, qkvwb, 3*DD/4);
    cvt_bf16_kernel<<<(DD/4 + 255)/256, 256, 0, stream>>>(outw, outwb, DD/4);

    // 1-3. conv branches (implicit im2col MFMA GEMM) -> OUT_ACC
    const float* cbs[3] = {c1b, c2b, c3b};
    const int    cks[3] = {3, 5, 7};
    const long long coff[3] = {0, (long long)3*DD, (long long)8*DD};
    for (int ci = 0; ci < 3; ++ci) {
        int K = cks[ci];
        mg(0, Xpad, DIMC, 0, WTbf + coff[ci], K*DIMC, 0, ROWS, DIMC, K*DIMC,
           1.f, 0, 0.f, K, 0, CONVY, 0, DIMC, nullptr, nullptr, nullptr, nullptr, nullptr, 1);
        ln_relu_add_kernel<<<ROWS, 256, 0, stream>>>(CONVY, cbs[ci], nw, nb, x, OUT_ACC, ci == 0);
    }

    // 4. T = ln(OUT_ACC, tnorm) -> bf16 (aliases Xpad; conv phase done)
    ln_kernel<<<ROWS, 256, 0, stream>>>(OUT_ACC, tw, tb, nullptr, Tbf);

    // 5. QKV projection, head-scatter epilogue -> Qbf/Kbf/Vbf (q scaled)
    mg(0, Tbf, DIMC, 0, qkvwb, DIMC, 0, ROWS, 3*DIMC, DIMC,
       1.f, 0, 0.f, 0, 3, nullptr, 0, 0, nullptr, nullptr, Qbf, Kbf, Vbf, 1);

    // 6. landmarks (f32 for sim2, bf16 for fused attn)
    landmark_kernel<<<(MD + 255)/256, 256, 0, stream>>>(Qbf, QLf, QLbf);
    landmark_kernel<<<(MD + 255)/256, 256, 0, stream>>>(Kbf, KLf, KLbf);

    const long long sMD = (long long)ML*DHD, sMM = (long long)ML*ML,
                    sND = (long long)SEQN*DHD;

    // 7. sim2 (small fp32 GEMM) + softmax -> A2f
    {
        dim3 g(6, 6, BHN), blk(256);
        gemm_k<true><<<g, blk, 0, stream>>>(QLf, DHD, sMD, KLf, DHD, sMD, A2f, ML, sMM,
                                            ML, ML, DHD);
    }
    softmax_rows<<<BHN*ML, 256, 0, stream>>>(A2f, ML);

    // 8. pinv init: z0 = attn2^T / (max_rowsum * max_colsum); A2 -> bf16
    init_scalars_kernel<<<1, 64, 0, stream>>>(SC);
    rowsum_max_kernel<<<(BHN*ML + 255)/256, 256, 0, stream>>>(A2f, SC);
    colsum_max_kernel<<<(BHN*ML + 255)/256, 256, 0, stream>>>(A2f, SC);
    z0_kernel<<<(MM_ + 255)/256, 256, 0, stream>>>(A2f, SC, Zabf);
    cvt_bf16_kernel<<<(MM_/4 + 255)/256, 256, 0, stream>>>(A2f, A2bf, MM_/4);

    // 9. Newton-Schulz x6 (bf16 MFMA): z = 0.25 z (13I - xz(15I - xz(7I - xz)))
    unsigned short* Zc = Zabf; unsigned short* Zn = Zbbf;
    for (int it = 0; it < 6; ++it) {
        mg(1, A2bf, ML, sMM, Zc,  ML, sMM, ML, ML, ML, 1.f,  0, 0.f,  0, 2,
           nullptr, sMM, ML, XZbf, nullptr, nullptr, nullptr, nullptr, BHN);
        mg(1, XZbf, ML, sMM, XZbf, ML, sMM, ML, ML, ML, 1.f,  1, 7.f,  0, 2,
           nullptr, sMM, ML, Zn,   nullptr, nullptr, nullptr, nullptr, BHN);
        mg(1, XZbf, ML, sMM, Zn,  ML, sMM, ML, ML, ML, 1.f,  1, 15.f, 0, 2,
           nullptr, sMM, ML, T1bf, nullptr, nullptr, nullptr, nullptr, BHN);
        mg(1, Zc,   ML, sMM, T1bf, ML, sMM, ML, ML, ML, 0.25f, 1, 13.f, 0, 2,
           nullptr, sMM, ML, Zn,   nullptr, nullptr, nullptr, nullptr, BHN);
        unsigned short* t = Zc; Zc = Zn; Zn = t;
    }

    // 10. R3 = softmax(QL K^T) @ V  — split-K flash (6 chunks) + LSE combine
    {
        dim3 g(ML/FA_ROWS, NCH, BHN), blk(256);
        attn_part_k<<<g, blk, 0, stream>>>(QLbf, sMD, Kbf, sND, Vbf, sND, Pacc, Pm, Pl);
        dim3 gc(ML/FA_ROWS, 1, BHN);
        combine_r3_k<<<gc, blk, 0, stream>>>(Pacc, Pm, Pl, R3bf, sMD);
    }

    // 11. W2 = pinv(attn2) @ R3  (bf16 MFMA, N=96)
    mg(1, Zc, ML, sMM, R3bf, DHD, sMD, ML, DHD, ML, 1.f, 0, 0.f, 0, 2,
       nullptr, sMD, DHD, W2bf, nullptr, nullptr, nullptr, nullptr, BHN);

    // 12. AO = softmax(Q KL^T) @ W2  (fused flash, f32 out; overwrites partials)
    {
        dim3 g(SEQN/FA_ROWS, 1, BHN), blk(256);
        attn_fused_k<0><<<g, blk, 0, stream>>>(Qbf, sND, KLbf, sMD, W2bf, sMD, ML,
                                               AOf, nullptr, sND);
    }

    // 13. residual depthwise conv on V -> AOf
    resconv_kernel<<<(BND + 255)/256, 256, 0, stream>>>(Vbf, rcw, AOf);

    // 14. [B,H,N,Dh] -> [B,N,D] bf16 (CTbf aliases Kbf)
    concat_heads_kernel<<<(BND + 255)/256, 256, 0, stream>>>(AOf, CTbf);

    // 15. out projection + bias, accumulate into OUT_ACC (outer residual)
    mg(0, CTbf, DIMC, 0, outwb, DIMC, 0, ROWS, DIMC, DIMC,
       1.f, 0, 0.f, 0, 1, OUT_ACC, 0, DIMC, nullptr, outb, nullptr, nullptr, nullptr, 1);

    // 16. final layernorm -> d_out
    ln_kernel<<<ROWS, 256, 0, stream>>>(OUT_ACC, nw, nb, out, nullptr);
}

// Round 6
// 2137.200 us; speedup vs baseline: 2.3986x; 1.1243x over previous
//
#include <hip/hip_runtime.h>

#define SEQN 3840
#define BATCH 2
#define DIMC 768
#define NH 8
#define DHD 96
#define ML 384
#define LW 10
#define BHN 16
#define ROWS (BATCH*SEQN)
#define PADX 4
#define XPADN (SEQN + 2*PADX)   // 3848

static const int BND = BATCH*SEQN*DIMC;   // 5,898,240
static const int MD  = BHN*ML*DHD;        // 589,824
static const int MM_ = BHN*ML*ML;         // 2,359,296

// ---------------- bf16 helpers ----------------
__device__ __forceinline__ unsigned short f2bf(float f) {
    unsigned int u = __float_as_uint(f);
    u = (u + 0x7FFF + ((u >> 16) & 1)) >> 16;   // RNE
    return (unsigned short)u;
}
__device__ __forceinline__ float bf2f(unsigned short s) {
    return __uint_as_float(((unsigned int)s) << 16);
}
__device__ __forceinline__ unsigned short f2h(float f) {
    _Float16 h = (_Float16)f;
    return *(unsigned short*)&h;
}
__device__ __forceinline__ float h2f(unsigned short u) {
    _Float16 h = *(_Float16*)&u;
    return (float)h;
}

// ---------------- reductions ----------------
__device__ __forceinline__ float wave_sum(float v) {
#pragma unroll
    for (int m = 32; m; m >>= 1) v += __shfl_xor(v, m, 64);
    return v;
}
__device__ __forceinline__ float wave_max(float v) {
#pragma unroll
    for (int m = 32; m; m >>= 1) v = fmaxf(v, __shfl_xor(v, m, 64));
    return v;
}

// ================= bf16 MFMA GEMM =================
// C = alpha * A @ B' ; A bf16 [Mr][Kd] (or implicit conv im2col of padded X)
// BMODE 0 (BT): B' from B[N][K] row-major (rows along K)
// BMODE 1 (NN): B' from B[K][N] row-major; optional bdiag: B'[k][j] = (k==j?bda:0)-B[k][j]
// epi: 0 = f32 store; 1 = f32 C += v + bias; 2 = bf16 store; 3 = QKV head-scatter (bf16);
//      4 = f16 store
typedef short bf16x8 __attribute__((ext_vector_type(8)));
typedef float f32x4 __attribute__((ext_vector_type(4)));
#define ROWP 40   // LDS row pitch in shorts (80 B: 16B-aligned, 2-way-max bank pattern)

template<int BMODE>
__global__ __launch_bounds__(256) void mgemm_k(
    const unsigned short* __restrict__ A, int lda, long long sA,
    const unsigned short* __restrict__ Bm, int ldb, long long sB,
    int Mr, int Nc, int Kd, float alpha, int bdiag, float bda, int conv_k,
    int epi, float* __restrict__ Cf, long long sC, int ldc,
    unsigned short* __restrict__ Cb, const float* __restrict__ bias,
    unsigned short* __restrict__ Qo, unsigned short* __restrict__ Ko,
    unsigned short* __restrict__ Vo)
{
    __shared__ unsigned short As[128*ROWP] __attribute__((aligned(16)));
    __shared__ unsigned short Bs[128*ROWP] __attribute__((aligned(16)));
    const int bz = blockIdx.z;
    const long long aoff = (long long)bz * sA, boff = (long long)bz * sB;
    const long long coff = (long long)bz * sC;
    const int i0 = blockIdx.y * 128, j0 = blockIdx.x * 128;
    const int tid = threadIdx.x;
    const int w = tid >> 6, l = tid & 63;
    const int wr = (w >> 1) << 6, wc = (w & 1) << 6;
    const int lr = l & 15, lk = l >> 4;
    const int khalf = conv_k >> 1;

    f32x4 acc[4][4] = {};

    for (int k0 = 0; k0 < Kd; k0 += 32) {
        // ---- stage A: 128 rows x 32 shorts ----
#pragma unroll
        for (int pass = 0; pass < 2; ++pass) {
            const int flat = tid + pass * 256;
            const int row = flat >> 2, seg = (flat & 3) << 3;
            long long ga;
            if (conv_k) {
                const int gi = i0 + row;
                const int b = gi / SEQN, n = gi - b * SEQN;
                const int tap = k0 / DIMC, c = k0 - tap * DIMC;
                ga = ((long long)(b * XPADN + n + tap + PADX - khalf)) * DIMC + c + seg;
            } else {
                ga = aoff + (long long)(i0 + row) * lda + k0 + seg;
            }
            *(uint4*)&As[row * ROWP + seg] = *(const uint4*)&A[ga];
        }
        // ---- stage B into Bs[col][k] ----
        if (BMODE == 0) {
#pragma unroll
            for (int pass = 0; pass < 2; ++pass) {
                const int flat = tid + pass * 256;
                const int row = flat >> 2, seg = (flat & 3) << 3;
                const int gj = j0 + row;
                uint4 v;
                if (gj < Nc) v = *(const uint4*)&Bm[boff + (long long)gj * ldb + k0 + seg];
                else { v.x = v.y = v.z = v.w = 0u; }
                *(uint4*)&Bs[row * ROWP + seg] = v;
            }
        } else {
            // vectorized: thread (kk, j16) loads 16 contiguous j's of row gk
            const int kk  = tid >> 3;           // 0..31
            const int j16 = (tid & 7) << 4;     // 0,16,...,112
            const int gk  = k0 + kk;
            const int gj0 = j0 + j16;
            unsigned short buf[16];
            if (gj0 + 16 <= Nc) {
                const unsigned short* bp = &Bm[boff + (long long)gk * ldb + gj0];
                *(uint4*)&buf[0] = *(const uint4*)bp;
                *(uint4*)&buf[8] = *(const uint4*)(bp + 8);
                if (bdiag) {
#pragma unroll
                    for (int u = 0; u < 16; ++u) {
                        float v = ((gk == gj0 + u) ? bda : 0.f) - bf2f(buf[u]);
                        buf[u] = f2bf(v);
                    }
                }
            } else {
#pragma unroll
                for (int u = 0; u < 16; ++u) buf[u] = 0;
            }
#pragma unroll
            for (int u = 0; u < 16; ++u)
                Bs[(j16 + u) * ROWP + kk] = buf[u];
        }
        __syncthreads();
        // ---- compute: each wave 64x64 via 16 MFMA 16x16x32 ----
        bf16x8 af[4], bfv[4];
#pragma unroll
        for (int fi = 0; fi < 4; ++fi)
            af[fi] = *(const bf16x8*)&As[(wr + fi * 16 + lr) * ROWP + lk * 8];
#pragma unroll
        for (int fj = 0; fj < 4; ++fj)
            bfv[fj] = *(const bf16x8*)&Bs[(wc + fj * 16 + lr) * ROWP + lk * 8];
#pragma unroll
        for (int fi = 0; fi < 4; ++fi)
#pragma unroll
            for (int fj = 0; fj < 4; ++fj)
                acc[fi][fj] = __builtin_amdgcn_mfma_f32_16x16x32_bf16(
                    af[fi], bfv[fj], acc[fi][fj], 0, 0, 0);
        __syncthreads();
    }
    // ---- epilogue ----
#pragma unroll
    for (int fi = 0; fi < 4; ++fi) {
#pragma unroll
        for (int fj = 0; fj < 4; ++fj) {
            const int col = j0 + wc + fj * 16 + lr;
            if (col >= Nc) continue;
#pragma unroll
            for (int r = 0; r < 4; ++r) {
                const int row = i0 + wr + fi * 16 + lk * 4 + r;
                float v = acc[fi][fj][r] * alpha;
                if (epi == 0) {
                    Cf[coff + (long long)row * ldc + col] = v;
                } else if (epi == 1) {
                    const long long ix = coff + (long long)row * ldc + col;
                    Cf[ix] = Cf[ix] + v + bias[col];
                } else if (epi == 2) {
                    Cb[coff + (long long)row * ldc + col] = f2bf(v);
                } else if (epi == 4) {
                    Cb[coff + (long long)row * ldc + col] = f2h(v);
                } else {
                    const int which = col / DIMC;
                    const int c = col - which * DIMC;
                    const int h = c / DHD, d = c - h * DHD;
                    const int b = row / SEQN, n = row - b * SEQN;
                    const long long o = (((long long)(b * NH + h)) * SEQN + n) * DHD + d;
                    if (which == 0)      Qo[o] = f2bf(v * 0.10206207261596575f);
                    else if (which == 1) Ko[o] = f2bf(v);
                    else                 Vo[o] = f2bf(v);
                }
            }
        }
    }
}

// ---------------- row softmax: f16 scores in, bf16 probs out, in place ----------------
// NV = ceil(W/256) as compile-time trip count (static reg indexing, rule #20)
template<int NV>
__global__ __launch_bounds__(256) void softmax_h2b(unsigned short* __restrict__ data, int W)
{
    __shared__ float red[4];
    const long long r = blockIdx.x;
    unsigned short* row = data + r * (long long)W;
    const int t = threadIdx.x, lane = t & 63, wid = t >> 6;
    float v[NV];
    float mx = -3.4e38f;
#pragma unroll
    for (int i = 0; i < NV; ++i) {
        const int j = t + i * 256;
        float f = -3.4e38f;
        if (j < W) f = h2f(row[j]);
        v[i] = f;
        mx = fmaxf(mx, f);
    }
    mx = wave_max(mx);
    if (lane == 0) red[wid] = mx;
    __syncthreads();
    mx = fmaxf(fmaxf(red[0], red[1]), fmaxf(red[2], red[3]));
    __syncthreads();
    float s = 0.f;
#pragma unroll
    for (int i = 0; i < NV; ++i) {
        v[i] = __expf(v[i] - mx);   // masked lanes: exp(-inf) = 0
        s += v[i];
    }
    s = wave_sum(s);
    if (lane == 0) red[wid] = s;
    __syncthreads();
    s = red[0] + red[1] + red[2] + red[3];
    const float inv = 1.f / s;
#pragma unroll
    for (int i = 0; i < NV; ++i) {
        const int j = t + i * 256;
        if (j < W) row[j] = f2bf(v[i] * inv);
    }
}

// ---------------- LayerNorm (row = 768), dual-dtype output ----------------
__global__ __launch_bounds__(256) void ln_kernel(
    const float* __restrict__ in, const float* __restrict__ w,
    const float* __restrict__ b, float* __restrict__ outf,
    unsigned short* __restrict__ outb)
{
    __shared__ float red[4];
    const long long r = blockIdx.x;
    const float* row = in + r * DIMC;
    const int t = threadIdx.x, lane = t & 63, wid = t >> 6;
    float x0 = row[t], x1 = row[t+256], x2 = row[t+512];
    float s = wave_sum(x0 + x1 + x2);
    if (lane == 0) red[wid] = s;
    __syncthreads();
    float mu = (red[0]+red[1]+red[2]+red[3]) * (1.f/DIMC);
    __syncthreads();
    float d0 = x0-mu, d1 = x1-mu, d2 = x2-mu;
    float q = wave_sum(d0*d0 + d1*d1 + d2*d2);
    if (lane == 0) red[wid] = q;
    __syncthreads();
    float rs = rsqrtf((red[0]+red[1]+red[2]+red[3]) * (1.f/DIMC) + 1e-5f);
    float v0 = d0*rs*w[t]     + b[t];
    float v1 = d1*rs*w[t+256] + b[t+256];
    float v2 = d2*rs*w[t+512] + b[t+512];
    if (outf) {
        float* o = outf + r * DIMC;
        o[t] = v0; o[t+256] = v1; o[t+512] = v2;
    }
    if (outb) {
        unsigned short* o = outb + r * DIMC;
        o[t] = f2bf(v0); o[t+256] = f2bf(v1); o[t+512] = f2bf(v2);
    }
}

// conv-branch epilogue: acc = (init ? x : acc) + relu(ln(y+cb))
__global__ __launch_bounds__(256) void ln_relu_add_kernel(
    const float* __restrict__ Y, const float* __restrict__ cb,
    const float* __restrict__ w, const float* __restrict__ b,
    const float* __restrict__ xin, float* __restrict__ acc, int init)
{
    __shared__ float red[4];
    const long long r = blockIdx.x;
    const float* row = Y + r * DIMC;
    const int t = threadIdx.x, lane = t & 63, wid = t >> 6;
    float x0 = row[t]     + cb[t];
    float x1 = row[t+256] + cb[t+256];
    float x2 = row[t+512] + cb[t+512];
    float s = wave_sum(x0 + x1 + x2);
    if (lane == 0) red[wid] = s;
    __syncthreads();
    float mu = (red[0]+red[1]+red[2]+red[3]) * (1.f/DIMC);
    __syncthreads();
    float d0 = x0-mu, d1 = x1-mu, d2 = x2-mu;
    float q = wave_sum(d0*d0 + d1*d1 + d2*d2);
    if (lane == 0) red[wid] = q;
    __syncthreads();
    float rs = rsqrtf((red[0]+red[1]+red[2]+red[3]) * (1.f/DIMC) + 1e-5f);
    float v0 = fmaxf(d0*rs*w[t]     + b[t],     0.f);
    float v1 = fmaxf(d1*rs*w[t+256] + b[t+256], 0.f);
    float v2 = fmaxf(d2*rs*w[t+512] + b[t+512], 0.f);
    float* arow = acc + r * DIMC;
    if (init) {
        const float* xr = xin + r * DIMC;
        arow[t]     = xr[t]     + v0;
        arow[t+256] = xr[t+256] + v1;
        arow[t+512] = xr[t+512] + v2;
    } else {
        arow[t]     += v0;
        arow[t+256] += v1;
        arow[t+512] += v2;
    }
}

// ---------------- row softmax (in-place, f32, W=384 for attn2) ----------------
__global__ __launch_bounds__(256) void softmax_rows(float* __restrict__ data, int W)
{
    __shared__ float red[4];
    const long long r = blockIdx.x;
    float* row = data + r * (long long)W;
    const int t = threadIdx.x, lane = t & 63, wid = t >> 6;
    float mx = -3.4e38f;
    for (int j = t; j < W; j += 256) mx = fmaxf(mx, row[j]);
    mx = wave_max(mx);
    if (lane == 0) red[wid] = mx;
    __syncthreads();
    mx = fmaxf(fmaxf(red[0], red[1]), fmaxf(red[2], red[3]));
    __syncthreads();
    float s = 0.f;
    for (int j = t; j < W; j += 256) s += __expf(row[j] - mx);
    s = wave_sum(s);
    if (lane == 0) red[wid] = s;
    __syncthreads();
    s = red[0]+red[1]+red[2]+red[3];
    const float inv = 1.f / s;
    for (int j = t; j < W; j += 256) row[j] = __expf(row[j] - mx) * inv;
}

// ---------------- small helpers ----------------
__global__ void pad_x_kernel(const float* __restrict__ x, unsigned short* __restrict__ xp)
{
    int i = blockIdx.x * 256 + threadIdx.x;
    if (i >= BATCH * XPADN * (DIMC/4)) return;
    int e = i * 4;
    int c = e % DIMC; int rr = e / DIMC; int pr = rr % XPADN; int b = rr / XPADN;
    int n = pr - PADX;
    ushort4 o;
    if (n < 0 || n >= SEQN) { o.x = o.y = o.z = o.w = 0; }
    else {
        float4 v = *(const float4*)&x[((long long)(b * SEQN + n)) * DIMC + c];
        o.x = f2bf(v.x); o.y = f2bf(v.y); o.z = f2bf(v.z); o.w = f2bf(v.w);
    }
    *(ushort4*)&xp[e] = o;
}

// conv weight [O][I][K] -> bf16 [O][K][I]
__global__ void transpose_w_bf16_kernel(const float* __restrict__ W,
                                        unsigned short* __restrict__ WT, int K, int total)
{
    int idx = blockIdx.x * 256 + threadIdx.x;
    if (idx >= total) return;
    int i = idx % DIMC; int t = idx / DIMC; int k = t % K; int o = t / K;
    WT[idx] = f2bf(W[((long long)o * DIMC + i) * K + k]);
}

__global__ void cvt_bf16_kernel(const float* __restrict__ src,
                                unsigned short* __restrict__ dst, int n4)
{
    int i = blockIdx.x * 256 + threadIdx.x;
    if (i >= n4) return;
    float4 v = ((const float4*)src)[i];
    ushort4 o; o.x = f2bf(v.x); o.y = f2bf(v.y); o.z = f2bf(v.z); o.w = f2bf(v.w);
    ((ushort4*)dst)[i] = o;
}

__global__ void landmark_kernel(const unsigned short* __restrict__ src,
                                unsigned short* __restrict__ dstb)
{
    int idx = blockIdx.x * 256 + threadIdx.x;
    if (idx >= MD) return;
    int d = idx % DHD; int rem = idx / DHD; int m = rem % ML; int bh = rem / ML;
    const unsigned short* p = src + ((long long)bh * SEQN + m * LW) * DHD + d;
    float s = 0.f;
#pragma unroll
    for (int j = 0; j < LW; ++j) s += bf2f(p[(long long)j * DHD]);
    dstb[idx] = f2bf(s * (1.f / LW));
}

__global__ void init_scalars_kernel(float* sc)
{
    if (blockIdx.x == 0 && threadIdx.x < 2) sc[threadIdx.x] = 0.f;
}
__global__ void rowsum_max_kernel(const float* __restrict__ A2, float* sc)
{
    int r = blockIdx.x * 256 + threadIdx.x;
    if (r >= BHN * ML) return;
    const float* row = A2 + (long long)r * ML;
    float s = 0.f;
    for (int j = 0; j < ML; ++j) s += fabsf(row[j]);
    atomicMax((unsigned int*)(sc + 0), __float_as_uint(s));
}
__global__ void colsum_max_kernel(const float* __restrict__ A2, float* sc)
{
    int idx = blockIdx.x * 256 + threadIdx.x;
    if (idx >= BHN * ML) return;
    int j = idx % ML, bh = idx / ML;
    const float* base = A2 + (long long)bh * ML * ML + j;
    float s = 0.f;
    for (int i = 0; i < ML; ++i) s += fabsf(base[(long long)i * ML]);
    atomicMax((unsigned int*)(sc + 1), __float_as_uint(s));
}
__global__ void z0_kernel(const float* __restrict__ A2, const float* __restrict__ sc,
                          unsigned short* __restrict__ Z)
{
    long long idx = (long long)blockIdx.x * 256 + threadIdx.x;
    if (idx >= (long long)MM_) return;
    int j = idx % ML; long long rem = idx / ML; int i = (int)(rem % ML); long long bh = rem / ML;
    float inv = 1.f / (sc[0] * sc[1]);
    Z[idx] = f2bf(A2[(bh * ML + j) * ML + i] * inv);
}

__global__ void resconv_kernel(const unsigned short* __restrict__ V,
                               const float* __restrict__ RW, float* __restrict__ AO)
{
    int idx = blockIdx.x * 256 + threadIdx.x;
    if (idx >= BND) return;
    int d = idx % DHD; int rem = idx / DHD; int n = rem % SEQN; int bh = rem / SEQN;
    int h = bh % NH;
    const unsigned short* vb = V + (long long)bh * SEQN * DHD + d;
    float s = 0.f;
#pragma unroll
    for (int j = 0; j < 33; ++j) {
        int sn = n + j - 16;
        if (sn >= 0 && sn < SEQN) s += bf2f(vb[(long long)sn * DHD]) * RW[h * 33 + j];
    }
    AO[idx] += s;
}

__global__ void concat_heads_kernel(const float* __restrict__ AO,
                                    unsigned short* __restrict__ CT)
{
    int idx = blockIdx.x * 256 + threadIdx.x;
    if (idx >= BND) return;
    int d = idx % DHD; int rem = idx / DHD; int n = rem % SEQN; int bh = rem / SEQN;
    int h = bh % NH, b = bh / NH;
    CT[((long long)(b * SEQN + n)) * DIMC + h * DHD + d] = f2bf(AO[idx]);
}

__global__ void sentinel_kernel(float* __restrict__ out, int n)
{
    int i = blockIdx.x * 256 + threadIdx.x;
    if (i < n) out[i] = 1.0e6f;
}

// ---------------- host ----------------
extern "C" void kernel_launch(void* const* d_in, const int* in_sizes, int n_in,
                              void* d_out, int out_size, void* d_ws, size_t ws_size,
                              hipStream_t stream)
{
    (void)in_sizes; (void)n_in;
    const float* x    = (const float*)d_in[0];
    const float* c1w  = (const float*)d_in[1];
    const float* c1b  = (const float*)d_in[2];
    const float* c2w  = (const float*)d_in[3];
    const float* c2b  = (const float*)d_in[4];
    const float* c3w  = (const float*)d_in[5];
    const float* c3b  = (const float*)d_in[6];
    const float* nw   = (const float*)d_in[7];
    const float* nb   = (const float*)d_in[8];
    const float* tw   = (const float*)d_in[9];
    const float* tb   = (const float*)d_in[10];
    const float* qkvw = (const float*)d_in[11];
    const float* outw = (const float*)d_in[12];
    const float* outb = (const float*)d_in[13];
    const float* rcw  = (const float*)d_in[14];
    float* out = (float*)d_out;
    float* ws  = (float*)d_ws;

    // ---------- workspace layout (float units; bf16/f16 buffers carved as ushort*) ----------
    const int POOLA_F = 7378944;   // Xpad+WTbf during conv; Tbf alias; later part of score span
    const int POOLB_F = 8847360;   // Qbf/Kbf/Vbf; CONVY f32 alias; CTbf aliases Kbf
    const int POOLC_F = 3538944;   // qkvw/outw/A2bf/R3bf/QLbf/KLbf/W2bf
    float* OUT_ACC = ws;                          // BND f32
    float* A2f  = OUT_ACC + BND;                  // MM_ f32; later head of AOf2 span
    float* QLf  = A2f + MM_;                      // (region only; f32 landmarks no longer used)
    float* KLf  = QLf + MD;
    float* Zab  = KLf + MD;                       // MM_ f32 (= Za_bf + Zb_bf shorts)
    float* AOf  = Zab + MM_;                      // BND f32; head of 13.3M-float score span
    float* poolA = AOf + BND;
    float* poolB = poolA + POOLA_F;
    float* poolC = poolB + POOLB_F;
    float* SC   = poolC + POOLC_F;                // 16 f32

    unsigned short* Xpad  = (unsigned short*)poolA;          // [2][3848][768]
    unsigned short* WTbf  = Xpad + BATCH*XPADN*DIMC;         // 8,847,360 sh
    unsigned short* Tbf   = Xpad;                            // alias (post-conv)
    float*          CONVY = poolB;                           // f32 alias (conv phase)
    unsigned short* Qbf   = (unsigned short*)poolB;          // BND sh
    unsigned short* Kbf   = Qbf + BND;
    unsigned short* Vbf   = Kbf + BND;
    unsigned short* CTbf  = Kbf;                             // alias (post-attn)
    unsigned short* qkvwb = (unsigned short*)poolC;          // 1,769,472 sh
    unsigned short* outwb = qkvwb + 3*DIMC*DIMC;             // 589,824 sh
    unsigned short* A2bf  = outwb + DIMC*DIMC;               // MM_ sh
    unsigned short* R3bf  = A2bf + MM_;                      // MD sh
    unsigned short* QLbf  = R3bf + MD;                       // MD sh
    unsigned short* KLbf  = QLbf + MD;                       // MD sh
    unsigned short* W2bf  = KLbf + MD;                       // MD sh
    unsigned short* XZbf  = (unsigned short*)A2f;            // MM_ sh (A2f dead post-z0/cvt)
    unsigned short* T1bf  = XZbf + MM_;
    unsigned short* Zabf  = (unsigned short*)Zab;
    unsigned short* Zbbf  = Zabf + MM_;
    // score matrix span: 16*3840*384 = 23.6M shorts in AOf(5.9M f32)+poolA(7.38M f32)
    unsigned short* Sh    = (unsigned short*)AOf;
    // attention output span: A2f..Zab+MM_ = exactly BND f32 (all dead after step 11)
    float* AOf2 = A2f;

    size_t need_bytes = (size_t)(SC + 16 - ws) * sizeof(float);
    if (ws_size < need_bytes) {
        sentinel_kernel<<<(out_size + 255)/256, 256, 0, stream>>>(out, out_size);
        return;
    }

    auto mg = [&](int bmode, const unsigned short* A, int lda, long long sA,
                  const unsigned short* Bm, int ldb, long long sB,
                  int Mr, int Nc, int Kd, float alpha, int bdiag, float bda, int convk,
                  int epi, float* Cf, long long sC, int ldc, unsigned short* Cb,
                  const float* bias, unsigned short* Qo, unsigned short* Ko,
                  unsigned short* Vo, int batch) {
        dim3 g((Nc + 127) / 128, Mr / 128, batch), blk(256);
        if (bmode == 0)
            mgemm_k<0><<<g, blk, 0, stream>>>(A, lda, sA, Bm, ldb, sB, Mr, Nc, Kd,
                alpha, bdiag, bda, convk, epi, Cf, sC, ldc, Cb, bias, Qo, Ko, Vo);
        else
            mgemm_k<1><<<g, blk, 0, stream>>>(A, lda, sA, Bm, ldb, sB, Mr, Nc, Kd,
                alpha, bdiag, bda, convk, epi, Cf, sC, ldc, Cb, bias, Qo, Ko, Vo);
    };

    const int DD = DIMC * DIMC;
    const long long sMD = (long long)ML*DHD, sMM = (long long)ML*ML,
                    sND = (long long)SEQN*DHD, sMN = (long long)ML*SEQN;

    // 0. bf16 conversions: padded X, conv weights (transposed), qkv/out weights
    pad_x_kernel<<<(BATCH*XPADN*(DIMC/4) + 255)/256, 256, 0, stream>>>(x, Xpad);
    transpose_w_bf16_kernel<<<(DD*3 + 255)/256, 256, 0, stream>>>(c1w, WTbf,                  3, DD*3);
    transpose_w_bf16_kernel<<<(DD*5 + 255)/256, 256, 0, stream>>>(c2w, WTbf + (long long)3*DD, 5, DD*5);
    transpose_w_bf16_kernel<<<(DD*7 + 255)/256, 256, 0, stream>>>(c3w, WTbf + (long long)8*DD, 7, DD*7);
    cvt_bf16_kernel<<<(3*DD/4 + 255)/256, 256, 0, stream>>>(qkvw, qkvwb, 3*DD/4);
    cvt_bf16_kernel<<<(DD/4 + 255)/256, 256, 0, stream>>>(outw, outwb, DD/4);

    // 1-3. conv branches (implicit im2col MFMA GEMM) -> OUT_ACC
    const float* cbs[3] = {c1b, c2b, c3b};
    const int    cks[3] = {3, 5, 7};
    const long long coff[3] = {0, (long long)3*DD, (long long)8*DD};
    for (int ci = 0; ci < 3; ++ci) {
        int K = cks[ci];
        mg(0, Xpad, DIMC, 0, WTbf + coff[ci], K*DIMC, 0, ROWS, DIMC, K*DIMC,
           1.f, 0, 0.f, K, 0, CONVY, 0, DIMC, nullptr, nullptr, nullptr, nullptr, nullptr, 1);
        ln_relu_add_kernel<<<ROWS, 256, 0, stream>>>(CONVY, cbs[ci], nw, nb, x, OUT_ACC, ci == 0);
    }

    // 4. T = ln(OUT_ACC, tnorm) -> bf16 (aliases Xpad; conv phase done)
    ln_kernel<<<ROWS, 256, 0, stream>>>(OUT_ACC, tw, tb, nullptr, Tbf);

    // 5. QKV projection, head-scatter epilogue -> Qbf/Kbf/Vbf (q scaled)
    mg(0, Tbf, DIMC, 0, qkvwb, DIMC, 0, ROWS, 3*DIMC, DIMC,
       1.f, 0, 0.f, 0, 3, nullptr, 0, 0, nullptr, nullptr, Qbf, Kbf, Vbf, 1);

    // 6. landmarks (bf16)
    landmark_kernel<<<(MD + 255)/256, 256, 0, stream>>>(Qbf, QLbf);
    landmark_kernel<<<(MD + 255)/256, 256, 0, stream>>>(Kbf, KLbf);

    // 7. sim2 (MFMA, f32 out) + softmax -> A2f
    mg(0, QLbf, DHD, sMD, KLbf, DHD, sMD, ML, ML, DHD,
       1.f, 0, 0.f, 0, 0, A2f, sMM, ML, nullptr, nullptr, nullptr, nullptr, nullptr, BHN);
    softmax_rows<<<BHN*ML, 256, 0, stream>>>(A2f, ML);

    // 8. pinv init: z0 = attn2^T / (max_rowsum * max_colsum); A2 -> bf16
    init_scalars_kernel<<<1, 64, 0, stream>>>(SC);
    rowsum_max_kernel<<<(BHN*ML + 255)/256, 256, 0, stream>>>(A2f, SC);
    colsum_max_kernel<<<(BHN*ML + 255)/256, 256, 0, stream>>>(A2f, SC);
    z0_kernel<<<(MM_ + 255)/256, 256, 0, stream>>>(A2f, SC, Zabf);
    cvt_bf16_kernel<<<(MM_/4 + 255)/256, 256, 0, stream>>>(A2f, A2bf, MM_/4);

    // 9. Newton-Schulz x6 (bf16 MFMA): z = 0.25 z (13I - xz(15I - xz(7I - xz)))
    unsigned short* Zc = Zabf; unsigned short* Zn = Zbbf;
    for (int it = 0; it < 6; ++it) {
        mg(1, A2bf, ML, sMM, Zc,  ML, sMM, ML, ML, ML, 1.f,  0, 0.f,  0, 2,
           nullptr, sMM, ML, XZbf, nullptr, nullptr, nullptr, nullptr, BHN);
        mg(1, XZbf, ML, sMM, XZbf, ML, sMM, ML, ML, ML, 1.f,  1, 7.f,  0, 2,
           nullptr, sMM, ML, Zn,   nullptr, nullptr, nullptr, nullptr, BHN);
        mg(1, XZbf, ML, sMM, Zn,  ML, sMM, ML, ML, ML, 1.f,  1, 15.f, 0, 2,
           nullptr, sMM, ML, T1bf, nullptr, nullptr, nullptr, nullptr, BHN);
        mg(1, Zc,   ML, sMM, T1bf, ML, sMM, ML, ML, ML, 0.25f, 1, 13.f, 0, 2,
           nullptr, sMM, ML, Zn,   nullptr, nullptr, nullptr, nullptr, BHN);
        unsigned short* t = Zc; Zc = Zn; Zn = t;
    }

    // 10. sim3 = QL @ K^T (f16 scores) -> softmax (bf16 probs) -> R3 = P @ V
    mg(0, QLbf, DHD, sMD, Kbf, DHD, sND, ML, SEQN, DHD,
       1.f, 0, 0.f, 0, 4, nullptr, sMN, SEQN, Sh, nullptr, nullptr, nullptr, nullptr, BHN);
    softmax_h2b<15><<<BHN*ML, 256, 0, stream>>>(Sh, SEQN);
    mg(1, Sh, SEQN, sMN, Vbf, DHD, sND, ML, DHD, SEQN,
       1.f, 0, 0.f, 0, 2, nullptr, sMD, DHD, R3bf, nullptr, nullptr, nullptr, nullptr, BHN);

    // 11. W2 = pinv(attn2) @ R3  (bf16 MFMA, N=96)
    mg(1, Zc, ML, sMM, R3bf, DHD, sMD, ML, DHD, ML, 1.f, 0, 0.f, 0, 2,
       nullptr, sMD, DHD, W2bf, nullptr, nullptr, nullptr, nullptr, BHN);

    // 12. sim1 = Q @ KL^T (f16 scores) -> softmax (bf16 probs) -> AO = P @ W2 (f32)
    mg(0, Qbf, DHD, sND, KLbf, DHD, sMD, SEQN, ML, DHD,
       1.f, 0, 0.f, 0, 4, nullptr, sMN, ML, Sh, nullptr, nullptr, nullptr, nullptr, BHN);
    softmax_h2b<2><<<BHN*SEQN, 256, 0, stream>>>(Sh, ML);
    mg(1, Sh, ML, sMN, W2bf, DHD, sMD, SEQN, DHD, ML,
       1.f, 0, 0.f, 0, 0, AOf2, sND, DHD, nullptr, nullptr, nullptr, nullptr, nullptr, BHN);

    // 13. residual depthwise conv on V -> AOf2
    resconv_kernel<<<(BND + 255)/256, 256, 0, stream>>>(Vbf, rcw, AOf2);

    // 14. [B,H,N,Dh] -> [B,N,D] bf16 (CTbf aliases Kbf)
    concat_heads_kernel<<<(BND + 255)/256, 256, 0, stream>>>(AOf2, CTbf);

    // 15. out projection + bias, accumulate into OUT_ACC (outer residual)
    mg(0, CTbf, DIMC, 0, outwb, DIMC, 0, ROWS, DIMC, DIMC,
       1.f, 0, 0.f, 0, 1, OUT_ACC, 0, DIMC, nullptr, outb, nullptr, nullptr, nullptr, 1);

    // 16. final layernorm -> d_out
    ln_kernel<<<ROWS, 256, 0, stream>>>(OUT_ACC, nw, nb, out, nullptr);
}

// Round 7
// 1709.969 us; speedup vs baseline: 2.9978x; 1.2498x over previous
//
#include <hip/hip_runtime.h>

#define SEQN 3840
#define BATCH 2
#define DIMC 768
#define NH 8
#define DHD 96
#define ML 384
#define LW 10
#define BHN 16
#define ROWS (BATCH*SEQN)
#define PADX 4
#define XPADN (SEQN + 2*PADX)   // 3848
#define NCOL3 (3*DIMC)          // 2304 merged-conv output cols
#define KD7 (7*DIMC)            // 5376 merged-conv K depth

static const int BND = BATCH*SEQN*DIMC;   // 5,898,240
static const int MD  = BHN*ML*DHD;        // 589,824
static const int MM_ = BHN*ML*ML;         // 2,359,296

// ---------------- scalar conv helpers ----------------
__device__ __forceinline__ unsigned short f2bf(float f) {
    unsigned int u = __float_as_uint(f);
    u = (u + 0x7FFF + ((u >> 16) & 1)) >> 16;   // RNE
    return (unsigned short)u;
}
__device__ __forceinline__ float bf2f(unsigned short s) {
    return __uint_as_float(((unsigned int)s) << 16);
}
__device__ __forceinline__ unsigned short f2h(float f) {
    _Float16 h = (_Float16)f;
    return *(unsigned short*)&h;
}
__device__ __forceinline__ float h2f(unsigned short u) {
    _Float16 h = *(_Float16*)&u;
    return (float)h;
}

// ---------------- reductions ----------------
__device__ __forceinline__ float wave_sum(float v) {
#pragma unroll
    for (int m = 32; m; m >>= 1) v += __shfl_xor(v, m, 64);
    return v;
}
__device__ __forceinline__ float wave_max(float v) {
#pragma unroll
    for (int m = 32; m; m >>= 1) v = fmaxf(v, __shfl_xor(v, m, 64));
    return v;
}

typedef short bf16x8 __attribute__((ext_vector_type(8)));
typedef float f32x4 __attribute__((ext_vector_type(4)));
#define ROWP 40   // LDS row pitch in shorts (80 B)

// ================= 128x128 bf16 MFMA GEMM (BT; big shapes) =================
// C = alpha * A @ B^T ; A bf16 [Mr][Kd] (or implicit conv im2col of padded X, conv_k=7)
// epi: 0 f32 store; 1 f32 C += v + bias; 3 QKV head-scatter (bf16); 4 f16 store
__global__ __launch_bounds__(256) void mgemm_k(
    const unsigned short* __restrict__ A, int lda, long long sA,
    const unsigned short* __restrict__ Bm, int ldb, long long sB,
    int Mr, int Nc, int Kd, float alpha, int conv_k,
    int epi, float* __restrict__ Cf, long long sC, int ldc,
    unsigned short* __restrict__ Cb, const float* __restrict__ bias,
    unsigned short* __restrict__ Qo, unsigned short* __restrict__ Ko,
    unsigned short* __restrict__ Vo)
{
    __shared__ unsigned short As[128*ROWP] __attribute__((aligned(16)));
    __shared__ unsigned short Bs[128*ROWP] __attribute__((aligned(16)));
    const int bz = blockIdx.z;
    const long long aoff = (long long)bz * sA, boff = (long long)bz * sB;
    const long long coff = (long long)bz * sC;
    const int i0 = blockIdx.y * 128, j0 = blockIdx.x * 128;
    const int tid = threadIdx.x;
    const int w = tid >> 6, l = tid & 63;
    const int wr = (w >> 1) << 6, wc = (w & 1) << 6;
    const int lr = l & 15, lk = l >> 4;
    const int khalf = conv_k >> 1;

    f32x4 acc[4][4] = {};

    for (int k0 = 0; k0 < Kd; k0 += 32) {
#pragma unroll
        for (int pass = 0; pass < 2; ++pass) {
            const int flat = tid + pass * 256;
            const int row = flat >> 2, seg = (flat & 3) << 3;
            long long ga;
            if (conv_k) {
                const int gi = i0 + row;
                const int b = gi / SEQN, n = gi - b * SEQN;
                const int tap = k0 / DIMC, c = k0 - tap * DIMC;
                ga = ((long long)(b * XPADN + n + tap + PADX - khalf)) * DIMC + c + seg;
            } else {
                ga = aoff + (long long)(i0 + row) * lda + k0 + seg;
            }
            *(uint4*)&As[row * ROWP + seg] = *(const uint4*)&A[ga];
        }
#pragma unroll
        for (int pass = 0; pass < 2; ++pass) {
            const int flat = tid + pass * 256;
            const int row = flat >> 2, seg = (flat & 3) << 3;
            const int gj = j0 + row;
            uint4 v;
            if (gj < Nc) v = *(const uint4*)&Bm[boff + (long long)gj * ldb + k0 + seg];
            else { v.x = v.y = v.z = v.w = 0u; }
            *(uint4*)&Bs[row * ROWP + seg] = v;
        }
        __syncthreads();
        bf16x8 af[4], bfv[4];
#pragma unroll
        for (int fi = 0; fi < 4; ++fi)
            af[fi] = *(const bf16x8*)&As[(wr + fi * 16 + lr) * ROWP + lk * 8];
#pragma unroll
        for (int fj = 0; fj < 4; ++fj)
            bfv[fj] = *(const bf16x8*)&Bs[(wc + fj * 16 + lr) * ROWP + lk * 8];
#pragma unroll
        for (int fi = 0; fi < 4; ++fi)
#pragma unroll
            for (int fj = 0; fj < 4; ++fj)
                acc[fi][fj] = __builtin_amdgcn_mfma_f32_16x16x32_bf16(
                    af[fi], bfv[fj], acc[fi][fj], 0, 0, 0);
        __syncthreads();
    }
#pragma unroll
    for (int fi = 0; fi < 4; ++fi) {
#pragma unroll
        for (int fj = 0; fj < 4; ++fj) {
            const int col = j0 + wc + fj * 16 + lr;
            if (col >= Nc) continue;
#pragma unroll
            for (int r = 0; r < 4; ++r) {
                const int row = i0 + wr + fi * 16 + lk * 4 + r;
                float v = acc[fi][fj][r] * alpha;
                if (epi == 0) {
                    Cf[coff + (long long)row * ldc + col] = v;
                } else if (epi == 1) {
                    const long long ix = coff + (long long)row * ldc + col;
                    Cf[ix] = Cf[ix] + v + bias[col];
                } else if (epi == 4) {
                    Cb[coff + (long long)row * ldc + col] = f2h(v);
                } else {
                    const int which = col / DIMC;
                    const int c = col - which * DIMC;
                    const int h = c / DHD, d = c - h * DHD;
                    const int b = row / SEQN, n = row - b * SEQN;
                    const long long o = (((long long)(b * NH + h)) * SEQN + n) * DHD + d;
                    if (which == 0)      Qo[o] = f2bf(v * 0.10206207261596575f);
                    else if (which == 1) Ko[o] = f2bf(v);
                    else                 Vo[o] = f2bf(v);
                }
            }
        }
    }
}

// ================= 64x64 bf16 MFMA GEMM (small/batched shapes) =================
// BMODE 0: B^T from B[N][K]; BMODE 1: NN from B[K][N], optional bdiag: B'=(k==j?bda:0)-B
// epi: 0 f32 store; 2 bf16 store; 5 f32 atomicAdd (for split-K)
template<int BMODE>
__global__ __launch_bounds__(256) void mgemm64_k(
    const unsigned short* __restrict__ A, int lda, long long sA,
    const unsigned short* __restrict__ Bm, int ldb, long long sB,
    int Mr, int Nc, int Kd, float alpha, int bdiag, float bda, int ksplit,
    int epi, float* __restrict__ Cf, long long sC, int ldc,
    unsigned short* __restrict__ Cb)
{
    __shared__ unsigned short As[64*ROWP] __attribute__((aligned(16)));
    __shared__ unsigned short Bs[64*ROWP] __attribute__((aligned(16)));
    const int bz = blockIdx.z / ksplit;
    const int kch = blockIdx.z - bz * ksplit;
    const long long aoff = (long long)bz * sA, boff = (long long)bz * sB;
    const long long coff = (long long)bz * sC;
    const int i0 = blockIdx.y * 64, j0 = blockIdx.x * 64;
    const int tid = threadIdx.x;
    const int w = tid >> 6, l = tid & 63;
    const int lr = l & 15, lk = l >> 4;
    const int klen = Kd / ksplit;
    const int kbeg = kch * klen, kend = kbeg + klen;

    f32x4 acc[4] = {};

    for (int k0 = kbeg; k0 < kend; k0 += 32) {
        {
            const int row = tid >> 2, seg = (tid & 3) << 3;
            *(uint4*)&As[row*ROWP+seg] =
                *(const uint4*)&A[aoff + (long long)(i0+row)*lda + k0 + seg];
        }
        if (BMODE == 0) {
            const int row = tid >> 2, seg = (tid & 3) << 3;
            const int gj = j0 + row;
            uint4 v;
            if (gj < Nc) v = *(const uint4*)&Bm[boff + (long long)gj*ldb + k0 + seg];
            else { v.x=v.y=v.z=v.w=0u; }
            *(uint4*)&Bs[row*ROWP+seg] = v;
        } else {
            const int kk = tid >> 3, j8 = (tid & 7) << 3;
            const int gk = k0 + kk, gj0 = j0 + j8;
            unsigned short buf[8];
            if (gj0 + 8 <= Nc) {
                *(uint4*)&buf[0] = *(const uint4*)&Bm[boff + (long long)gk*ldb + gj0];
                if (bdiag) {
#pragma unroll
                    for (int u = 0; u < 8; ++u) {
                        float v = ((gk == gj0+u) ? bda : 0.f) - bf2f(buf[u]);
                        buf[u] = f2bf(v);
                    }
                }
            } else {
#pragma unroll
                for (int u = 0; u < 8; ++u) buf[u] = 0;
            }
#pragma unroll
            for (int u = 0; u < 8; ++u) Bs[(j8+u)*ROWP + kk] = buf[u];
        }
        __syncthreads();
        bf16x8 af = *(const bf16x8*)&As[(w*16+lr)*ROWP + lk*8];
        bf16x8 b0 = *(const bf16x8*)&Bs[(lr)*ROWP + lk*8];
        bf16x8 b1 = *(const bf16x8*)&Bs[(16+lr)*ROWP + lk*8];
        bf16x8 b2 = *(const bf16x8*)&Bs[(32+lr)*ROWP + lk*8];
        bf16x8 b3 = *(const bf16x8*)&Bs[(48+lr)*ROWP + lk*8];
        acc[0] = __builtin_amdgcn_mfma_f32_16x16x32_bf16(af, b0, acc[0], 0,0,0);
        acc[1] = __builtin_amdgcn_mfma_f32_16x16x32_bf16(af, b1, acc[1], 0,0,0);
        acc[2] = __builtin_amdgcn_mfma_f32_16x16x32_bf16(af, b2, acc[2], 0,0,0);
        acc[3] = __builtin_amdgcn_mfma_f32_16x16x32_bf16(af, b3, acc[3], 0,0,0);
        __syncthreads();
    }
#pragma unroll
    for (int fj = 0; fj < 4; ++fj) {
        const int col = j0 + fj*16 + lr;
        if (col >= Nc) continue;
#pragma unroll
        for (int r = 0; r < 4; ++r) {
            const int row = i0 + w*16 + lk*4 + r;
            float v = acc[fj][r] * alpha;
            if (epi == 0)      Cf[coff + (long long)row*ldc + col] = v;
            else if (epi == 2) Cb[coff + (long long)row*ldc + col] = f2bf(v);
            else               atomicAdd(&Cf[coff + (long long)row*ldc + col], v);
        }
    }
}

// ---------------- row softmax: f16 scores in, bf16 probs out, in place ----------------
template<int NV>
__global__ __launch_bounds__(256) void softmax_h2b(unsigned short* __restrict__ data, int W)
{
    __shared__ float red[4];
    const long long r = blockIdx.x;
    unsigned short* row = data + r * (long long)W;
    const int t = threadIdx.x, lane = t & 63, wid = t >> 6;
    float v[NV];
    float mx = -3.4e38f;
#pragma unroll
    for (int i = 0; i < NV; ++i) {
        const int j = t + i * 256;
        float f = -3.4e38f;
        if (j < W) f = h2f(row[j]);
        v[i] = f;
        mx = fmaxf(mx, f);
    }
    mx = wave_max(mx);
    if (lane == 0) red[wid] = mx;
    __syncthreads();
    mx = fmaxf(fmaxf(red[0], red[1]), fmaxf(red[2], red[3]));
    __syncthreads();
    float s = 0.f;
#pragma unroll
    for (int i = 0; i < NV; ++i) {
        v[i] = __expf(v[i] - mx);
        s += v[i];
    }
    s = wave_sum(s);
    if (lane == 0) red[wid] = s;
    __syncthreads();
    s = red[0] + red[1] + red[2] + red[3];
    const float inv = 1.f / s;
#pragma unroll
    for (int i = 0; i < NV; ++i) {
        const int j = t + i * 256;
        if (j < W) row[j] = f2bf(v[i] * inv);
    }
}

// ---------------- LayerNorm (row = 768), dual-dtype output ----------------
__global__ __launch_bounds__(256) void ln_kernel(
    const float* __restrict__ in, const float* __restrict__ w,
    const float* __restrict__ b, float* __restrict__ outf,
    unsigned short* __restrict__ outb)
{
    __shared__ float red[4];
    const long long r = blockIdx.x;
    const float* row = in + r * DIMC;
    const int t = threadIdx.x, lane = t & 63, wid = t >> 6;
    float x0 = row[t], x1 = row[t+256], x2 = row[t+512];
    float s = wave_sum(x0 + x1 + x2);
    if (lane == 0) red[wid] = s;
    __syncthreads();
    float mu = (red[0]+red[1]+red[2]+red[3]) * (1.f/DIMC);
    __syncthreads();
    float d0 = x0-mu, d1 = x1-mu, d2 = x2-mu;
    float q = wave_sum(d0*d0 + d1*d1 + d2*d2);
    if (lane == 0) red[wid] = q;
    __syncthreads();
    float rs = rsqrtf((red[0]+red[1]+red[2]+red[3]) * (1.f/DIMC) + 1e-5f);
    float v0 = d0*rs*w[t]     + b[t];
    float v1 = d1*rs*w[t+256] + b[t+256];
    float v2 = d2*rs*w[t+512] + b[t+512];
    if (outf) {
        float* o = outf + r * DIMC;
        o[t] = v0; o[t+256] = v1; o[t+512] = v2;
    }
    if (outb) {
        unsigned short* o = outb + r * DIMC;
        o[t] = f2bf(v0); o[t+256] = f2bf(v1); o[t+512] = f2bf(v2);
    }
}

// ---------------- merged conv epilogue: acc = x + sum_s relu(ln(y_s+cb_s)) ----------------
__global__ __launch_bounds__(256) void ln_relu_add3_kernel(
    const unsigned short* __restrict__ Y16,   // [rows][2304] f16
    const float* __restrict__ cb0, const float* __restrict__ cb1,
    const float* __restrict__ cb2,
    const float* __restrict__ w, const float* __restrict__ b,
    const float* __restrict__ xin, float* __restrict__ acc)
{
    __shared__ float red[4];
    const long long r = blockIdx.x;
    const unsigned short* row = Y16 + r * NCOL3;
    const int t = threadIdx.x, lane = t & 63, wid = t >> 6;
    const float* xr = xin + r * DIMC;
    float o0 = xr[t], o1 = xr[t+256], o2 = xr[t+512];
    const float* cbs[3] = {cb0, cb1, cb2};
#pragma unroll
    for (int s = 0; s < 3; ++s) {
        const float* cb = cbs[s];
        float x0 = h2f(row[s*DIMC + t])     + cb[t];
        float x1 = h2f(row[s*DIMC + t+256]) + cb[t+256];
        float x2 = h2f(row[s*DIMC + t+512]) + cb[t+512];
        float su = wave_sum(x0 + x1 + x2);
        __syncthreads();
        if (lane == 0) red[wid] = su;
        __syncthreads();
        float mu = (red[0]+red[1]+red[2]+red[3]) * (1.f/DIMC);
        float d0 = x0-mu, d1 = x1-mu, d2 = x2-mu;
        float q = wave_sum(d0*d0 + d1*d1 + d2*d2);
        __syncthreads();
        if (lane == 0) red[wid] = q;
        __syncthreads();
        float rs = rsqrtf((red[0]+red[1]+red[2]+red[3]) * (1.f/DIMC) + 1e-5f);
        o0 += fmaxf(d0*rs*w[t]     + b[t],     0.f);
        o1 += fmaxf(d1*rs*w[t+256] + b[t+256], 0.f);
        o2 += fmaxf(d2*rs*w[t+512] + b[t+512], 0.f);
    }
    float* ar = acc + r * DIMC;
    ar[t] = o0; ar[t+256] = o1; ar[t+512] = o2;
}

// ---------------- row softmax (in-place, f32, W=384 for attn2) ----------------
__global__ __launch_bounds__(256) void softmax_rows(float* __restrict__ data, int W)
{
    __shared__ float red[4];
    const long long r = blockIdx.x;
    float* row = data + r * (long long)W;
    const int t = threadIdx.x, lane = t & 63, wid = t >> 6;
    float mx = -3.4e38f;
    for (int j = t; j < W; j += 256) mx = fmaxf(mx, row[j]);
    mx = wave_max(mx);
    if (lane == 0) red[wid] = mx;
    __syncthreads();
    mx = fmaxf(fmaxf(red[0], red[1]), fmaxf(red[2], red[3]));
    __syncthreads();
    float s = 0.f;
    for (int j = t; j < W; j += 256) s += __expf(row[j] - mx);
    s = wave_sum(s);
    if (lane == 0) red[wid] = s;
    __syncthreads();
    s = red[0]+red[1]+red[2]+red[3];
    const float inv = 1.f / s;
    for (int j = t; j < W; j += 256) row[j] = __expf(row[j] - mx) * inv;
}

// ---------------- small helpers ----------------
__global__ void pad_x_kernel(const float* __restrict__ x, unsigned short* __restrict__ xp)
{
    int i = blockIdx.x * 256 + threadIdx.x;
    if (i >= BATCH * XPADN * (DIMC/4)) return;
    int e = i * 4;
    int c = e % DIMC; int rr = e / DIMC; int pr = rr % XPADN; int b = rr / XPADN;
    int n = pr - PADX;
    ushort4 o;
    if (n < 0 || n >= SEQN) { o.x = o.y = o.z = o.w = 0; }
    else {
        float4 v = *(const float4*)&x[((long long)(b * SEQN + n)) * DIMC + c];
        o.x = f2bf(v.x); o.y = f2bf(v.y); o.z = f2bf(v.z); o.w = f2bf(v.w);
    }
    *(ushort4*)&xp[e] = o;
}

// conv weight [O][I][K] -> bf16 7-tap frame rows: WT[(branch*768+o)][tap][i]
__global__ void transpose_w7_kernel(const float* __restrict__ W,
                                    unsigned short* __restrict__ WT, int K, int branch)
{
    int idx = blockIdx.x * 256 + threadIdx.x;
    if (idx >= DIMC * 7 * DIMC) return;
    int i = idx % DIMC; int rem = idx / DIMC; int t = rem % 7; int o = rem / 7;
    int k = t - (3 - (K >> 1));
    float v = (k >= 0 && k < K) ? W[((long long)o * DIMC + i) * K + k] : 0.f;
    WT[((long long)(branch * DIMC + o)) * KD7 + t * DIMC + i] = f2bf(v);
}

__global__ void cvt_bf16_kernel(const float* __restrict__ src,
                                unsigned short* __restrict__ dst, int n4)
{
    int i = blockIdx.x * 256 + threadIdx.x;
    if (i >= n4) return;
    float4 v = ((const float4*)src)[i];
    ushort4 o; o.x = f2bf(v.x); o.y = f2bf(v.y); o.z = f2bf(v.z); o.w = f2bf(v.w);
    ((ushort4*)dst)[i] = o;
}

__global__ void zero_f32_kernel(float* __restrict__ p, int n)
{
    int i = blockIdx.x * 256 + threadIdx.x;
    if (i < n) p[i] = 0.f;
}

__global__ void landmark_kernel(const unsigned short* __restrict__ src,
                                unsigned short* __restrict__ dstb)
{
    int idx = blockIdx.x * 256 + threadIdx.x;
    if (idx >= MD) return;
    int d = idx % DHD; int rem = idx / DHD; int m = rem % ML; int bh = rem / ML;
    const unsigned short* p = src + ((long long)bh * SEQN + m * LW) * DHD + d;
    float s = 0.f;
#pragma unroll
    for (int j = 0; j < LW; ++j) s += bf2f(p[(long long)j * DHD]);
    dstb[idx] = f2bf(s * (1.f / LW));
}

__global__ void init_scalars_kernel(float* sc)
{
    if (blockIdx.x == 0 && threadIdx.x < 2) sc[threadIdx.x] = 0.f;
}
__global__ void rowsum_max_kernel(const float* __restrict__ A2, float* sc)
{
    int r = blockIdx.x * 256 + threadIdx.x;
    if (r >= BHN * ML) return;
    const float* row = A2 + (long long)r * ML;
    float s = 0.f;
    for (int j = 0; j < ML; ++j) s += fabsf(row[j]);
    atomicMax((unsigned int*)(sc + 0), __float_as_uint(s));
}
__global__ void colsum_max_kernel(const float* __restrict__ A2, float* sc)
{
    int idx = blockIdx.x * 256 + threadIdx.x;
    if (idx >= BHN * ML) return;
    int j = idx % ML, bh = idx / ML;
    const float* base = A2 + (long long)bh * ML * ML + j;
    float s = 0.f;
    for (int i = 0; i < ML; ++i) s += fabsf(base[(long long)i * ML]);
    atomicMax((unsigned int*)(sc + 1), __float_as_uint(s));
}
__global__ void z0_kernel(const float* __restrict__ A2, const float* __restrict__ sc,
                          unsigned short* __restrict__ Z)
{
    long long idx = (long long)blockIdx.x * 256 + threadIdx.x;
    if (idx >= (long long)MM_) return;
    int j = idx % ML; long long rem = idx / ML; int i = (int)(rem % ML); long long bh = rem / ML;
    float inv = 1.f / (sc[0] * sc[1]);
    Z[idx] = f2bf(A2[(bh * ML + j) * ML + i] * inv);
}

// depthwise residual conv on V + head-concat, fused: CT[b,n,h*96+d] = bf16(AO + conv(V))
__global__ void resconv_concat_kernel(const unsigned short* __restrict__ V,
                                      const float* __restrict__ RW,
                                      const float* __restrict__ AO,
                                      unsigned short* __restrict__ CT)
{
    int idx = blockIdx.x * 256 + threadIdx.x;
    if (idx >= BND) return;
    int d = idx % DHD; int rem = idx / DHD; int n = rem % SEQN; int bh = rem / SEQN;
    int h = bh % NH, b = bh / NH;
    const unsigned short* vb = V + (long long)bh * SEQN * DHD + d;
    float s = AO[idx];
#pragma unroll
    for (int j = 0; j < 33; ++j) {
        int sn = n + j - 16;
        if (sn >= 0 && sn < SEQN) s += bf2f(vb[(long long)sn * DHD]) * RW[h * 33 + j];
    }
    CT[((long long)(b * SEQN + n)) * DIMC + h * DHD + d] = f2bf(s);
}

__global__ void sentinel_kernel(float* __restrict__ out, int n)
{
    int i = blockIdx.x * 256 + threadIdx.x;
    if (i < n) out[i] = 1.0e6f;
}

// ---------------- host ----------------
extern "C" void kernel_launch(void* const* d_in, const int* in_sizes, int n_in,
                              void* d_out, int out_size, void* d_ws, size_t ws_size,
                              hipStream_t stream)
{
    (void)in_sizes; (void)n_in;
    const float* x    = (const float*)d_in[0];
    const float* c1w  = (const float*)d_in[1];
    const float* c1b  = (const float*)d_in[2];
    const float* c2w  = (const float*)d_in[3];
    const float* c2b  = (const float*)d_in[4];
    const float* c3w  = (const float*)d_in[5];
    const float* c3b  = (const float*)d_in[6];
    const float* nw   = (const float*)d_in[7];
    const float* nb   = (const float*)d_in[8];
    const float* tw   = (const float*)d_in[9];
    const float* tb   = (const float*)d_in[10];
    const float* qkvw = (const float*)d_in[11];
    const float* outw = (const float*)d_in[12];
    const float* outb = (const float*)d_in[13];
    const float* rcw  = (const float*)d_in[14];
    float* out = (float*)d_out;
    float* ws  = (float*)d_ws;

    // ---------- workspace layout (float units; same extents as round 5/6) ----------
    const int POOLA_F = 7378944;
    const int POOLB_F = 8847360;
    const int POOLC_F = 3538944;
    float* OUT_ACC = ws;                          // BND f32
    float* A2f  = OUT_ACC + BND;                  // MM_ f32
    float* QLf  = A2f + MM_;                      // MD f32 (scratch: R3f32)
    float* KLf  = QLf + MD;                       // MD f32
    float* Zab  = KLf + MD;                       // MM_ f32 (= Za_bf + Zb_bf shorts)
    float* AOf  = Zab + MM_;                      // BND f32 (head of score span)
    float* poolA = AOf + BND;
    float* poolB = poolA + POOLA_F;
    float* poolC = poolB + POOLB_F;
    float* SC   = poolC + POOLC_F;                // 16 f32

    unsigned short* Xpad   = (unsigned short*)poolA;         // [2][3848][768] bf16
    unsigned short* Tbf    = Xpad;                           // alias (post-conv)
    unsigned short* WTbf7  = (unsigned short*)A2f;           // [2304][5376] bf16 (conv phase)
    unsigned short* CONVY16= (unsigned short*)poolB;         // [7680][2304] f16 (conv phase)
    unsigned short* Qbf    = (unsigned short*)poolB;         // BND sh
    unsigned short* Kbf    = Qbf + BND;
    unsigned short* Vbf    = Kbf + BND;
    unsigned short* CTbf   = Kbf;                            // alias (post-attn)
    unsigned short* qkvwb  = (unsigned short*)poolC;         // 3*DD sh
    unsigned short* outwb  = qkvwb + 3*DIMC*DIMC;            // DD sh
    unsigned short* A2bf   = outwb + DIMC*DIMC;              // MM_ sh
    unsigned short* R3bf   = A2bf + MM_;                     // MD sh
    unsigned short* QLbf   = R3bf + MD;                      // MD sh
    unsigned short* KLbf   = QLbf + MD;                      // MD sh
    unsigned short* W2bf   = KLbf + MD;                      // MD sh
    unsigned short* XZbf   = (unsigned short*)A2f;           // MM_ sh (NS phase)
    unsigned short* T1bf   = XZbf + MM_;                     // MM_ sh (ends at A2f+MM_ f32)
    unsigned short* Zabf   = (unsigned short*)Zab;
    unsigned short* Zbbf   = Zabf + MM_;
    unsigned short* Sh     = (unsigned short*)AOf;           // scores: 23.6M sh in AOf+poolA
    float* AOf2  = A2f;                                      // attn out: A2f..Zab end = BND f32
    float* R3f32 = QLf;                                      // split-K accumulator (MD f32)

    size_t need_bytes = (size_t)(SC + 16 - ws) * sizeof(float);
    if (ws_size < need_bytes) {
        sentinel_kernel<<<(out_size + 255)/256, 256, 0, stream>>>(out, out_size);
        return;
    }

    auto mg = [&](const unsigned short* A, int lda, long long sA,
                  const unsigned short* Bm, int ldb, long long sB,
                  int Mr, int Nc, int Kd, float alpha, int convk,
                  int epi, float* Cf, long long sC, int ldc, unsigned short* Cb,
                  const float* bias, unsigned short* Qo, unsigned short* Ko,
                  unsigned short* Vo, int batch) {
        dim3 g((Nc + 127) / 128, Mr / 128, batch), blk(256);
        mgemm_k<<<g, blk, 0, stream>>>(A, lda, sA, Bm, ldb, sB, Mr, Nc, Kd,
            alpha, convk, epi, Cf, sC, ldc, Cb, bias, Qo, Ko, Vo);
    };
    auto mg64 = [&](int bmode, const unsigned short* A, int lda, long long sA,
                    const unsigned short* Bm, int ldb, long long sB,
                    int Mr, int Nc, int Kd, float alpha, int bdiag, float bda,
                    int ksplit, int epi, float* Cf, long long sC, int ldc,
                    unsigned short* Cb, int batch) {
        dim3 g((Nc + 63) / 64, Mr / 64, batch * ksplit), blk(256);
        if (bmode == 0)
            mgemm64_k<0><<<g, blk, 0, stream>>>(A, lda, sA, Bm, ldb, sB, Mr, Nc, Kd,
                alpha, bdiag, bda, ksplit, epi, Cf, sC, ldc, Cb);
        else
            mgemm64_k<1><<<g, blk, 0, stream>>>(A, lda, sA, Bm, ldb, sB, Mr, Nc, Kd,
                alpha, bdiag, bda, ksplit, epi, Cf, sC, ldc, Cb);
    };

    const int DD = DIMC * DIMC;
    const long long sMD = (long long)ML*DHD, sMM = (long long)ML*ML,
                    sND = (long long)SEQN*DHD, sMN = (long long)ML*SEQN;
    const int W7N = DIMC * 7 * DIMC;

    // 0. bf16 conversions: padded X, 7-tap-frame conv weights, qkv/out weights
    pad_x_kernel<<<(BATCH*XPADN*(DIMC/4) + 255)/256, 256, 0, stream>>>(x, Xpad);
    transpose_w7_kernel<<<(W7N + 255)/256, 256, 0, stream>>>(c1w, WTbf7, 3, 0);
    transpose_w7_kernel<<<(W7N + 255)/256, 256, 0, stream>>>(c2w, WTbf7, 5, 1);
    transpose_w7_kernel<<<(W7N + 255)/256, 256, 0, stream>>>(c3w, WTbf7, 7, 2);
    cvt_bf16_kernel<<<(3*DD/4 + 255)/256, 256, 0, stream>>>(qkvw, qkvwb, 3*DD/4);
    cvt_bf16_kernel<<<(DD/4 + 255)/256, 256, 0, stream>>>(outw, outwb, DD/4);

    // 1. merged conv (3 branches in one GEMM, f16 out): [7680][2304]
    mg(Xpad, DIMC, 0, WTbf7, KD7, 0, ROWS, NCOL3, KD7,
       1.f, 7, 4, nullptr, 0, NCOL3, CONVY16, nullptr, nullptr, nullptr, nullptr, 1);

    // 2. fused triple LN+ReLU + residual -> OUT_ACC
    ln_relu_add3_kernel<<<ROWS, 256, 0, stream>>>(CONVY16, c1b, c2b, c3b, nw, nb, x, OUT_ACC);

    // 3. T = ln(OUT_ACC, tnorm) -> bf16 (aliases Xpad)
    ln_kernel<<<ROWS, 256, 0, stream>>>(OUT_ACC, tw, tb, nullptr, Tbf);

    // 4. QKV projection, head-scatter epilogue (overwrites CONVY16)
    mg(Tbf, DIMC, 0, qkvwb, DIMC, 0, ROWS, 3*DIMC, DIMC,
       1.f, 0, 3, nullptr, 0, 0, nullptr, nullptr, Qbf, Kbf, Vbf, 1);

    // 5. landmarks (bf16)
    landmark_kernel<<<(MD + 255)/256, 256, 0, stream>>>(Qbf, QLbf);
    landmark_kernel<<<(MD + 255)/256, 256, 0, stream>>>(Kbf, KLbf);

    // 6. sim2 (64-tile MFMA, f32 out) + softmax -> A2f  (WTbf7 dead)
    mg64(0, QLbf, DHD, sMD, KLbf, DHD, sMD, ML, ML, DHD,
         1.f, 0, 0.f, 1, 0, A2f, sMM, ML, nullptr, BHN);
    softmax_rows<<<BHN*ML, 256, 0, stream>>>(A2f, ML);

    // 7. pinv init: z0 = attn2^T / (max_rowsum * max_colsum); A2 -> bf16
    init_scalars_kernel<<<1, 64, 0, stream>>>(SC);
    rowsum_max_kernel<<<(BHN*ML + 255)/256, 256, 0, stream>>>(A2f, SC);
    colsum_max_kernel<<<(BHN*ML + 255)/256, 256, 0, stream>>>(A2f, SC);
    z0_kernel<<<(MM_ + 255)/256, 256, 0, stream>>>(A2f, SC, Zabf);
    cvt_bf16_kernel<<<(MM_/4 + 255)/256, 256, 0, stream>>>(A2f, A2bf, MM_/4);

    // 8. Newton-Schulz x6 (64-tile bf16 MFMA, 576 blocks/dispatch)
    unsigned short* Zc = Zabf; unsigned short* Zn = Zbbf;
    for (int it = 0; it < 6; ++it) {
        mg64(1, A2bf, ML, sMM, Zc,   ML, sMM, ML, ML, ML, 1.f,   0, 0.f,  1, 2,
             nullptr, sMM, ML, XZbf, BHN);
        mg64(1, XZbf, ML, sMM, XZbf, ML, sMM, ML, ML, ML, 1.f,   1, 7.f,  1, 2,
             nullptr, sMM, ML, Zn,   BHN);
        mg64(1, XZbf, ML, sMM, Zn,   ML, sMM, ML, ML, ML, 1.f,   1, 15.f, 1, 2,
             nullptr, sMM, ML, T1bf, BHN);
        mg64(1, Zc,   ML, sMM, T1bf, ML, sMM, ML, ML, ML, 0.25f, 1, 13.f, 1, 2,
             nullptr, sMM, ML, Zn,   BHN);
        unsigned short* t = Zc; Zc = Zn; Zn = t;
    }

    // 9. sim3 = QL @ K^T (f16 scores) -> softmax (bf16 probs) -> R3 = P @ V (split-K x4)
    mg(QLbf, DHD, sMD, Kbf, DHD, sND, ML, SEQN, DHD,
       1.f, 0, 4, nullptr, sMN, SEQN, Sh, nullptr, nullptr, nullptr, nullptr, BHN);
    softmax_h2b<15><<<BHN*ML, 256, 0, stream>>>(Sh, SEQN);
    zero_f32_kernel<<<(MD + 255)/256, 256, 0, stream>>>(R3f32, MD);
    mg64(1, Sh, SEQN, sMN, Vbf, DHD, sND, ML, DHD, SEQN,
         1.f, 0, 0.f, 4, 5, R3f32, sMD, DHD, nullptr, BHN);
    cvt_bf16_kernel<<<(MD/4 + 255)/256, 256, 0, stream>>>(R3f32, R3bf, MD/4);

    // 10. W2 = pinv(attn2) @ R3
    mg64(1, Zc, ML, sMM, R3bf, DHD, sMD, ML, DHD, ML,
         1.f, 0, 0.f, 1, 2, nullptr, sMD, DHD, W2bf, BHN);

    // 11. sim1 = Q @ KL^T (f16 scores) -> softmax (bf16) -> AO = P @ W2 (f32)
    mg(Qbf, DHD, sND, KLbf, DHD, sMD, SEQN, ML, DHD,
       1.f, 0, 4, nullptr, sMN, ML, Sh, nullptr, nullptr, nullptr, nullptr, BHN);
    softmax_h2b<2><<<BHN*SEQN, 256, 0, stream>>>(Sh, ML);
    mg64(1, Sh, ML, sMN, W2bf, DHD, sMD, SEQN, DHD, ML,
         1.f, 0, 0.f, 1, 0, AOf2, sND, DHD, nullptr, BHN);

    // 12. residual depthwise conv on V + head-concat (fused) -> CTbf
    resconv_concat_kernel<<<(BND + 255)/256, 256, 0, stream>>>(Vbf, rcw, AOf2, CTbf);

    // 13. out projection + bias, accumulate into OUT_ACC (outer residual)
    mg(CTbf, DIMC, 0, outwb, DIMC, 0, ROWS, DIMC, DIMC,
       1.f, 0, 1, OUT_ACC, 0, DIMC, nullptr, outb, nullptr, nullptr, nullptr, 1);

    // 14. final layernorm -> d_out
    ln_kernel<<<ROWS, 256, 0, stream>>>(OUT_ACC, nw, nb, out, nullptr);
}

// Round 8
// 1502.731 us; speedup vs baseline: 3.4113x; 1.1379x over previous
//
#include <hip/hip_runtime.h>

#define SEQN 3840
#define BATCH 2
#define DIMC 768
#define NH 8
#define DHD 96
#define ML 384
#define LW 10
#define BHN 16
#define ROWS (BATCH*SEQN)
#define PADX 4
#define XPADN (SEQN + 2*PADX)   // 3848
#define NCOL3 (3*DIMC)          // 2304 merged-conv output cols
#define KD7 (7*DIMC)            // 5376 merged-conv K depth

static const int BND = BATCH*SEQN*DIMC;   // 5,898,240
static const int MD  = BHN*ML*DHD;        // 589,824
static const int MM_ = BHN*ML*ML;         // 2,359,296

// ---------------- scalar helpers ----------------
__device__ __forceinline__ unsigned short f2bf(float f) {
    unsigned int u = __float_as_uint(f);
    u = (u + 0x7FFF + ((u >> 16) & 1)) >> 16;   // RNE
    return (unsigned short)u;
}
__device__ __forceinline__ float bf2f(unsigned short s) {
    return __uint_as_float(((unsigned int)s) << 16);
}
__device__ __forceinline__ unsigned short f2h(float f) {
    _Float16 h = (_Float16)f;
    return *(unsigned short*)&h;
}
__device__ __forceinline__ float h2f(unsigned short u) {
    _Float16 h = *(_Float16*)&u;
    return (float)h;
}

// ---------------- reductions ----------------
__device__ __forceinline__ float wave_sum(float v) {
#pragma unroll
    for (int m = 32; m; m >>= 1) v += __shfl_xor(v, m, 64);
    return v;
}
__device__ __forceinline__ float wave_max(float v) {
#pragma unroll
    for (int m = 32; m; m >>= 1) v = fmaxf(v, __shfl_xor(v, m, 64));
    return v;
}

typedef short bf16x8 __attribute__((ext_vector_type(8)));
typedef float f32x4 __attribute__((ext_vector_type(4)));
#define ROWP 40   // LDS row pitch in shorts (mgemm64 only)

// 16B async global->LDS DMA: LDS dest = wave-uniform base + lane*16
#define GLOAD_LDS16(gp, lp) __builtin_amdgcn_global_load_lds( \
    (const __attribute__((address_space(1))) void*)(gp), \
    (__attribute__((address_space(3))) void*)(lp), 16, 0, 0)

// ================= 128x128 bf16 MFMA GEMM (BT; big shapes) =================
// All call sites: Mr % 128 == 0, Nc % 128 == 0, Kd % 32 == 0.
// C = alpha * A @ B^T ; A bf16 [Mr][Kd] (or implicit conv im2col of padded X, conv_k=7)
// epi: 0 f32 store; 1 f32 C += v + bias; 3 QKV head-scatter (bf16); 4 f16 store
// Staging: global_load_lds direct DMA, linear LDS [128][32] shorts, XOR chunk swizzle
// (chunk' = chunk ^ ((row>>1)&3)) applied at both stage (source addr) and read.
__global__ __launch_bounds__(256) void mgemm_k(
    const unsigned short* __restrict__ A, int lda, long long sA,
    const unsigned short* __restrict__ Bm, int ldb, long long sB,
    int Mr, int Nc, int Kd, float alpha, int conv_k,
    int epi, float* __restrict__ Cf, long long sC, int ldc,
    unsigned short* __restrict__ Cb, const float* __restrict__ bias,
    unsigned short* __restrict__ Qo, unsigned short* __restrict__ Ko,
    unsigned short* __restrict__ Vo)
{
    __shared__ unsigned short As[128*32] __attribute__((aligned(16)));
    __shared__ unsigned short Bs[128*32] __attribute__((aligned(16)));
    const int bz = blockIdx.z;
    const long long aoff = (long long)bz * sA, boff = (long long)bz * sB;
    const long long coff = (long long)bz * sC;
    const int i0 = blockIdx.y * 128, j0 = blockIdx.x * 128;
    const int tid = threadIdx.x;
    const int w = tid >> 6, l = tid & 63;
    const int wr = (w >> 1) << 6, wc = (w & 1) << 6;
    const int lr = l & 15, lk = l >> 4;
    const int khalf = conv_k >> 1;

    // staging geometry: wave w, pass p stages seg = p*4+w (16 rows = 1 KB);
    // lane l covers LDS row seg*16 + (l>>2), physical chunk (l&3).
    const int lrow4  = l >> 2;
    const int lchunk = (l & 3) ^ ((lrow4 >> 1) & 3);   // logical chunk this lane fetches
    // fragment-read physical chunk (lane-constant across frags)
    const int pcr = lk ^ ((lr >> 1) & 3);

    // conv: batch index is uniform per block (SEQN % 128 == 0)
    const int cb_ = conv_k ? (i0 / SEQN) : 0;
    const int cn0 = conv_k ? (i0 - cb_ * SEQN) : 0;

    f32x4 acc[4][4] = {};

    for (int k0 = 0; k0 < Kd; k0 += 32) {
#pragma unroll
        for (int p = 0; p < 2; ++p) {
            const int seg = p * 4 + w;
            const int row = seg * 16 + lrow4;
            long long ga;
            if (conv_k) {
                const int tap = k0 / DIMC, c = k0 - tap * DIMC;   // 32-chunks never straddle a tap
                ga = ((long long)(cb_ * XPADN + cn0 + row + tap + PADX - khalf)) * DIMC
                     + c + lchunk * 8;
            } else {
                ga = aoff + (long long)(i0 + row) * lda + k0 + lchunk * 8;
            }
            GLOAD_LDS16(A + ga, As + seg * 512);
            const long long gb = boff + (long long)(j0 + row) * ldb + k0 + lchunk * 8;
            GLOAD_LDS16(Bm + gb, Bs + seg * 512);
        }
        __syncthreads();   // drains vmcnt(0): DMA complete, tile visible
        bf16x8 af[4], bfv[4];
#pragma unroll
        for (int fi = 0; fi < 4; ++fi)
            af[fi] = *(const bf16x8*)&As[(wr + fi * 16 + lr) * 32 + pcr * 8];
#pragma unroll
        for (int fj = 0; fj < 4; ++fj)
            bfv[fj] = *(const bf16x8*)&Bs[(wc + fj * 16 + lr) * 32 + pcr * 8];
#pragma unroll
        for (int fi = 0; fi < 4; ++fi)
#pragma unroll
            for (int fj = 0; fj < 4; ++fj)
                acc[fi][fj] = __builtin_amdgcn_mfma_f32_16x16x32_bf16(
                    af[fi], bfv[fj], acc[fi][fj], 0, 0, 0);
        __syncthreads();   // all reads done before next iter's DMA overwrites
    }
    // ---- epilogue ----
#pragma unroll
    for (int fi = 0; fi < 4; ++fi) {
#pragma unroll
        for (int fj = 0; fj < 4; ++fj) {
            const int col = j0 + wc + fj * 16 + lr;
#pragma unroll
            for (int r = 0; r < 4; ++r) {
                const int row = i0 + wr + fi * 16 + lk * 4 + r;
                float v = acc[fi][fj][r] * alpha;
                if (epi == 0) {
                    Cf[coff + (long long)row * ldc + col] = v;
                } else if (epi == 1) {
                    const long long ix = coff + (long long)row * ldc + col;
                    Cf[ix] = Cf[ix] + v + bias[col];
                } else if (epi == 4) {
                    Cb[coff + (long long)row * ldc + col] = f2h(v);
                } else {
                    const int which = col / DIMC;
                    const int c = col - which * DIMC;
                    const int h = c / DHD, d = c - h * DHD;
                    const int b = row / SEQN, n = row - b * SEQN;
                    const long long o = (((long long)(b * NH + h)) * SEQN + n) * DHD + d;
                    if (which == 0)      Qo[o] = f2bf(v * 0.10206207261596575f);
                    else if (which == 1) Ko[o] = f2bf(v);
                    else                 Vo[o] = f2bf(v);
                }
            }
        }
    }
}

// ================= 64x64 bf16 MFMA GEMM (small/batched shapes) =================
// BMODE 0: B^T from B[N][K]; BMODE 1: NN from B[K][N], optional bdiag: B'=(k==j?bda:0)-B
// epi: 0 f32 store; 2 bf16 store; 5 f32 atomicAdd (for split-K)
template<int BMODE>
__global__ __launch_bounds__(256) void mgemm64_k(
    const unsigned short* __restrict__ A, int lda, long long sA,
    const unsigned short* __restrict__ Bm, int ldb, long long sB,
    int Mr, int Nc, int Kd, float alpha, int bdiag, float bda, int ksplit,
    int epi, float* __restrict__ Cf, long long sC, int ldc,
    unsigned short* __restrict__ Cb)
{
    __shared__ unsigned short As[64*ROWP] __attribute__((aligned(16)));
    __shared__ unsigned short Bs[64*ROWP] __attribute__((aligned(16)));
    const int bz = blockIdx.z / ksplit;
    const int kch = blockIdx.z - bz * ksplit;
    const long long aoff = (long long)bz * sA, boff = (long long)bz * sB;
    const long long coff = (long long)bz * sC;
    const int i0 = blockIdx.y * 64, j0 = blockIdx.x * 64;
    const int tid = threadIdx.x;
    const int w = tid >> 6, l = tid & 63;
    const int lr = l & 15, lk = l >> 4;
    const int klen = Kd / ksplit;
    const int kbeg = kch * klen, kend = kbeg + klen;

    f32x4 acc[4] = {};

    for (int k0 = kbeg; k0 < kend; k0 += 32) {
        {
            const int row = tid >> 2, seg = (tid & 3) << 3;
            *(uint4*)&As[row*ROWP+seg] =
                *(const uint4*)&A[aoff + (long long)(i0+row)*lda + k0 + seg];
        }
        if (BMODE == 0) {
            const int row = tid >> 2, seg = (tid & 3) << 3;
            const int gj = j0 + row;
            uint4 v;
            if (gj < Nc) v = *(const uint4*)&Bm[boff + (long long)gj*ldb + k0 + seg];
            else { v.x=v.y=v.z=v.w=0u; }
            *(uint4*)&Bs[row*ROWP+seg] = v;
        } else {
            const int kk = tid >> 3, j8 = (tid & 7) << 3;
            const int gk = k0 + kk, gj0 = j0 + j8;
            unsigned short buf[8];
            if (gj0 + 8 <= Nc) {
                *(uint4*)&buf[0] = *(const uint4*)&Bm[boff + (long long)gk*ldb + gj0];
                if (bdiag) {
#pragma unroll
                    for (int u = 0; u < 8; ++u) {
                        float v = ((gk == gj0+u) ? bda : 0.f) - bf2f(buf[u]);
                        buf[u] = f2bf(v);
                    }
                }
            } else {
#pragma unroll
                for (int u = 0; u < 8; ++u) buf[u] = 0;
            }
#pragma unroll
            for (int u = 0; u < 8; ++u) Bs[(j8+u)*ROWP + kk] = buf[u];
        }
        __syncthreads();
        bf16x8 af = *(const bf16x8*)&As[(w*16+lr)*ROWP + lk*8];
        bf16x8 b0 = *(const bf16x8*)&Bs[(lr)*ROWP + lk*8];
        bf16x8 b1 = *(const bf16x8*)&Bs[(16+lr)*ROWP + lk*8];
        bf16x8 b2 = *(const bf16x8*)&Bs[(32+lr)*ROWP + lk*8];
        bf16x8 b3 = *(const bf16x8*)&Bs[(48+lr)*ROWP + lk*8];
        acc[0] = __builtin_amdgcn_mfma_f32_16x16x32_bf16(af, b0, acc[0], 0,0,0);
        acc[1] = __builtin_amdgcn_mfma_f32_16x16x32_bf16(af, b1, acc[1], 0,0,0);
        acc[2] = __builtin_amdgcn_mfma_f32_16x16x32_bf16(af, b2, acc[2], 0,0,0);
        acc[3] = __builtin_amdgcn_mfma_f32_16x16x32_bf16(af, b3, acc[3], 0,0,0);
        __syncthreads();
    }
#pragma unroll
    for (int fj = 0; fj < 4; ++fj) {
        const int col = j0 + fj*16 + lr;
        if (col >= Nc) continue;
#pragma unroll
        for (int r = 0; r < 4; ++r) {
            const int row = i0 + w*16 + lk*4 + r;
            float v = acc[fj][r] * alpha;
            if (epi == 0)      Cf[coff + (long long)row*ldc + col] = v;
            else if (epi == 2) Cb[coff + (long long)row*ldc + col] = f2bf(v);
            else               atomicAdd(&Cf[coff + (long long)row*ldc + col], v);
        }
    }
}

// ---------------- row softmax: f16 scores in, bf16 probs out, in place ----------------
template<int NV>
__global__ __launch_bounds__(256) void softmax_h2b(unsigned short* __restrict__ data, int W)
{
    __shared__ float red[4];
    const long long r = blockIdx.x;
    unsigned short* row = data + r * (long long)W;
    const int t = threadIdx.x, lane = t & 63, wid = t >> 6;
    float v[NV];
    float mx = -3.4e38f;
#pragma unroll
    for (int i = 0; i < NV; ++i) {
        const int j = t + i * 256;
        float f = -3.4e38f;
        if (j < W) f = h2f(row[j]);
        v[i] = f;
        mx = fmaxf(mx, f);
    }
    mx = wave_max(mx);
    if (lane == 0) red[wid] = mx;
    __syncthreads();
    mx = fmaxf(fmaxf(red[0], red[1]), fmaxf(red[2], red[3]));
    __syncthreads();
    float s = 0.f;
#pragma unroll
    for (int i = 0; i < NV; ++i) {
        v[i] = __expf(v[i] - mx);
        s += v[i];
    }
    s = wave_sum(s);
    if (lane == 0) red[wid] = s;
    __syncthreads();
    s = red[0] + red[1] + red[2] + red[3];
    const float inv = 1.f / s;
#pragma unroll
    for (int i = 0; i < NV; ++i) {
        const int j = t + i * 256;
        if (j < W) row[j] = f2bf(v[i] * inv);
    }
}

// ---------------- LayerNorm (row = 768), dual-dtype output ----------------
__global__ __launch_bounds__(256) void ln_kernel(
    const float* __restrict__ in, const float* __restrict__ w,
    const float* __restrict__ b, float* __restrict__ outf,
    unsigned short* __restrict__ outb)
{
    __shared__ float red[4];
    const long long r = blockIdx.x;
    const float* row = in + r * DIMC;
    const int t = threadIdx.x, lane = t & 63, wid = t >> 6;
    float x0 = row[t], x1 = row[t+256], x2 = row[t+512];
    float s = wave_sum(x0 + x1 + x2);
    if (lane == 0) red[wid] = s;
    __syncthreads();
    float mu = (red[0]+red[1]+red[2]+red[3]) * (1.f/DIMC);
    __syncthreads();
    float d0 = x0-mu, d1 = x1-mu, d2 = x2-mu;
    float q = wave_sum(d0*d0 + d1*d1 + d2*d2);
    if (lane == 0) red[wid] = q;
    __syncthreads();
    float rs = rsqrtf((red[0]+red[1]+red[2]+red[3]) * (1.f/DIMC) + 1e-5f);
    float v0 = d0*rs*w[t]     + b[t];
    float v1 = d1*rs*w[t+256] + b[t+256];
    float v2 = d2*rs*w[t+512] + b[t+512];
    if (outf) {
        float* o = outf + r * DIMC;
        o[t] = v0; o[t+256] = v1; o[t+512] = v2;
    }
    if (outb) {
        unsigned short* o = outb + r * DIMC;
        o[t] = f2bf(v0); o[t+256] = f2bf(v1); o[t+512] = f2bf(v2);
    }
}

// ---------------- merged conv epilogue: acc = x + sum_s relu(ln(y_s+cb_s)) ----------------
__global__ __launch_bounds__(256) void ln_relu_add3_kernel(
    const unsigned short* __restrict__ Y16,   // [rows][2304] f16
    const float* __restrict__ cb0, const float* __restrict__ cb1,
    const float* __restrict__ cb2,
    const float* __restrict__ w, const float* __restrict__ b,
    const float* __restrict__ xin, float* __restrict__ acc)
{
    __shared__ float red[4];
    const long long r = blockIdx.x;
    const unsigned short* row = Y16 + r * NCOL3;
    const int t = threadIdx.x, lane = t & 63, wid = t >> 6;
    const float* xr = xin + r * DIMC;
    float o0 = xr[t], o1 = xr[t+256], o2 = xr[t+512];
    const float* cbs[3] = {cb0, cb1, cb2};
#pragma unroll
    for (int s = 0; s < 3; ++s) {
        const float* cb = cbs[s];
        float x0 = h2f(row[s*DIMC + t])     + cb[t];
        float x1 = h2f(row[s*DIMC + t+256]) + cb[t+256];
        float x2 = h2f(row[s*DIMC + t+512]) + cb[t+512];
        float su = wave_sum(x0 + x1 + x2);
        __syncthreads();
        if (lane == 0) red[wid] = su;
        __syncthreads();
        float mu = (red[0]+red[1]+red[2]+red[3]) * (1.f/DIMC);
        float d0 = x0-mu, d1 = x1-mu, d2 = x2-mu;
        float q = wave_sum(d0*d0 + d1*d1 + d2*d2);
        __syncthreads();
        if (lane == 0) red[wid] = q;
        __syncthreads();
        float rs = rsqrtf((red[0]+red[1]+red[2]+red[3]) * (1.f/DIMC) + 1e-5f);
        o0 += fmaxf(d0*rs*w[t]     + b[t],     0.f);
        o1 += fmaxf(d1*rs*w[t+256] + b[t+256], 0.f);
        o2 += fmaxf(d2*rs*w[t+512] + b[t+512], 0.f);
    }
    float* ar = acc + r * DIMC;
    ar[t] = o0; ar[t+256] = o1; ar[t+512] = o2;
}

// ---------------- row softmax (in-place, f32, W=384 for attn2) ----------------
__global__ __launch_bounds__(256) void softmax_rows(float* __restrict__ data, int W)
{
    __shared__ float red[4];
    const long long r = blockIdx.x;
    float* row = data + r * (long long)W;
    const int t = threadIdx.x, lane = t & 63, wid = t >> 6;
    float mx = -3.4e38f;
    for (int j = t; j < W; j += 256) mx = fmaxf(mx, row[j]);
    mx = wave_max(mx);
    if (lane == 0) red[wid] = mx;
    __syncthreads();
    mx = fmaxf(fmaxf(red[0], red[1]), fmaxf(red[2], red[3]));
    __syncthreads();
    float s = 0.f;
    for (int j = t; j < W; j += 256) s += __expf(row[j] - mx);
    s = wave_sum(s);
    if (lane == 0) red[wid] = s;
    __syncthreads();
    s = red[0]+red[1]+red[2]+red[3];
    const float inv = 1.f / s;
    for (int j = t; j < W; j += 256) row[j] = __expf(row[j] - mx) * inv;
}

// ---------------- small helpers ----------------
__global__ void pad_x_kernel(const float* __restrict__ x, unsigned short* __restrict__ xp)
{
    int i = blockIdx.x * 256 + threadIdx.x;
    if (i >= BATCH * XPADN * (DIMC/4)) return;
    int e = i * 4;
    int c = e % DIMC; int rr = e / DIMC; int pr = rr % XPADN; int b = rr / XPADN;
    int n = pr - PADX;
    ushort4 o;
    if (n < 0 || n >= SEQN) { o.x = o.y = o.z = o.w = 0; }
    else {
        float4 v = *(const float4*)&x[((long long)(b * SEQN + n)) * DIMC + c];
        o.x = f2bf(v.x); o.y = f2bf(v.y); o.z = f2bf(v.z); o.w = f2bf(v.w);
    }
    *(ushort4*)&xp[e] = o;
}

// conv weight [O][I][K] -> bf16 7-tap frame rows: WT[(branch*768+o)][tap][i]
__global__ void transpose_w7_kernel(const float* __restrict__ W,
                                    unsigned short* __restrict__ WT, int K, int branch)
{
    int idx = blockIdx.x * 256 + threadIdx.x;
    if (idx >= DIMC * 7 * DIMC) return;
    int i = idx % DIMC; int rem = idx / DIMC; int t = rem % 7; int o = rem / 7;
    int k = t - (3 - (K >> 1));
    float v = (k >= 0 && k < K) ? W[((long long)o * DIMC + i) * K + k] : 0.f;
    WT[((long long)(branch * DIMC + o)) * KD7 + t * DIMC + i] = f2bf(v);
}

__global__ void cvt_bf16_kernel(const float* __restrict__ src,
                                unsigned short* __restrict__ dst, int n4)
{
    int i = blockIdx.x * 256 + threadIdx.x;
    if (i >= n4) return;
    float4 v = ((const float4*)src)[i];
    ushort4 o; o.x = f2bf(v.x); o.y = f2bf(v.y); o.z = f2bf(v.z); o.w = f2bf(v.w);
    ((ushort4*)dst)[i] = o;
}

__global__ void zero_f32_kernel(float* __restrict__ p, int n)
{
    int i = blockIdx.x * 256 + threadIdx.x;
    if (i < n) p[i] = 0.f;
}

__global__ void landmark_kernel(const unsigned short* __restrict__ src,
                                unsigned short* __restrict__ dstb)
{
    int idx = blockIdx.x * 256 + threadIdx.x;
    if (idx >= MD) return;
    int d = idx % DHD; int rem = idx / DHD; int m = rem % ML; int bh = rem / ML;
    const unsigned short* p = src + ((long long)bh * SEQN + m * LW) * DHD + d;
    float s = 0.f;
#pragma unroll
    for (int j = 0; j < LW; ++j) s += bf2f(p[(long long)j * DHD]);
    dstb[idx] = f2bf(s * (1.f / LW));
}

__global__ void init_scalars_kernel(float* sc)
{
    if (blockIdx.x == 0 && threadIdx.x < 2) sc[threadIdx.x] = 0.f;
}
__global__ void rowsum_max_kernel(const float* __restrict__ A2, float* sc)
{
    int r = blockIdx.x * 256 + threadIdx.x;
    if (r >= BHN * ML) return;
    const float* row = A2 + (long long)r * ML;
    float s = 0.f;
    for (int j = 0; j < ML; ++j) s += fabsf(row[j]);
    atomicMax((unsigned int*)(sc + 0), __float_as_uint(s));
}
__global__ void colsum_max_kernel(const float* __restrict__ A2, float* sc)
{
    int idx = blockIdx.x * 256 + threadIdx.x;
    if (idx >= BHN * ML) return;
    int j = idx % ML, bh = idx / ML;
    const float* base = A2 + (long long)bh * ML * ML + j;
    float s = 0.f;
    for (int i = 0; i < ML; ++i) s += fabsf(base[(long long)i * ML]);
    atomicMax((unsigned int*)(sc + 1), __float_as_uint(s));
}
__global__ void z0_kernel(const float* __restrict__ A2, const float* __restrict__ sc,
                          unsigned short* __restrict__ Z)
{
    long long idx = (long long)blockIdx.x * 256 + threadIdx.x;
    if (idx >= (long long)MM_) return;
    int j = idx % ML; long long rem = idx / ML; int i = (int)(rem % ML); long long bh = rem / ML;
    float inv = 1.f / (sc[0] * sc[1]);
    Z[idx] = f2bf(A2[(bh * ML + j) * ML + i] * inv);
}

// depthwise residual conv on V + head-concat, fused: CT[b,n,h*96+d] = bf16(AO + conv(V))
__global__ void resconv_concat_kernel(const unsigned short* __restrict__ V,
                                      const float* __restrict__ RW,
                                      const float* __restrict__ AO,
                                      unsigned short* __restrict__ CT)
{
    int idx = blockIdx.x * 256 + threadIdx.x;
    if (idx >= BND) return;
    int d = idx % DHD; int rem = idx / DHD; int n = rem % SEQN; int bh = rem / SEQN;
    int h = bh % NH, b = bh / NH;
    const unsigned short* vb = V + (long long)bh * SEQN * DHD + d;
    float s = AO[idx];
#pragma unroll
    for (int j = 0; j < 33; ++j) {
        int sn = n + j - 16;
        if (sn >= 0 && sn < SEQN) s += bf2f(vb[(long long)sn * DHD]) * RW[h * 33 + j];
    }
    CT[((long long)(b * SEQN + n)) * DIMC + h * DHD + d] = f2bf(s);
}

__global__ void sentinel_kernel(float* __restrict__ out, int n)
{
    int i = blockIdx.x * 256 + threadIdx.x;
    if (i < n) out[i] = 1.0e6f;
}

// ---------------- host ----------------
extern "C" void kernel_launch(void* const* d_in, const int* in_sizes, int n_in,
                              void* d_out, int out_size, void* d_ws, size_t ws_size,
                              hipStream_t stream)
{
    (void)in_sizes; (void)n_in;
    const float* x    = (const float*)d_in[0];
    const float* c1w  = (const float*)d_in[1];
    const float* c1b  = (const float*)d_in[2];
    const float* c2w  = (const float*)d_in[3];
    const float* c2b  = (const float*)d_in[4];
    const float* c3w  = (const float*)d_in[5];
    const float* c3b  = (const float*)d_in[6];
    const float* nw   = (const float*)d_in[7];
    const float* nb   = (const float*)d_in[8];
    const float* tw   = (const float*)d_in[9];
    const float* tb   = (const float*)d_in[10];
    const float* qkvw = (const float*)d_in[11];
    const float* outw = (const float*)d_in[12];
    const float* outb = (const float*)d_in[13];
    const float* rcw  = (const float*)d_in[14];
    float* out = (float*)d_out;
    float* ws  = (float*)d_ws;

    // ---------- workspace layout (float units; same extents as round 6/7) ----------
    const int POOLA_F = 7378944;
    const int POOLB_F = 8847360;
    const int POOLC_F = 3538944;
    float* OUT_ACC = ws;                          // BND f32
    float* A2f  = OUT_ACC + BND;                  // MM_ f32
    float* QLf  = A2f + MM_;                      // MD f32 (scratch: R3f32)
    float* KLf  = QLf + MD;                       // MD f32
    float* Zab  = KLf + MD;                       // MM_ f32 (= Za_bf + Zb_bf shorts)
    float* AOf  = Zab + MM_;                      // BND f32 (head of score span)
    float* poolA = AOf + BND;
    float* poolB = poolA + POOLA_F;
    float* poolC = poolB + POOLB_F;
    float* SC   = poolC + POOLC_F;                // 16 f32

    unsigned short* Xpad   = (unsigned short*)poolA;         // [2][3848][768] bf16
    unsigned short* Tbf    = Xpad;                           // alias (post-conv)
    unsigned short* WTbf7  = (unsigned short*)A2f;           // [2304][5376] bf16 (conv phase)
    unsigned short* CONVY16= (unsigned short*)poolB;         // [7680][2304] f16 (conv phase)
    unsigned short* Qbf    = (unsigned short*)poolB;         // BND sh
    unsigned short* Kbf    = Qbf + BND;
    unsigned short* Vbf    = Kbf + BND;
    unsigned short* CTbf   = Kbf;                            // alias (post-attn)
    unsigned short* qkvwb  = (unsigned short*)poolC;         // 3*DD sh
    unsigned short* outwb  = qkvwb + 3*DIMC*DIMC;            // DD sh
    unsigned short* A2bf   = outwb + DIMC*DIMC;              // MM_ sh
    unsigned short* R3bf   = A2bf + MM_;                     // MD sh
    unsigned short* QLbf   = R3bf + MD;                      // MD sh
    unsigned short* KLbf   = QLbf + MD;                      // MD sh
    unsigned short* W2bf   = KLbf + MD;                      // MD sh
    unsigned short* XZbf   = (unsigned short*)A2f;           // MM_ sh (NS phase)
    unsigned short* T1bf   = XZbf + MM_;                     // MM_ sh
    unsigned short* Zabf   = (unsigned short*)Zab;
    unsigned short* Zbbf   = Zabf + MM_;
    unsigned short* Sh     = (unsigned short*)AOf;           // scores: 23.6M sh in AOf+poolA
    float* AOf2  = A2f;                                      // attn out: BND f32
    float* R3f32 = QLf;                                      // split-K accumulator (MD f32)

    size_t need_bytes = (size_t)(SC + 16 - ws) * sizeof(float);
    if (ws_size < need_bytes) {
        sentinel_kernel<<<(out_size + 255)/256, 256, 0, stream>>>(out, out_size);
        return;
    }

    auto mg = [&](const unsigned short* A, int lda, long long sA,
                  const unsigned short* Bm, int ldb, long long sB,
                  int Mr, int Nc, int Kd, float alpha, int convk,
                  int epi, float* Cf, long long sC, int ldc, unsigned short* Cb,
                  const float* bias, unsigned short* Qo, unsigned short* Ko,
                  unsigned short* Vo, int batch) {
        dim3 g((Nc + 127) / 128, Mr / 128, batch), blk(256);
        mgemm_k<<<g, blk, 0, stream>>>(A, lda, sA, Bm, ldb, sB, Mr, Nc, Kd,
            alpha, convk, epi, Cf, sC, ldc, Cb, bias, Qo, Ko, Vo);
    };
    auto mg64 = [&](int bmode, const unsigned short* A, int lda, long long sA,
                    const unsigned short* Bm, int ldb, long long sB,
                    int Mr, int Nc, int Kd, float alpha, int bdiag, float bda,
                    int ksplit, int epi, float* Cf, long long sC, int ldc,
                    unsigned short* Cb, int batch) {
        dim3 g((Nc + 63) / 64, Mr / 64, batch * ksplit), blk(256);
        if (bmode == 0)
            mgemm64_k<0><<<g, blk, 0, stream>>>(A, lda, sA, Bm, ldb, sB, Mr, Nc, Kd,
                alpha, bdiag, bda, ksplit, epi, Cf, sC, ldc, Cb);
        else
            mgemm64_k<1><<<g, blk, 0, stream>>>(A, lda, sA, Bm, ldb, sB, Mr, Nc, Kd,
                alpha, bdiag, bda, ksplit, epi, Cf, sC, ldc, Cb);
    };

    const int DD = DIMC * DIMC;
    const long long sMD = (long long)ML*DHD, sMM = (long long)ML*ML,
                    sND = (long long)SEQN*DHD, sMN = (long long)ML*SEQN;
    const int W7N = DIMC * 7 * DIMC;

    // 0. bf16 conversions: padded X, 7-tap-frame conv weights, qkv/out weights
    pad_x_kernel<<<(BATCH*XPADN*(DIMC/4) + 255)/256, 256, 0, stream>>>(x, Xpad);
    transpose_w7_kernel<<<(W7N + 255)/256, 256, 0, stream>>>(c1w, WTbf7, 3, 0);
    transpose_w7_kernel<<<(W7N + 255)/256, 256, 0, stream>>>(c2w, WTbf7, 5, 1);
    transpose_w7_kernel<<<(W7N + 255)/256, 256, 0, stream>>>(c3w, WTbf7, 7, 2);
    cvt_bf16_kernel<<<(3*DD/4 + 255)/256, 256, 0, stream>>>(qkvw, qkvwb, 3*DD/4);
    cvt_bf16_kernel<<<(DD/4 + 255)/256, 256, 0, stream>>>(outw, outwb, DD/4);

    // 1. merged conv (3 branches in one GEMM, f16 out): [7680][2304]
    mg(Xpad, DIMC, 0, WTbf7, KD7, 0, ROWS, NCOL3, KD7,
       1.f, 7, 4, nullptr, 0, NCOL3, CONVY16, nullptr, nullptr, nullptr, nullptr, 1);

    // 2. fused triple LN+ReLU + residual -> OUT_ACC
    ln_relu_add3_kernel<<<ROWS, 256, 0, stream>>>(CONVY16, c1b, c2b, c3b, nw, nb, x, OUT_ACC);

    // 3. T = ln(OUT_ACC, tnorm) -> bf16 (aliases Xpad)
    ln_kernel<<<ROWS, 256, 0, stream>>>(OUT_ACC, tw, tb, nullptr, Tbf);

    // 4. QKV projection, head-scatter epilogue (overwrites CONVY16)
    mg(Tbf, DIMC, 0, qkvwb, DIMC, 0, ROWS, 3*DIMC, DIMC,
       1.f, 0, 3, nullptr, 0, 0, nullptr, nullptr, Qbf, Kbf, Vbf, 1);

    // 5. landmarks (bf16)
    landmark_kernel<<<(MD + 255)/256, 256, 0, stream>>>(Qbf, QLbf);
    landmark_kernel<<<(MD + 255)/256, 256, 0, stream>>>(Kbf, KLbf);

    // 6. sim2 (64-tile MFMA, f32 out) + softmax -> A2f
    mg64(0, QLbf, DHD, sMD, KLbf, DHD, sMD, ML, ML, DHD,
         1.f, 0, 0.f, 1, 0, A2f, sMM, ML, nullptr, BHN);
    softmax_rows<<<BHN*ML, 256, 0, stream>>>(A2f, ML);

    // 7. pinv init: z0 = attn2^T / (max_rowsum * max_colsum); A2 -> bf16
    init_scalars_kernel<<<1, 64, 0, stream>>>(SC);
    rowsum_max_kernel<<<(BHN*ML + 255)/256, 256, 0, stream>>>(A2f, SC);
    colsum_max_kernel<<<(BHN*ML + 255)/256, 256, 0, stream>>>(A2f, SC);
    z0_kernel<<<(MM_ + 255)/256, 256, 0, stream>>>(A2f, SC, Zabf);
    cvt_bf16_kernel<<<(MM_/4 + 255)/256, 256, 0, stream>>>(A2f, A2bf, MM_/4);

    // 8. Newton-Schulz x6 (64-tile bf16 MFMA)
    unsigned short* Zc = Zabf; unsigned short* Zn = Zbbf;
    for (int it = 0; it < 6; ++it) {
        mg64(1, A2bf, ML, sMM, Zc,   ML, sMM, ML, ML, ML, 1.f,   0, 0.f,  1, 2,
             nullptr, sMM, ML, XZbf, BHN);
        mg64(1, XZbf, ML, sMM, XZbf, ML, sMM, ML, ML, ML, 1.f,   1, 7.f,  1, 2,
             nullptr, sMM, ML, Zn,   BHN);
        mg64(1, XZbf, ML, sMM, Zn,   ML, sMM, ML, ML, ML, 1.f,   1, 15.f, 1, 2,
             nullptr, sMM, ML, T1bf, BHN);
        mg64(1, Zc,   ML, sMM, T1bf, ML, sMM, ML, ML, ML, 0.25f, 1, 13.f, 1, 2,
             nullptr, sMM, ML, Zn,   BHN);
        unsigned short* t = Zc; Zc = Zn; Zn = t;
    }

    // 9. sim3 = QL @ K^T (f16 scores) -> softmax (bf16 probs) -> R3 = P @ V (split-K x4)
    mg(QLbf, DHD, sMD, Kbf, DHD, sND, ML, SEQN, DHD,
       1.f, 0, 4, nullptr, sMN, SEQN, Sh, nullptr, nullptr, nullptr, nullptr, BHN);
    softmax_h2b<15><<<BHN*ML, 256, 0, stream>>>(Sh, SEQN);
    zero_f32_kernel<<<(MD + 255)/256, 256, 0, stream>>>(R3f32, MD);
    mg64(1, Sh, SEQN, sMN, Vbf, DHD, sND, ML, DHD, SEQN,
         1.f, 0, 0.f, 4, 5, R3f32, sMD, DHD, nullptr, BHN);
    cvt_bf16_kernel<<<(MD/4 + 255)/256, 256, 0, stream>>>(R3f32, R3bf, MD/4);

    // 10. W2 = pinv(attn2) @ R3
    mg64(1, Zc, ML, sMM, R3bf, DHD, sMD, ML, DHD, ML,
         1.f, 0, 0.f, 1, 2, nullptr, sMD, DHD, W2bf, BHN);

    // 11. sim1 = Q @ KL^T (f16 scores) -> softmax (bf16) -> AO = P @ W2 (f32)
    mg(Qbf, DHD, sND, KLbf, DHD, sMD, SEQN, ML, DHD,
       1.f, 0, 4, nullptr, sMN, ML, Sh, nullptr, nullptr, nullptr, nullptr, BHN);
    softmax_h2b<2><<<BHN*SEQN, 256, 0, stream>>>(Sh, ML);
    mg64(1, Sh, ML, sMN, W2bf, DHD, sMD, SEQN, DHD, ML,
         1.f, 0, 0.f, 1, 0, AOf2, sND, DHD, nullptr, BHN);

    // 12. residual depthwise conv on V + head-concat (fused) -> CTbf
    resconv_concat_kernel<<<(BND + 255)/256, 256, 0, stream>>>(Vbf, rcw, AOf2, CTbf);

    // 13. out projection + bias, accumulate into OUT_ACC (outer residual)
    mg(CTbf, DIMC, 0, outwb, DIMC, 0, ROWS, DIMC, DIMC,
       1.f, 0, 1, OUT_ACC, 0, DIMC, nullptr, outb, nullptr, nullptr, nullptr, 1);

    // 14. final layernorm -> d_out
    ln_kernel<<<ROWS, 256, 0, stream>>>(OUT_ACC, nw, nb, out, nullptr);
}